// Round 7
// baseline (575.696 us; speedup 1.0000x reference)
//
#include <hip/hip_runtime.h>
#include <math.h>

#define N_NODES 100000
#define N_EDGES 1600000
#define IN_DIM  500
#define HID     64
#define OUT_DIM 40
#define BN_EPS  1e-5f
#define SCAN_NB 98          // ceil(100000 / 1024)

typedef __attribute__((ext_vector_type(8))) short bf16x8;
typedef __attribute__((ext_vector_type(4))) float f32x4;

static inline int cdiv(long a, int b) { return (int)((a + b - 1) / b); }

__device__ inline unsigned short f2bf_rne(float f) {
    unsigned int u = __float_as_uint(f);
    unsigned int r = (u + 0x7FFFu + ((u >> 16) & 1u)) >> 16;
    return (unsigned short)r;
}
__device__ inline float bf2f(unsigned short h) {
    return __uint_as_float(((unsigned int)h) << 16);
}

// ---------------- zero int scratch ----------------
__global__ void k_zero2(int* a, int* b) {
    int i = blockIdx.x * 256 + threadIdx.x;
    if (i < N_NODES) { a[i] = 0; b[i] = 0; }
}

// ---------------- integer in-degree ----------------
__global__ void k_count_deg(const int* __restrict__ ei, int* degi) {
    int e = blockIdx.x * 256 + threadIdx.x;
    if (e < N_EDGES) atomicAdd(&degi[ei[N_EDGES + e]], 1);
}

__global__ void k_dis(const int* __restrict__ degi, float* dis) {
    int i = blockIdx.x * 256 + threadIdx.x;
    if (i < N_NODES) dis[i] = rsqrtf((float)degi[i] + 1.0f);
}

// ---------------- exclusive scan (3 kernels) ----------------
__global__ void k_scan1(const int* __restrict__ degi, int* __restrict__ rowptr,
                        int* __restrict__ blocksum) {
    __shared__ int sd[256];
    int tid = threadIdx.x;
    int base = blockIdx.x * 1024 + tid * 4;
    int v0 = (base + 0 < N_NODES) ? degi[base + 0] : 0;
    int v1 = (base + 1 < N_NODES) ? degi[base + 1] : 0;
    int v2 = (base + 2 < N_NODES) ? degi[base + 2] : 0;
    int v3 = (base + 3 < N_NODES) ? degi[base + 3] : 0;
    int s = v0 + v1 + v2 + v3;
    sd[tid] = s;
    __syncthreads();
    for (int off = 1; off < 256; off <<= 1) {
        int t = (tid >= off) ? sd[tid - off] : 0;
        __syncthreads();
        sd[tid] += t;
        __syncthreads();
    }
    int excl = sd[tid] - s;
    if (base + 0 < N_NODES) rowptr[base + 0] = excl;
    if (base + 1 < N_NODES) rowptr[base + 1] = excl + v0;
    if (base + 2 < N_NODES) rowptr[base + 2] = excl + v0 + v1;
    if (base + 3 < N_NODES) rowptr[base + 3] = excl + v0 + v1 + v2;
    if (tid == 255) blocksum[blockIdx.x] = sd[255];
}

__global__ void k_scan2(int* __restrict__ blocksum, int* __restrict__ blockbase) {
    __shared__ int sd[128];
    int tid = threadIdx.x;
    int v = (tid < SCAN_NB) ? blocksum[tid] : 0;
    sd[tid] = v;
    __syncthreads();
    for (int off = 1; off < 128; off <<= 1) {
        int t = (tid >= off) ? sd[tid - off] : 0;
        __syncthreads();
        sd[tid] += t;
        __syncthreads();
    }
    if (tid < SCAN_NB) blockbase[tid] = sd[tid] - v;
}

__global__ void k_scan3(int* __restrict__ rowptr, const int* __restrict__ blockbase) {
    int add = blockbase[blockIdx.x];
    int base = blockIdx.x * 1024 + threadIdx.x * 4;
#pragma unroll
    for (int i = 0; i < 4; ++i)
        if (base + i < N_NODES) rowptr[base + i] += add;
}

// ---------------- CSR permute: group edges by dst ----------------
__global__ void k_permute(const int* __restrict__ ei, const int* __restrict__ rowptr,
                          int* __restrict__ cursor, const float* __restrict__ dis,
                          int* __restrict__ col, float* __restrict__ valn) {
    int e = blockIdx.x * 256 + threadIdx.x;
    if (e >= N_EDGES) return;
    int s = ei[e];
    int d = ei[N_EDGES + e];
    int pos = rowptr[d] + atomicAdd(&cursor[d], 1);
    col[pos]  = s;
    valn[pos] = dis[s] * dis[d];
}

// ---------------- weight preconvert: W[K,F] -> Wt_hi/lo[64][KP] (transposed,
// zero-padded in k (K..KP) and n (F..64)) ----------------
template <int K, int F, int KP>
__global__ void k_convW(const float* __restrict__ W,
                        unsigned short* __restrict__ wt_hi,
                        unsigned short* __restrict__ wt_lo) {
    int idx = blockIdx.x * 256 + threadIdx.x;
    if (idx >= 64 * KP) return;
    int n = idx / KP, k = idx % KP;
    float v = (n < F && k < K) ? W[(long)k * F + n] : 0.f;
    unsigned short hi = f2bf_rne(v);
    unsigned short lo = f2bf_rne(v - bf2f(hi));
    wt_hi[idx] = hi;
    wt_lo[idx] = lo;
}

// ---------------- split-bf16 MFMA GEMM: dbuf + swizzle + 16x64 wave-tile ----
// h[N,F] = x[N,K] @ W[K,F].  BM=64, BK=64 fp32, 4 waves, wave-tile 16x64.
// A staged RAW FP32 via global_load_lds into double-buffered LDS (2x16 KB),
// source-granule XOR-swizzled (g ^= row&7) so fragment ds_reads are 2-way max.
// Counted s_waitcnt vmcnt(4): next tile's loads stay in flight across compute.
// B fragments straight from L2 (pre-transposed, zero-padded hi/lo weights).
// C = Ah*Bh + Ah*Bl + Al*Bh.
template <int K, int KP, int F>
__global__ __launch_bounds__(256) void k_gemm_mfma(
        const float* __restrict__ x,
        const unsigned short* __restrict__ wt_hi,
        const unsigned short* __restrict__ wt_lo,
        float* __restrict__ h) {
    constexpr int T = KP / 64;
    __shared__ float As[2 * 4096];    // 2 x (64 rows x 64 fp32), linear+swizzled

    const int tid   = threadIdx.x;
    const int wid   = tid >> 6;
    const int lane  = tid & 63;
    const int l15   = lane & 15;
    const int lhi   = lane >> 4;
    const int brow  = blockIdx.x * 64;

    const int srow  = tid >> 4;       // staging row (+16 per p)
    const int sgq   = tid & 15;       // staging dest granule

    const char* xb   = (const char*)x;
    const char* xend = xb + (long)N_NODES * K * 4 - 16;

    const int r  = wid * 16 + l15;    // A fragment row
    const int rx = r & 7;             // read-side swizzle key

    f32x4 acc[4];
#pragma unroll
    for (int nt = 0; nt < 4; ++nt) acc[nt] = (f32x4){0.f, 0.f, 0.f, 0.f};

    // ---- stage tile 0 ----
#pragma unroll
    for (int p = 0; p < 4; ++p) {
        int row = p * 16 + srow;
        long grow = brow + row;
        const char* src = xb + grow * (long)(K * 4) + (long)(sgq ^ (row & 7)) * 16;
        if (src > xend) src = xend;
        unsigned int* dst = (unsigned int*)((char*)As + p * 4096 + tid * 16);
        __builtin_amdgcn_global_load_lds((const unsigned int*)src, dst, 16, 0, 0);
    }

    for (int t = 0; t < T; ++t) {
        const int buf = t & 1;

        // ---- issue next tile's loads into the other buffer ----
        if (t + 1 < T) {
            const int k0n = (t + 1) * 64;
#pragma unroll
            for (int p = 0; p < 4; ++p) {
                int row = p * 16 + srow;
                long grow = brow + row;
                const char* src = xb + grow * (long)(K * 4) + (long)k0n * 4
                                + (long)(sgq ^ (row & 7)) * 16;
                if (src > xend) src = xend;
                unsigned int* dst = (unsigned int*)((char*)As + (buf ^ 1) * 16384
                                                    + p * 4096 + tid * 16);
                __builtin_amdgcn_global_load_lds((const unsigned int*)src, dst, 16, 0, 0);
            }
            asm volatile("s_waitcnt vmcnt(4)" ::: "memory");
        } else {
            asm volatile("s_waitcnt vmcnt(0)" ::: "memory");
        }
        __builtin_amdgcn_s_barrier();   // tile t ready for all waves

        const float* base = As + buf * 4096;
        const int k0 = t * 64;

#pragma unroll
        for (int s = 0; s < 2; ++s) {
            const int g0 = s * 8 + lhi * 2;

            // B fragments straight from global (L2-resident)
            bf16x8 bh[4], bl[4];
#pragma unroll
            for (int nt = 0; nt < 4; ++nt) {
                long off = (long)(nt * 16 + l15) * KP + k0 + s * 32 + lhi * 8;
                bh[nt] = *reinterpret_cast<const bf16x8*>(wt_hi + off);
                bl[nt] = *reinterpret_cast<const bf16x8*>(wt_lo + off);
            }

            // A fragment: swizzled fp32 LDS reads, split hi/lo in regs
            f32x4 a0 = *reinterpret_cast<const f32x4*>(base + r * 64 + ((g0 ^ rx) << 2));
            f32x4 a1 = *reinterpret_cast<const f32x4*>(base + r * 64 + (((g0 + 1) ^ rx) << 2));
            float av[8] = {a0[0], a0[1], a0[2], a0[3], a1[0], a1[1], a1[2], a1[3]};
            bf16x8 ah, al;
#pragma unroll
            for (int i = 0; i < 8; ++i) {
                unsigned short hi = f2bf_rne(av[i]);
                ah[i] = (short)hi;
                al[i] = (short)f2bf_rne(av[i] - bf2f(hi));
            }

#pragma unroll
            for (int nt = 0; nt < 4; ++nt) {
                acc[nt] = __builtin_amdgcn_mfma_f32_16x16x32_bf16(al, bh[nt], acc[nt], 0, 0, 0);
                acc[nt] = __builtin_amdgcn_mfma_f32_16x16x32_bf16(ah, bl[nt], acc[nt], 0, 0, 0);
                acc[nt] = __builtin_amdgcn_mfma_f32_16x16x32_bf16(ah, bh[nt], acc[nt], 0, 0, 0);
            }
        }

        __builtin_amdgcn_s_barrier();   // all waves done reading buf before overwrite
    }

    // epilogue: C/D layout: col = lane&15, row = (lane>>4)*4 + reg
#pragma unroll
    for (int nt = 0; nt < 4; ++nt) {
        int coln = nt * 16 + l15;
        if (F != 64 && coln >= F) continue;
#pragma unroll
        for (int rr = 0; rr < 4; ++rr) {
            int grow = brow + wid * 16 + lhi * 4 + rr;
            if (grow < N_NODES)
                h[(long)grow * F + coln] = acc[nt][rr];
        }
    }
}

// ---------------- pull aggregation + bias + BN + ReLU ----------------
template <int F>
__global__ __launch_bounds__(256) void k_agg_bn_relu(
        const float* __restrict__ h, const int* __restrict__ rowptr,
        const int* __restrict__ degi, const int* __restrict__ col,
        const float* __restrict__ valn, const float* __restrict__ dis,
        const float* __restrict__ bias, const float* __restrict__ g,
        const float* __restrict__ be, const float* __restrict__ m,
        const float* __restrict__ v, float* __restrict__ out) {
    int wid  = (blockIdx.x * 256 + threadIdx.x) >> 6;
    int lane = threadIdx.x & 63;
    if (wid >= N_NODES) return;

    int start = rowptr[wid];
    int cnt   = degi[wid];

    float acc = 0.0f;
    if (lane < F) {
        float d = dis[wid];
        acc = h[(long)wid * F + lane] * d * d + bias[lane];
    }

    int j = 0;
    for (; j + 4 <= cnt; j += 4) {
        int   s0 = col[start + j + 0], s1 = col[start + j + 1];
        int   s2 = col[start + j + 2], s3 = col[start + j + 3];
        float w0 = valn[start + j + 0], w1 = valn[start + j + 1];
        float w2 = valn[start + j + 2], w3 = valn[start + j + 3];
        if (lane < F) {
            float h0 = h[(long)s0 * F + lane];
            float h1 = h[(long)s1 * F + lane];
            float h2 = h[(long)s2 * F + lane];
            float h3 = h[(long)s3 * F + lane];
            acc += h0 * w0; acc += h1 * w1; acc += h2 * w2; acc += h3 * w3;
        }
    }
    for (; j < cnt; ++j) {
        int   s = col[start + j];
        float w = valn[start + j];
        if (lane < F) acc += h[(long)s * F + lane] * w;
    }

    if (lane < F) {
        float xv = (acc - m[lane]) * rsqrtf(v[lane] + BN_EPS) * g[lane] + be[lane];
        out[(long)wid * F + lane] = fmaxf(xv, 0.0f);
    }
}

// ---------------- pull aggregation + bias + log_softmax (layer 3) ----------------
template <int F>
__global__ __launch_bounds__(256) void k_agg_lsm(
        const float* __restrict__ h, const int* __restrict__ rowptr,
        const int* __restrict__ degi, const int* __restrict__ col,
        const float* __restrict__ valn, const float* __restrict__ dis,
        const float* __restrict__ bias, float* __restrict__ out) {
    int wid  = (blockIdx.x * 256 + threadIdx.x) >> 6;
    int lane = threadIdx.x & 63;
    if (wid >= N_NODES) return;

    int start = rowptr[wid];
    int cnt   = degi[wid];

    float acc = 0.0f;
    if (lane < F) {
        float d = dis[wid];
        acc = h[(long)wid * F + lane] * d * d + bias[lane];
    }

    int j = 0;
    for (; j + 4 <= cnt; j += 4) {
        int   s0 = col[start + j + 0], s1 = col[start + j + 1];
        int   s2 = col[start + j + 2], s3 = col[start + j + 3];
        float w0 = valn[start + j + 0], w1 = valn[start + j + 1];
        float w2 = valn[start + j + 2], w3 = valn[start + j + 3];
        if (lane < F) {
            float h0 = h[(long)s0 * F + lane];
            float h1 = h[(long)s1 * F + lane];
            float h2 = h[(long)s2 * F + lane];
            float h3 = h[(long)s3 * F + lane];
            acc += h0 * w0; acc += h1 * w1; acc += h2 * w2; acc += h3 * w3;
        }
    }
    for (; j < cnt; ++j) {
        int   s = col[start + j];
        float w = valn[start + j];
        if (lane < F) acc += h[(long)s * F + lane] * w;
    }

    float valf = (lane < F) ? acc : -INFINITY;
    float mx = valf;
#pragma unroll
    for (int o = 32; o > 0; o >>= 1) mx = fmaxf(mx, __shfl_xor(mx, o));
    float ex = (lane < F) ? expf(valf - mx) : 0.0f;
    float sm = ex;
#pragma unroll
    for (int o = 32; o > 0; o >>= 1) sm += __shfl_xor(sm, o);
    float ls = logf(sm);
    if (lane < F) out[(long)wid * F + lane] = valf - mx - ls;
}

extern "C" void kernel_launch(void* const* d_in, const int* in_sizes, int n_in,
                              void* d_out, int out_size, void* d_ws, size_t ws_size,
                              hipStream_t stream) {
    const float* x   = (const float*)d_in[0];
    const int*   ei  = (const int*)d_in[1];
    const float* W1  = (const float*)d_in[2];
    const float* b1  = (const float*)d_in[3];
    const float* g1  = (const float*)d_in[4];
    const float* be1 = (const float*)d_in[5];
    const float* m1  = (const float*)d_in[6];
    const float* v1  = (const float*)d_in[7];
    const float* W2  = (const float*)d_in[8];
    const float* b2  = (const float*)d_in[9];
    const float* g2  = (const float*)d_in[10];
    const float* be2 = (const float*)d_in[11];
    const float* m2  = (const float*)d_in[12];
    const float* v2  = (const float*)d_in[13];
    const float* W3  = (const float*)d_in[14];
    const float* b3  = (const float*)d_in[15];
    float* out = (float*)d_out;

    // workspace layout (16B-aligned slabs)
    float* ws        = (float*)d_ws;
    float* dis       = ws;                            // 100096
    int*   degi      = (int*)(ws + 100096);           // 100096
    int*   cursor    = degi + 100096;                 // 100096
    int*   rowptr    = cursor + 100096;               // 100096
    int*   blocksum  = rowptr + 100096;               // 128
    int*   blockbase = blocksum + 128;                // 128
    int*   col       = blockbase + 128;               // 1.6M
    float* valn      = (float*)(col + N_EDGES);       // 1.6M
    float* bufH      = valn + N_EDGES;                // 6.4M
    float* bufA      = bufH + (long)N_NODES * HID;    // 6.4M
    unsigned short* wt1_hi = (unsigned short*)(bufA + (long)N_NODES * HID); // 64*512
    unsigned short* wt1_lo = wt1_hi + 64 * 512;
    unsigned short* wt2_hi = wt1_lo + 64 * 512;       // 64*64
    unsigned short* wt2_lo = wt2_hi + 64 * 64;
    unsigned short* wt3_hi = wt2_lo + 64 * 64;        // 64*64
    unsigned short* wt3_lo = wt3_hi + 64 * 64;

    // ---- CSR build ----
    k_zero2<<<cdiv(N_NODES, 256), 256, 0, stream>>>(degi, cursor);
    k_count_deg<<<cdiv(N_EDGES, 256), 256, 0, stream>>>(ei, degi);
    k_dis<<<cdiv(N_NODES, 256), 256, 0, stream>>>(degi, dis);
    k_scan1<<<SCAN_NB, 256, 0, stream>>>(degi, rowptr, blocksum);
    k_scan2<<<1, 128, 0, stream>>>(blocksum, blockbase);
    k_scan3<<<SCAN_NB, 256, 0, stream>>>(rowptr, blockbase);
    k_permute<<<cdiv(N_EDGES, 256), 256, 0, stream>>>(ei, rowptr, cursor, dis, col, valn);

    // ---- weight preconvert (hi/lo bf16, transposed, zero-padded) ----
    k_convW<IN_DIM, HID, 512><<<(64 * 512) / 256, 256, 0, stream>>>(W1, wt1_hi, wt1_lo);
    k_convW<HID, HID, 64><<<(64 * 64) / 256, 256, 0, stream>>>(W2, wt2_hi, wt2_lo);
    k_convW<HID, OUT_DIM, 64><<<(64 * 64) / 256, 256, 0, stream>>>(W3, wt3_hi, wt3_lo);

    const int gemm_grid = cdiv(N_NODES, 64);
    const int agg_grid  = cdiv((long)N_NODES * 64, 256);

    // ---- layer 1: 500 -> 64 ----
    k_gemm_mfma<IN_DIM, 512, HID><<<gemm_grid, 256, 0, stream>>>(x, wt1_hi, wt1_lo, bufH);
    k_agg_bn_relu<HID><<<agg_grid, 256, 0, stream>>>(bufH, rowptr, degi, col, valn,
                                                     dis, b1, g1, be1, m1, v1, bufA);

    // ---- layer 2: 64 -> 64 ----
    k_gemm_mfma<HID, 64, HID><<<gemm_grid, 256, 0, stream>>>(bufA, wt2_hi, wt2_lo, bufH);
    k_agg_bn_relu<HID><<<agg_grid, 256, 0, stream>>>(bufH, rowptr, degi, col, valn,
                                                     dis, b2, g2, be2, m2, v2, bufA);

    // ---- layer 3: 64 -> 40 ----
    k_gemm_mfma<HID, 64, OUT_DIM><<<gemm_grid, 256, 0, stream>>>(bufA, wt3_hi, wt3_lo, bufH);
    k_agg_lsm<OUT_DIM><<<agg_grid, 256, 0, stream>>>(bufH, rowptr, degi, col, valn,
                                                     dis, b3, out);
}

// Round 8
// 519.929 us; speedup vs baseline: 1.1073x; 1.1073x over previous
//
#include <hip/hip_runtime.h>
#include <math.h>

#define N_NODES 100000
#define N_EDGES 1600000
#define IN_DIM  500
#define HID     64
#define OUT_DIM 40
#define BN_EPS  1e-5f
#define SCAN_NB 98          // ceil(100000 / 1024)

typedef __attribute__((ext_vector_type(8))) short bf16x8;
typedef __attribute__((ext_vector_type(4))) float f32x4;

static inline int cdiv(long a, int b) { return (int)((a + b - 1) / b); }

__device__ inline unsigned short f2bf_rne(float f) {
    unsigned int u = __float_as_uint(f);
    unsigned int r = (u + 0x7FFFu + ((u >> 16) & 1u)) >> 16;
    return (unsigned short)r;
}
__device__ inline float bf2f(unsigned short h) {
    return __uint_as_float(((unsigned int)h) << 16);
}

// ---------------- zero int scratch ----------------
__global__ void k_zero2(int* a, int* b) {
    int i = blockIdx.x * 256 + threadIdx.x;
    if (i < N_NODES) { a[i] = 0; b[i] = 0; }
}

// ---------------- integer in-degree ----------------
__global__ void k_count_deg(const int* __restrict__ ei, int* degi) {
    int e = blockIdx.x * 256 + threadIdx.x;
    if (e < N_EDGES) atomicAdd(&degi[ei[N_EDGES + e]], 1);
}

__global__ void k_dis(const int* __restrict__ degi, float* dis) {
    int i = blockIdx.x * 256 + threadIdx.x;
    if (i < N_NODES) dis[i] = rsqrtf((float)degi[i] + 1.0f);
}

// ---------------- exclusive scan (3 kernels) ----------------
__global__ void k_scan1(const int* __restrict__ degi, int* __restrict__ rowptr,
                        int* __restrict__ blocksum) {
    __shared__ int sd[256];
    int tid = threadIdx.x;
    int base = blockIdx.x * 1024 + tid * 4;
    int v0 = (base + 0 < N_NODES) ? degi[base + 0] : 0;
    int v1 = (base + 1 < N_NODES) ? degi[base + 1] : 0;
    int v2 = (base + 2 < N_NODES) ? degi[base + 2] : 0;
    int v3 = (base + 3 < N_NODES) ? degi[base + 3] : 0;
    int s = v0 + v1 + v2 + v3;
    sd[tid] = s;
    __syncthreads();
    for (int off = 1; off < 256; off <<= 1) {
        int t = (tid >= off) ? sd[tid - off] : 0;
        __syncthreads();
        sd[tid] += t;
        __syncthreads();
    }
    int excl = sd[tid] - s;
    if (base + 0 < N_NODES) rowptr[base + 0] = excl;
    if (base + 1 < N_NODES) rowptr[base + 1] = excl + v0;
    if (base + 2 < N_NODES) rowptr[base + 2] = excl + v0 + v1;
    if (base + 3 < N_NODES) rowptr[base + 3] = excl + v0 + v1 + v2;
    if (tid == 255) blocksum[blockIdx.x] = sd[255];
}

__global__ void k_scan2(int* __restrict__ blocksum, int* __restrict__ blockbase) {
    __shared__ int sd[128];
    int tid = threadIdx.x;
    int v = (tid < SCAN_NB) ? blocksum[tid] : 0;
    sd[tid] = v;
    __syncthreads();
    for (int off = 1; off < 128; off <<= 1) {
        int t = (tid >= off) ? sd[tid - off] : 0;
        __syncthreads();
        sd[tid] += t;
        __syncthreads();
    }
    if (tid < SCAN_NB) blockbase[tid] = sd[tid] - v;
}

__global__ void k_scan3(int* __restrict__ rowptr, const int* __restrict__ blockbase) {
    int add = blockbase[blockIdx.x];
    int base = blockIdx.x * 1024 + threadIdx.x * 4;
#pragma unroll
    for (int i = 0; i < 4; ++i)
        if (base + i < N_NODES) rowptr[base + i] += add;
}

// ---------------- CSR permute: group edges by dst ----------------
__global__ void k_permute(const int* __restrict__ ei, const int* __restrict__ rowptr,
                          int* __restrict__ cursor, const float* __restrict__ dis,
                          int* __restrict__ col, float* __restrict__ valn) {
    int e = blockIdx.x * 256 + threadIdx.x;
    if (e >= N_EDGES) return;
    int s = ei[e];
    int d = ei[N_EDGES + e];
    int pos = rowptr[d] + atomicAdd(&cursor[d], 1);
    col[pos]  = s;
    valn[pos] = dis[s] * dis[d];
}

// ---------------- weight preconvert: W[K,F] -> Wt_hi/lo[64][KP] (transposed,
// zero-padded in k (K..KP) and n (F..64)) ----------------
template <int K, int F, int KP>
__global__ void k_convW(const float* __restrict__ W,
                        unsigned short* __restrict__ wt_hi,
                        unsigned short* __restrict__ wt_lo) {
    int idx = blockIdx.x * 256 + threadIdx.x;
    if (idx >= 64 * KP) return;
    int n = idx / KP, k = idx % KP;
    float v = (n < F && k < K) ? W[(long)k * F + n] : 0.f;
    unsigned short hi = f2bf_rne(v);
    unsigned short lo = f2bf_rne(v - bf2f(hi));
    wt_hi[idx] = hi;
    wt_lo[idx] = lo;
}

// ---------------- split-bf16 MFMA GEMM, direct-from-global (no LDS) --------
// h_bf16[N,F] = x[N,K] @ W[K,F].  One wave owns 32 rows; A fragments loaded
// straight from global (lane: row=l15(+16), k=lhi*8..+7 -> 2x f32x4, lanes
// lhi pair into full 64B lines), converted hi/lo bf16 in regs. B fragments
// from L2 (pre-transposed, zero-padded hi/lo weights). No barriers, no LDS:
// waves independent, TLP hides latency.  C = Ah*Bh + Ah*Bl + Al*Bh.
template <int K, int KP, int F>
__global__ __launch_bounds__(256) void k_gemm_mfma(
        const float* __restrict__ x,
        const unsigned short* __restrict__ wt_hi,
        const unsigned short* __restrict__ wt_lo,
        unsigned short* __restrict__ h) {
    constexpr int T = KP / 32;
    const int tid  = threadIdx.x;
    const int wid  = tid >> 6;
    const int lane = tid & 63;
    const int l15  = lane & 15;
    const int lhi  = lane >> 4;

    const long wrow = (long)blockIdx.x * 128 + wid * 32;

    const char* xb   = (const char*)x;
    const char* xmax = xb + (long)N_NODES * K * 4 - 32;  // last valid 32B chunk

    const char* s0 = xb + (wrow + l15) * (long)(K * 4) + (long)lhi * 32;
    const char* s1 = s0 + 16 * (long)(K * 4);

    const unsigned short* bp_h = wt_hi + (long)l15 * KP + lhi * 8;
    const unsigned short* bp_l = wt_lo + (long)l15 * KP + lhi * 8;

    f32x4 acc[2][4];
#pragma unroll
    for (int mt = 0; mt < 2; ++mt)
#pragma unroll
        for (int nt = 0; nt < 4; ++nt)
            acc[mt][nt] = (f32x4){0.f, 0.f, 0.f, 0.f};

    for (int t = 0; t < T; ++t) {
        // ---- A fragments, straight from global ----
        const char* p0 = s0 + (long)t * 128;
        const char* p1 = s1 + (long)t * 128;
        if (p0 > xmax) p0 = xmax;   // row/k tail: garbage x B-zero-pad = 0
        if (p1 > xmax) p1 = xmax;
        f32x4 a00 = *reinterpret_cast<const f32x4*>(p0);
        f32x4 a01 = *reinterpret_cast<const f32x4*>(p0 + 16);
        f32x4 a10 = *reinterpret_cast<const f32x4*>(p1);
        f32x4 a11 = *reinterpret_cast<const f32x4*>(p1 + 16);

        bf16x8 ah0, al0, ah1, al1;
#pragma unroll
        for (int i = 0; i < 4; ++i) {
            unsigned short hi;
            hi = f2bf_rne(a00[i]); ah0[i]     = (short)hi; al0[i]     = (short)f2bf_rne(a00[i] - bf2f(hi));
            hi = f2bf_rne(a01[i]); ah0[i + 4] = (short)hi; al0[i + 4] = (short)f2bf_rne(a01[i] - bf2f(hi));
            hi = f2bf_rne(a10[i]); ah1[i]     = (short)hi; al1[i]     = (short)f2bf_rne(a10[i] - bf2f(hi));
            hi = f2bf_rne(a11[i]); ah1[i + 4] = (short)hi; al1[i + 4] = (short)f2bf_rne(a11[i] - bf2f(hi));
        }

        // ---- B fragments from L2 ----
        bf16x8 bh[4], bl[4];
#pragma unroll
        for (int nt = 0; nt < 4; ++nt) {
            long off = (long)nt * 16 * KP + t * 32;
            bh[nt] = *reinterpret_cast<const bf16x8*>(bp_h + off);
            bl[nt] = *reinterpret_cast<const bf16x8*>(bp_l + off);
        }

#pragma unroll
        for (int nt = 0; nt < 4; ++nt) {
            acc[0][nt] = __builtin_amdgcn_mfma_f32_16x16x32_bf16(al0, bh[nt], acc[0][nt], 0, 0, 0);
            acc[0][nt] = __builtin_amdgcn_mfma_f32_16x16x32_bf16(ah0, bl[nt], acc[0][nt], 0, 0, 0);
            acc[0][nt] = __builtin_amdgcn_mfma_f32_16x16x32_bf16(ah0, bh[nt], acc[0][nt], 0, 0, 0);
            acc[1][nt] = __builtin_amdgcn_mfma_f32_16x16x32_bf16(al1, bh[nt], acc[1][nt], 0, 0, 0);
            acc[1][nt] = __builtin_amdgcn_mfma_f32_16x16x32_bf16(ah1, bl[nt], acc[1][nt], 0, 0, 0);
            acc[1][nt] = __builtin_amdgcn_mfma_f32_16x16x32_bf16(ah1, bh[nt], acc[1][nt], 0, 0, 0);
        }
    }

    // epilogue: C/D layout: col = lane&15, row = (lane>>4)*4 + reg; store bf16
#pragma unroll
    for (int mt = 0; mt < 2; ++mt)
#pragma unroll
        for (int nt = 0; nt < 4; ++nt) {
            int coln = nt * 16 + l15;
            if (F != 64 && coln >= F) continue;
#pragma unroll
            for (int rr = 0; rr < 4; ++rr) {
                long grow = wrow + mt * 16 + lhi * 4 + rr;
                if (grow < N_NODES)
                    h[grow * F + coln] = f2bf_rne(acc[mt][nt][rr]);
            }
        }
}

// ---------------- pull aggregation + bias + BN + ReLU (bf16 h) ----------------
template <int F>
__global__ __launch_bounds__(256) void k_agg_bn_relu(
        const unsigned short* __restrict__ h, const int* __restrict__ rowptr,
        const int* __restrict__ degi, const int* __restrict__ col,
        const float* __restrict__ valn, const float* __restrict__ dis,
        const float* __restrict__ bias, const float* __restrict__ g,
        const float* __restrict__ be, const float* __restrict__ m,
        const float* __restrict__ v, float* __restrict__ out) {
    int wid  = (blockIdx.x * 256 + threadIdx.x) >> 6;
    int lane = threadIdx.x & 63;
    if (wid >= N_NODES) return;

    int start = rowptr[wid];
    int cnt   = degi[wid];

    float acc = 0.0f;
    if (lane < F) {
        float d = dis[wid];
        acc = bf2f(h[(long)wid * F + lane]) * d * d + bias[lane];
    }

    int j = 0;
    for (; j + 4 <= cnt; j += 4) {
        int   s0 = col[start + j + 0], s1 = col[start + j + 1];
        int   s2 = col[start + j + 2], s3 = col[start + j + 3];
        float w0 = valn[start + j + 0], w1 = valn[start + j + 1];
        float w2 = valn[start + j + 2], w3 = valn[start + j + 3];
        if (lane < F) {
            float h0 = bf2f(h[(long)s0 * F + lane]);
            float h1 = bf2f(h[(long)s1 * F + lane]);
            float h2 = bf2f(h[(long)s2 * F + lane]);
            float h3 = bf2f(h[(long)s3 * F + lane]);
            acc += h0 * w0; acc += h1 * w1; acc += h2 * w2; acc += h3 * w3;
        }
    }
    for (; j < cnt; ++j) {
        int   s = col[start + j];
        float w = valn[start + j];
        if (lane < F) acc += bf2f(h[(long)s * F + lane]) * w;
    }

    if (lane < F) {
        float xv = (acc - m[lane]) * rsqrtf(v[lane] + BN_EPS) * g[lane] + be[lane];
        out[(long)wid * F + lane] = fmaxf(xv, 0.0f);
    }
}

// ---------------- pull aggregation + bias + log_softmax (bf16 h) ----------------
template <int F>
__global__ __launch_bounds__(256) void k_agg_lsm(
        const unsigned short* __restrict__ h, const int* __restrict__ rowptr,
        const int* __restrict__ degi, const int* __restrict__ col,
        const float* __restrict__ valn, const float* __restrict__ dis,
        const float* __restrict__ bias, float* __restrict__ out) {
    int wid  = (blockIdx.x * 256 + threadIdx.x) >> 6;
    int lane = threadIdx.x & 63;
    if (wid >= N_NODES) return;

    int start = rowptr[wid];
    int cnt   = degi[wid];

    float acc = 0.0f;
    if (lane < F) {
        float d = dis[wid];
        acc = bf2f(h[(long)wid * F + lane]) * d * d + bias[lane];
    }

    int j = 0;
    for (; j + 4 <= cnt; j += 4) {
        int   s0 = col[start + j + 0], s1 = col[start + j + 1];
        int   s2 = col[start + j + 2], s3 = col[start + j + 3];
        float w0 = valn[start + j + 0], w1 = valn[start + j + 1];
        float w2 = valn[start + j + 2], w3 = valn[start + j + 3];
        if (lane < F) {
            float h0 = bf2f(h[(long)s0 * F + lane]);
            float h1 = bf2f(h[(long)s1 * F + lane]);
            float h2 = bf2f(h[(long)s2 * F + lane]);
            float h3 = bf2f(h[(long)s3 * F + lane]);
            acc += h0 * w0; acc += h1 * w1; acc += h2 * w2; acc += h3 * w3;
        }
    }
    for (; j < cnt; ++j) {
        int   s = col[start + j];
        float w = valn[start + j];
        if (lane < F) acc += bf2f(h[(long)s * F + lane]) * w;
    }

    float valf = (lane < F) ? acc : -INFINITY;
    float mx = valf;
#pragma unroll
    for (int o = 32; o > 0; o >>= 1) mx = fmaxf(mx, __shfl_xor(mx, o));
    float ex = (lane < F) ? expf(valf - mx) : 0.0f;
    float sm = ex;
#pragma unroll
    for (int o = 32; o > 0; o >>= 1) sm += __shfl_xor(sm, o);
    float ls = logf(sm);
    if (lane < F) out[(long)wid * F + lane] = valf - mx - ls;
}

extern "C" void kernel_launch(void* const* d_in, const int* in_sizes, int n_in,
                              void* d_out, int out_size, void* d_ws, size_t ws_size,
                              hipStream_t stream) {
    const float* x   = (const float*)d_in[0];
    const int*   ei  = (const int*)d_in[1];
    const float* W1  = (const float*)d_in[2];
    const float* b1  = (const float*)d_in[3];
    const float* g1  = (const float*)d_in[4];
    const float* be1 = (const float*)d_in[5];
    const float* m1  = (const float*)d_in[6];
    const float* v1  = (const float*)d_in[7];
    const float* W2  = (const float*)d_in[8];
    const float* b2  = (const float*)d_in[9];
    const float* g2  = (const float*)d_in[10];
    const float* be2 = (const float*)d_in[11];
    const float* m2  = (const float*)d_in[12];
    const float* v2  = (const float*)d_in[13];
    const float* W3  = (const float*)d_in[14];
    const float* b3  = (const float*)d_in[15];
    float* out = (float*)d_out;

    // workspace layout (16B-aligned slabs)
    float* ws        = (float*)d_ws;
    float* dis       = ws;                            // 100096
    int*   degi      = (int*)(ws + 100096);           // 100096
    int*   cursor    = degi + 100096;                 // 100096
    int*   rowptr    = cursor + 100096;               // 100096
    int*   blocksum  = rowptr + 100096;               // 128
    int*   blockbase = blocksum + 128;                // 128
    int*   col       = blockbase + 128;               // 1.6M
    float* valn      = (float*)(col + N_EDGES);       // 1.6M
    unsigned short* bufH = (unsigned short*)(valn + N_EDGES);   // N*64 bf16
    float* bufA      = (float*)(bufH + (long)N_NODES * HID);    // N*64 fp32
    unsigned short* wt1_hi = (unsigned short*)(bufA + (long)N_NODES * HID); // 64*512
    unsigned short* wt1_lo = wt1_hi + 64 * 512;
    unsigned short* wt2_hi = wt1_lo + 64 * 512;       // 64*64
    unsigned short* wt2_lo = wt2_hi + 64 * 64;
    unsigned short* wt3_hi = wt2_lo + 64 * 64;        // 64*64
    unsigned short* wt3_lo = wt3_hi + 64 * 64;

    // ---- CSR build ----
    k_zero2<<<cdiv(N_NODES, 256), 256, 0, stream>>>(degi, cursor);
    k_count_deg<<<cdiv(N_EDGES, 256), 256, 0, stream>>>(ei, degi);
    k_dis<<<cdiv(N_NODES, 256), 256, 0, stream>>>(degi, dis);
    k_scan1<<<SCAN_NB, 256, 0, stream>>>(degi, rowptr, blocksum);
    k_scan2<<<1, 128, 0, stream>>>(blocksum, blockbase);
    k_scan3<<<SCAN_NB, 256, 0, stream>>>(rowptr, blockbase);
    k_permute<<<cdiv(N_EDGES, 256), 256, 0, stream>>>(ei, rowptr, cursor, dis, col, valn);

    // ---- weight preconvert (hi/lo bf16, transposed, zero-padded) ----
    k_convW<IN_DIM, HID, 512><<<(64 * 512) / 256, 256, 0, stream>>>(W1, wt1_hi, wt1_lo);
    k_convW<HID, HID, 64><<<(64 * 64) / 256, 256, 0, stream>>>(W2, wt2_hi, wt2_lo);
    k_convW<HID, OUT_DIM, 64><<<(64 * 64) / 256, 256, 0, stream>>>(W3, wt3_hi, wt3_lo);

    const int gemm_grid = cdiv(N_NODES, 128);   // 4 waves x 32 rows
    const int agg_grid  = cdiv((long)N_NODES * 64, 256);

    // ---- layer 1: 500 -> 64 ----
    k_gemm_mfma<IN_DIM, 512, HID><<<gemm_grid, 256, 0, stream>>>(x, wt1_hi, wt1_lo, bufH);
    k_agg_bn_relu<HID><<<agg_grid, 256, 0, stream>>>(bufH, rowptr, degi, col, valn,
                                                     dis, b1, g1, be1, m1, v1, bufA);

    // ---- layer 2: 64 -> 64 ----
    k_gemm_mfma<HID, 64, HID><<<gemm_grid, 256, 0, stream>>>(bufA, wt2_hi, wt2_lo, bufH);
    k_agg_bn_relu<HID><<<agg_grid, 256, 0, stream>>>(bufH, rowptr, degi, col, valn,
                                                     dis, b2, g2, be2, m2, v2, bufA);

    // ---- layer 3: 64 -> 40 ----
    k_gemm_mfma<HID, 64, OUT_DIM><<<gemm_grid, 256, 0, stream>>>(bufA, wt3_hi, wt3_lo, bufH);
    k_agg_lsm<OUT_DIM><<<agg_grid, 256, 0, stream>>>(bufH, rowptr, degi, col, valn,
                                                     dis, b3, out);
}

// Round 9
// 493.194 us; speedup vs baseline: 1.1673x; 1.0542x over previous
//
#include <hip/hip_runtime.h>
#include <math.h>

#define N_NODES 100000
#define N_EDGES 1600000
#define IN_DIM  500
#define HID     64
#define OUT_DIM 40
#define BN_EPS  1e-5f
#define SCAN_NB 98          // ceil(100000 / 1024)

typedef __attribute__((ext_vector_type(8))) short bf16x8;
typedef __attribute__((ext_vector_type(4))) float f32x4;

static inline int cdiv(long a, int b) { return (int)((a + b - 1) / b); }

__device__ inline unsigned short f2bf_rne(float f) {
    unsigned int u = __float_as_uint(f);
    unsigned int r = (u + 0x7FFFu + ((u >> 16) & 1u)) >> 16;
    return (unsigned short)r;
}
__device__ inline float bf2f(unsigned short h) {
    return __uint_as_float(((unsigned int)h) << 16);
}

// truncate-split one f32x4 pair into hi/lo bf16x8 slots.
// a = hi + r exactly to 2^-8; lo = trunc(r) captures r to 2^-16.
// (hi truncation bias is corrected by the Al*Bh MFMA term.)
__device__ inline void split2x4(const f32x4 a, const f32x4 b, bf16x8& hi, bf16x8& lo) {
#pragma unroll
    for (int i = 0; i < 4; ++i) {
        unsigned int ua = __float_as_uint(a[i]);
        float ra = a[i] - __uint_as_float(ua & 0xffff0000u);
        hi[i] = (short)(ua >> 16);
        lo[i] = (short)(__float_as_uint(ra) >> 16);
        unsigned int ub = __float_as_uint(b[i]);
        float rb = b[i] - __uint_as_float(ub & 0xffff0000u);
        hi[i + 4] = (short)(ub >> 16);
        lo[i + 4] = (short)(__float_as_uint(rb) >> 16);
    }
}

// ---------------- zero int scratch ----------------
__global__ void k_zero2(int* a, int* b) {
    int i = blockIdx.x * 256 + threadIdx.x;
    if (i < N_NODES) { a[i] = 0; b[i] = 0; }
}

// ---------------- integer in-degree ----------------
__global__ void k_count_deg(const int* __restrict__ ei, int* degi) {
    int e = blockIdx.x * 256 + threadIdx.x;
    if (e < N_EDGES) atomicAdd(&degi[ei[N_EDGES + e]], 1);
}

__global__ void k_dis(const int* __restrict__ degi, float* dis) {
    int i = blockIdx.x * 256 + threadIdx.x;
    if (i < N_NODES) dis[i] = rsqrtf((float)degi[i] + 1.0f);
}

// ---------------- exclusive scan (3 kernels) ----------------
__global__ void k_scan1(const int* __restrict__ degi, int* __restrict__ rowptr,
                        int* __restrict__ blocksum) {
    __shared__ int sd[256];
    int tid = threadIdx.x;
    int base = blockIdx.x * 1024 + tid * 4;
    int v0 = (base + 0 < N_NODES) ? degi[base + 0] : 0;
    int v1 = (base + 1 < N_NODES) ? degi[base + 1] : 0;
    int v2 = (base + 2 < N_NODES) ? degi[base + 2] : 0;
    int v3 = (base + 3 < N_NODES) ? degi[base + 3] : 0;
    int s = v0 + v1 + v2 + v3;
    sd[tid] = s;
    __syncthreads();
    for (int off = 1; off < 256; off <<= 1) {
        int t = (tid >= off) ? sd[tid - off] : 0;
        __syncthreads();
        sd[tid] += t;
        __syncthreads();
    }
    int excl = sd[tid] - s;
    if (base + 0 < N_NODES) rowptr[base + 0] = excl;
    if (base + 1 < N_NODES) rowptr[base + 1] = excl + v0;
    if (base + 2 < N_NODES) rowptr[base + 2] = excl + v0 + v1;
    if (base + 3 < N_NODES) rowptr[base + 3] = excl + v0 + v1 + v2;
    if (tid == 255) blocksum[blockIdx.x] = sd[255];
}

__global__ void k_scan2(int* __restrict__ blocksum, int* __restrict__ blockbase) {
    __shared__ int sd[128];
    int tid = threadIdx.x;
    int v = (tid < SCAN_NB) ? blocksum[tid] : 0;
    sd[tid] = v;
    __syncthreads();
    for (int off = 1; off < 128; off <<= 1) {
        int t = (tid >= off) ? sd[tid - off] : 0;
        __syncthreads();
        sd[tid] += t;
        __syncthreads();
    }
    if (tid < SCAN_NB) blockbase[tid] = sd[tid] - v;
}

__global__ void k_scan3(int* __restrict__ rowptr, const int* __restrict__ blockbase) {
    int add = blockbase[blockIdx.x];
    int base = blockIdx.x * 1024 + threadIdx.x * 4;
#pragma unroll
    for (int i = 0; i < 4; ++i)
        if (base + i < N_NODES) rowptr[base + i] += add;
}

// ---------------- CSR permute: group edges by dst ----------------
__global__ void k_permute(const int* __restrict__ ei, const int* __restrict__ rowptr,
                          int* __restrict__ cursor, const float* __restrict__ dis,
                          int* __restrict__ col, float* __restrict__ valn) {
    int e = blockIdx.x * 256 + threadIdx.x;
    if (e >= N_EDGES) return;
    int s = ei[e];
    int d = ei[N_EDGES + e];
    int pos = rowptr[d] + atomicAdd(&cursor[d], 1);
    col[pos]  = s;
    valn[pos] = dis[s] * dis[d];
}

// ---------------- weight preconvert: W[K,F] -> Wt_hi/lo[64][KP] ----------------
template <int K, int F, int KP>
__global__ void k_convW(const float* __restrict__ W,
                        unsigned short* __restrict__ wt_hi,
                        unsigned short* __restrict__ wt_lo) {
    int idx = blockIdx.x * 256 + threadIdx.x;
    if (idx >= 64 * KP) return;
    int n = idx / KP, k = idx % KP;
    float v = (n < F && k < K) ? W[(long)k * F + n] : 0.f;
    unsigned short hi = f2bf_rne(v);
    unsigned short lo = f2bf_rne(v - bf2f(hi));
    wt_hi[idx] = hi;
    wt_lo[idx] = lo;
}

// ---------------- split-bf16 MFMA GEMM, direct global + reg double-buffer ----
// h_bf16[N,64] = x[N,K] @ W[K,F] (cols F..63 zero via zero-padded weights).
// One wave owns 32 rows. Tile t+1's A (4x f32x4) and B (8x bf16x8) are loaded
// into registers BEFORE computing tile t: compiler emits counted vmcnt, loads
// stay in flight under convert+MFMA. No LDS, no barriers; waves independent.
// C = Ah*Bh + Ah*Bl + Al*Bh  (trunc-split A, RNE-split B).
template <int K, int KP>
__global__ __launch_bounds__(256) void k_gemm_mfma(
        const float* __restrict__ x,
        const unsigned short* __restrict__ wt_hi,
        const unsigned short* __restrict__ wt_lo,
        unsigned short* __restrict__ h) {
    constexpr int T = KP / 32;
    const int tid  = threadIdx.x;
    const int wid  = tid >> 6;
    const int lane = tid & 63;
    const int l15  = lane & 15;
    const int lhi  = lane >> 4;

    const long wrow = (long)blockIdx.x * 128 + wid * 32;

    const char* xb   = (const char*)x;
    const char* xmax = xb + (long)N_NODES * K * 4 - 32;  // 16B-aligned clamp
    const char* s0 = xb + (wrow + l15) * (long)(K * 4) + (long)lhi * 32;
    const char* s1 = s0 + 16 * (long)(K * 4);

    const unsigned short* bp_h = wt_hi + (long)l15 * KP + lhi * 8;
    const unsigned short* bp_l = wt_lo + (long)l15 * KP + lhi * 8;

    f32x4 acc[2][4];
#pragma unroll
    for (int mt = 0; mt < 2; ++mt)
#pragma unroll
        for (int nt = 0; nt < 4; ++nt)
            acc[mt][nt] = (f32x4){0.f, 0.f, 0.f, 0.f};

    f32x4  ca[4];
    bf16x8 cbh[4], cbl[4];

    {   // prologue: tile 0
        const char* p0 = s0;
        const char* p1 = s1;
        if (p0 > xmax) p0 = xmax;
        if (p1 > xmax) p1 = xmax;
        ca[0] = *(const f32x4*)p0; ca[1] = *(const f32x4*)(p0 + 16);
        ca[2] = *(const f32x4*)p1; ca[3] = *(const f32x4*)(p1 + 16);
#pragma unroll
        for (int nt = 0; nt < 4; ++nt) {
            cbh[nt] = *(const bf16x8*)(bp_h + (long)nt * 16 * KP);
            cbl[nt] = *(const bf16x8*)(bp_l + (long)nt * 16 * KP);
        }
    }

    for (int t = 0; t < T; ++t) {
        f32x4  na[4];
        bf16x8 nbh[4], nbl[4];
        if (t + 1 < T) {
            const char* p0 = s0 + (long)(t + 1) * 128;
            const char* p1 = s1 + (long)(t + 1) * 128;
            if (p0 > xmax) p0 = xmax;
            if (p1 > xmax) p1 = xmax;
            na[0] = *(const f32x4*)p0; na[1] = *(const f32x4*)(p0 + 16);
            na[2] = *(const f32x4*)p1; na[3] = *(const f32x4*)(p1 + 16);
            const unsigned short* ph = bp_h + (t + 1) * 32;
            const unsigned short* pl = bp_l + (t + 1) * 32;
#pragma unroll
            for (int nt = 0; nt < 4; ++nt) {
                nbh[nt] = *(const bf16x8*)(ph + (long)nt * 16 * KP);
                nbl[nt] = *(const bf16x8*)(pl + (long)nt * 16 * KP);
            }
        }

        bf16x8 ah0, al0, ah1, al1;
        split2x4(ca[0], ca[1], ah0, al0);
        split2x4(ca[2], ca[3], ah1, al1);

#pragma unroll
        for (int nt = 0; nt < 4; ++nt) {
            acc[0][nt] = __builtin_amdgcn_mfma_f32_16x16x32_bf16(al0, cbh[nt], acc[0][nt], 0, 0, 0);
            acc[0][nt] = __builtin_amdgcn_mfma_f32_16x16x32_bf16(ah0, cbl[nt], acc[0][nt], 0, 0, 0);
            acc[0][nt] = __builtin_amdgcn_mfma_f32_16x16x32_bf16(ah0, cbh[nt], acc[0][nt], 0, 0, 0);
            acc[1][nt] = __builtin_amdgcn_mfma_f32_16x16x32_bf16(al1, cbh[nt], acc[1][nt], 0, 0, 0);
            acc[1][nt] = __builtin_amdgcn_mfma_f32_16x16x32_bf16(ah1, cbl[nt], acc[1][nt], 0, 0, 0);
            acc[1][nt] = __builtin_amdgcn_mfma_f32_16x16x32_bf16(ah1, cbh[nt], acc[1][nt], 0, 0, 0);
        }

        if (t + 1 < T) {
#pragma unroll
            for (int i = 0; i < 4; ++i) { ca[i] = na[i]; cbh[i] = nbh[i]; cbl[i] = nbl[i]; }
        }
    }

    // epilogue: C/D layout: col = lane&15, row = (lane>>4)*4 + reg; store bf16
#pragma unroll
    for (int mt = 0; mt < 2; ++mt)
#pragma unroll
        for (int nt = 0; nt < 4; ++nt) {
            int coln = nt * 16 + l15;
#pragma unroll
            for (int rr = 0; rr < 4; ++rr) {
                long grow = wrow + mt * 16 + lhi * 4 + rr;
                if (grow < N_NODES)
                    h[grow * 64 + coln] = f2bf_rne(acc[mt][nt][rr]);
            }
        }
}

// ---------------- pull aggregation, 4 edges/wave + bias + BN + ReLU ------------
// lane = (edge slot e4 = lane>>4, col quad c4 = lane&15); each lane gathers
// 8B (4 bf16 cols) of h[src]; butterfly-reduce over e4; lanes 0..15 finish.
__global__ __launch_bounds__(256) void k_agg_bn_relu(
        const unsigned short* __restrict__ h, const int* __restrict__ rowptr,
        const int* __restrict__ degi, const int* __restrict__ col,
        const float* __restrict__ valn, const float* __restrict__ dis,
        const float* __restrict__ bias, const float* __restrict__ g,
        const float* __restrict__ be, const float* __restrict__ m,
        const float* __restrict__ v, float* __restrict__ out) {
    int node = blockIdx.x * 4 + (threadIdx.x >> 6);
    if (node >= N_NODES) return;
    const int lane = threadIdx.x & 63;
    const int e4 = lane >> 4, c4 = lane & 15;

    const int start = rowptr[node];
    const int cnt   = degi[node];

    float a0 = 0.f, a1 = 0.f, a2 = 0.f, a3 = 0.f;

    auto batch = [&](int j) {
        int jj = j + e4;
        bool valid = jj < cnt;
        int   s = valid ? col[start + jj] : 0;
        float w = valid ? valn[start + jj] : 0.0f;
        uint2 hv = *(const uint2*)(h + (long)s * 64 + c4 * 4);
        a0 += __uint_as_float(hv.x << 16) * w;
        a1 += __uint_as_float(hv.x & 0xffff0000u) * w;
        a2 += __uint_as_float(hv.y << 16) * w;
        a3 += __uint_as_float(hv.y & 0xffff0000u) * w;
    };

    int j = 0;
    for (; j + 4 < cnt; j += 8) { batch(j); batch(j + 4); }
    if (j < cnt) batch(j);

    a0 += __shfl_xor(a0, 16); a0 += __shfl_xor(a0, 32);
    a1 += __shfl_xor(a1, 16); a1 += __shfl_xor(a1, 32);
    a2 += __shfl_xor(a2, 16); a2 += __shfl_xor(a2, 32);
    a3 += __shfl_xor(a3, 16); a3 += __shfl_xor(a3, 32);

    if (e4 == 0) {
        float d = dis[node], d2 = d * d;
        uint2 sv = *(const uint2*)(h + (long)node * 64 + c4 * 4);
        float4 bb = *(const float4*)(bias + c4 * 4);
        float4 mm = *(const float4*)(m + c4 * 4);
        float4 vv = *(const float4*)(v + c4 * 4);
        float4 gg = *(const float4*)(g + c4 * 4);
        float4 ee = *(const float4*)(be + c4 * 4);
        float r0 = a0 + __uint_as_float(sv.x << 16) * d2 + bb.x;
        float r1 = a1 + __uint_as_float(sv.x & 0xffff0000u) * d2 + bb.y;
        float r2 = a2 + __uint_as_float(sv.y << 16) * d2 + bb.z;
        float r3 = a3 + __uint_as_float(sv.y & 0xffff0000u) * d2 + bb.w;
        r0 = fmaxf((r0 - mm.x) * rsqrtf(vv.x + BN_EPS) * gg.x + ee.x, 0.f);
        r1 = fmaxf((r1 - mm.y) * rsqrtf(vv.y + BN_EPS) * gg.y + ee.y, 0.f);
        r2 = fmaxf((r2 - mm.z) * rsqrtf(vv.z + BN_EPS) * gg.z + ee.z, 0.f);
        r3 = fmaxf((r3 - mm.w) * rsqrtf(vv.w + BN_EPS) * gg.w + ee.w, 0.f);
        *(float4*)(out + (long)node * 64 + c4 * 4) = make_float4(r0, r1, r2, r3);
    }
}

// ---------------- pull aggregation + bias + log_softmax (40 valid cols) -------
__global__ __launch_bounds__(256) void k_agg_lsm(
        const unsigned short* __restrict__ h, const int* __restrict__ rowptr,
        const int* __restrict__ degi, const int* __restrict__ col,
        const float* __restrict__ valn, const float* __restrict__ dis,
        const float* __restrict__ bias, float* __restrict__ out) {
    int node = blockIdx.x * 4 + (threadIdx.x >> 6);
    if (node >= N_NODES) return;
    const int lane = threadIdx.x & 63;
    const int e4 = lane >> 4, c4 = lane & 15;

    const int start = rowptr[node];
    const int cnt   = degi[node];

    float a0 = 0.f, a1 = 0.f, a2 = 0.f, a3 = 0.f;

    auto batch = [&](int j) {
        int jj = j + e4;
        bool valid = jj < cnt;
        int   s = valid ? col[start + jj] : 0;
        float w = valid ? valn[start + jj] : 0.0f;
        uint2 hv = *(const uint2*)(h + (long)s * 64 + c4 * 4);
        a0 += __uint_as_float(hv.x << 16) * w;
        a1 += __uint_as_float(hv.x & 0xffff0000u) * w;
        a2 += __uint_as_float(hv.y << 16) * w;
        a3 += __uint_as_float(hv.y & 0xffff0000u) * w;
    };

    int j = 0;
    for (; j + 4 < cnt; j += 8) { batch(j); batch(j + 4); }
    if (j < cnt) batch(j);

    a0 += __shfl_xor(a0, 16); a0 += __shfl_xor(a0, 32);
    a1 += __shfl_xor(a1, 16); a1 += __shfl_xor(a1, 32);
    a2 += __shfl_xor(a2, 16); a2 += __shfl_xor(a2, 32);
    a3 += __shfl_xor(a3, 16); a3 += __shfl_xor(a3, 32);

    const bool ok = c4 < 10;                      // cols c4*4..+3 all < 40
    float d = dis[node], d2 = d * d;
    uint2 sv = *(const uint2*)(h + (long)node * 64 + c4 * 4);
    float4 bb = ok ? *(const float4*)(bias + c4 * 4) : make_float4(0.f, 0.f, 0.f, 0.f);
    float v0 = a0 + __uint_as_float(sv.x << 16) * d2 + bb.x;
    float v1 = a1 + __uint_as_float(sv.x & 0xffff0000u) * d2 + bb.y;
    float v2 = a2 + __uint_as_float(sv.y << 16) * d2 + bb.z;
    float v3 = a3 + __uint_as_float(sv.y & 0xffff0000u) * d2 + bb.w;

    float mx = ok ? fmaxf(fmaxf(v0, v1), fmaxf(v2, v3)) : -INFINITY;
#pragma unroll
    for (int o = 1; o < 16; o <<= 1) mx = fmaxf(mx, __shfl_xor(mx, o));
    float es = ok ? (expf(v0 - mx) + expf(v1 - mx) + expf(v2 - mx) + expf(v3 - mx)) : 0.f;
#pragma unroll
    for (int o = 1; o < 16; o <<= 1) es += __shfl_xor(es, o);
    float ls = logf(es);

    if (e4 == 0 && ok)
        *(float4*)(out + (long)node * 40 + c4 * 4) =
            make_float4(v0 - mx - ls, v1 - mx - ls, v2 - mx - ls, v3 - mx - ls);
}

extern "C" void kernel_launch(void* const* d_in, const int* in_sizes, int n_in,
                              void* d_out, int out_size, void* d_ws, size_t ws_size,
                              hipStream_t stream) {
    const float* x   = (const float*)d_in[0];
    const int*   ei  = (const int*)d_in[1];
    const float* W1  = (const float*)d_in[2];
    const float* b1  = (const float*)d_in[3];
    const float* g1  = (const float*)d_in[4];
    const float* be1 = (const float*)d_in[5];
    const float* m1  = (const float*)d_in[6];
    const float* v1  = (const float*)d_in[7];
    const float* W2  = (const float*)d_in[8];
    const float* b2  = (const float*)d_in[9];
    const float* g2  = (const float*)d_in[10];
    const float* be2 = (const float*)d_in[11];
    const float* m2  = (const float*)d_in[12];
    const float* v2  = (const float*)d_in[13];
    const float* W3  = (const float*)d_in[14];
    const float* b3  = (const float*)d_in[15];
    float* out = (float*)d_out;

    // workspace layout (16B-aligned slabs)
    float* ws        = (float*)d_ws;
    float* dis       = ws;                            // 100096
    int*   degi      = (int*)(ws + 100096);           // 100096
    int*   cursor    = degi + 100096;                 // 100096
    int*   rowptr    = cursor + 100096;               // 100096
    int*   blocksum  = rowptr + 100096;               // 128
    int*   blockbase = blocksum + 128;                // 128
    int*   col       = blockbase + 128;               // 1.6M
    float* valn      = (float*)(col + N_EDGES);       // 1.6M
    unsigned short* bufH = (unsigned short*)(valn + N_EDGES);   // N*64 bf16
    float* bufA      = (float*)(bufH + (long)N_NODES * HID);    // N*64 fp32
    unsigned short* wt1_hi = (unsigned short*)(bufA + (long)N_NODES * HID); // 64*512
    unsigned short* wt1_lo = wt1_hi + 64 * 512;
    unsigned short* wt2_hi = wt1_lo + 64 * 512;       // 64*64
    unsigned short* wt2_lo = wt2_hi + 64 * 64;
    unsigned short* wt3_hi = wt2_lo + 64 * 64;        // 64*64
    unsigned short* wt3_lo = wt3_hi + 64 * 64;

    // ---- CSR build ----
    k_zero2<<<cdiv(N_NODES, 256), 256, 0, stream>>>(degi, cursor);
    k_count_deg<<<cdiv(N_EDGES, 256), 256, 0, stream>>>(ei, degi);
    k_dis<<<cdiv(N_NODES, 256), 256, 0, stream>>>(degi, dis);
    k_scan1<<<SCAN_NB, 256, 0, stream>>>(degi, rowptr, blocksum);
    k_scan2<<<1, 128, 0, stream>>>(blocksum, blockbase);
    k_scan3<<<SCAN_NB, 256, 0, stream>>>(rowptr, blockbase);
    k_permute<<<cdiv(N_EDGES, 256), 256, 0, stream>>>(ei, rowptr, cursor, dis, col, valn);

    // ---- weight preconvert (hi/lo bf16, transposed, zero-padded) ----
    k_convW<IN_DIM, HID, 512><<<(64 * 512) / 256, 256, 0, stream>>>(W1, wt1_hi, wt1_lo);
    k_convW<HID, HID, 64><<<(64 * 64) / 256, 256, 0, stream>>>(W2, wt2_hi, wt2_lo);
    k_convW<HID, OUT_DIM, 64><<<(64 * 64) / 256, 256, 0, stream>>>(W3, wt3_hi, wt3_lo);

    const int gemm_grid = cdiv(N_NODES, 128);   // 4 waves x 32 rows
    const int agg_grid  = cdiv(N_NODES, 4);     // 4 waves x 1 node

    // ---- layer 1: 500 -> 64 ----
    k_gemm_mfma<IN_DIM, 512><<<gemm_grid, 256, 0, stream>>>(x, wt1_hi, wt1_lo, bufH);
    k_agg_bn_relu<<<agg_grid, 256, 0, stream>>>(bufH, rowptr, degi, col, valn,
                                                dis, b1, g1, be1, m1, v1, bufA);

    // ---- layer 2: 64 -> 64 ----
    k_gemm_mfma<HID, 64><<<gemm_grid, 256, 0, stream>>>(bufA, wt2_hi, wt2_lo, bufH);
    k_agg_bn_relu<<<agg_grid, 256, 0, stream>>>(bufH, rowptr, degi, col, valn,
                                                dis, b2, g2, be2, m2, v2, bufA);

    // ---- layer 3: 64 -> 40 (stored 64-wide, cols 40..63 zero) ----
    k_gemm_mfma<HID, 64><<<gemm_grid, 256, 0, stream>>>(bufA, wt3_hi, wt3_lo, bufH);
    k_agg_lsm<<<agg_grid, 256, 0, stream>>>(bufH, rowptr, degi, col, valn,
                                            dis, b3, out);
}

// Round 10
// 474.780 us; speedup vs baseline: 1.2126x; 1.0388x over previous
//
#include <hip/hip_runtime.h>
#include <math.h>

#define N_NODES 100000
#define N_EDGES 1600000
#define IN_DIM  500
#define HID     64
#define OUT_DIM 40
#define BN_EPS  1e-5f
#define SCAN_NB 98          // ceil(100000 / 1024)
#define NTILE   6250        // N_NODES / 16 (exact)

typedef __attribute__((ext_vector_type(8))) short bf16x8;
typedef __attribute__((ext_vector_type(4))) float f32x4;

static inline int cdiv(long a, int b) { return (int)((a + b - 1) / b); }

__device__ inline unsigned short f2bf_rne(float f) {
    unsigned int u = __float_as_uint(f);
    unsigned int r = (u + 0x7FFFu + ((u >> 16) & 1u)) >> 16;
    return (unsigned short)r;
}
__device__ inline float bf2f(unsigned short h) {
    return __uint_as_float(((unsigned int)h) << 16);
}

// ---------------- zero int scratch ----------------
__global__ void k_zero2(int* a, int* b) {
    int i = blockIdx.x * 256 + threadIdx.x;
    if (i < N_NODES) { a[i] = 0; b[i] = 0; }
}

// ---------------- integer in-degree ----------------
__global__ void k_count_deg(const int* __restrict__ ei, int* degi) {
    int e = blockIdx.x * 256 + threadIdx.x;
    if (e < N_EDGES) atomicAdd(&degi[ei[N_EDGES + e]], 1);
}

__global__ void k_dis(const int* __restrict__ degi, float* dis) {
    int i = blockIdx.x * 256 + threadIdx.x;
    if (i < N_NODES) dis[i] = rsqrtf((float)degi[i] + 1.0f);
}

// ---------------- exclusive scan (3 kernels) ----------------
__global__ void k_scan1(const int* __restrict__ degi, int* __restrict__ rowptr,
                        int* __restrict__ blocksum) {
    __shared__ int sd[256];
    int tid = threadIdx.x;
    int base = blockIdx.x * 1024 + tid * 4;
    int v0 = (base + 0 < N_NODES) ? degi[base + 0] : 0;
    int v1 = (base + 1 < N_NODES) ? degi[base + 1] : 0;
    int v2 = (base + 2 < N_NODES) ? degi[base + 2] : 0;
    int v3 = (base + 3 < N_NODES) ? degi[base + 3] : 0;
    int s = v0 + v1 + v2 + v3;
    sd[tid] = s;
    __syncthreads();
    for (int off = 1; off < 256; off <<= 1) {
        int t = (tid >= off) ? sd[tid - off] : 0;
        __syncthreads();
        sd[tid] += t;
        __syncthreads();
    }
    int excl = sd[tid] - s;
    if (base + 0 < N_NODES) rowptr[base + 0] = excl;
    if (base + 1 < N_NODES) rowptr[base + 1] = excl + v0;
    if (base + 2 < N_NODES) rowptr[base + 2] = excl + v0 + v1;
    if (base + 3 < N_NODES) rowptr[base + 3] = excl + v0 + v1 + v2;
    if (tid == 255) blocksum[blockIdx.x] = sd[255];
}

__global__ void k_scan2(int* __restrict__ blocksum, int* __restrict__ blockbase) {
    __shared__ int sd[128];
    int tid = threadIdx.x;
    int v = (tid < SCAN_NB) ? blocksum[tid] : 0;
    sd[tid] = v;
    __syncthreads();
    for (int off = 1; off < 128; off <<= 1) {
        int t = (tid >= off) ? sd[tid - off] : 0;
        __syncthreads();
        sd[tid] += t;
        __syncthreads();
    }
    if (tid < SCAN_NB) blockbase[tid] = sd[tid] - v;
}

__global__ void k_scan3(int* __restrict__ rowptr, const int* __restrict__ blockbase) {
    int add = blockbase[blockIdx.x];
    int base = blockIdx.x * 1024 + threadIdx.x * 4;
#pragma unroll
    for (int i = 0; i < 4; ++i)
        if (base + i < N_NODES) rowptr[base + i] += add;
}

// ---------------- CSR permute: group edges by dst ----------------
__global__ void k_permute(const int* __restrict__ ei, const int* __restrict__ rowptr,
                          int* __restrict__ cursor, const float* __restrict__ dis,
                          int* __restrict__ col, float* __restrict__ valn) {
    int e = blockIdx.x * 256 + threadIdx.x;
    if (e >= N_EDGES) return;
    int s = ei[e];
    int d = ei[N_EDGES + e];
    int pos = rowptr[d] + atomicAdd(&cursor[d], 1);
    col[pos]  = s;
    valn[pos] = dis[s] * dis[d];
}

// ---------------- weight pack: W[K,F] -> wb[(t*4+nt)*64+lane][8] bf16 -------
// Fragment order: n = nt*16 + (lane&15), k = t*32 + (lane>>4)*8 + j.
template <int K, int F, int T>
__global__ void k_convWp(const float* __restrict__ W, unsigned short* __restrict__ wb) {
    int idx = blockIdx.x * 256 + threadIdx.x;
    if (idx >= T * 2048) return;
    int j    = idx & 7;
    int lane = (idx >> 3) & 63;
    int q    = idx >> 9;             // t*4 + nt
    int t    = q >> 2, nt = q & 3;
    int n = nt * 16 + (lane & 15);
    int k = t * 32 + ((lane >> 4) << 3) + j;
    float v = (k < K && n < F) ? W[(long)k * F + n] : 0.f;
    wb[idx] = f2bf_rne(v);
}

// ---------------- x transpose+pack: x[N,500] fp32 -> xp[rt][t][lane][8] bf16 -
// Coalesced row reads -> LDS (bf16, padded stride) -> contiguous packed writes.
__global__ __launch_bounds__(256) void k_xpose(const float* __restrict__ x,
                                               unsigned short* __restrict__ xp) {
    __shared__ unsigned short l[16 * 520];   // 16 rows x 512 k, stride 520 (1040 B)
    const int rt = blockIdx.x;
    const int tid = threadIdx.x;

    // phase 1: read 16 rows x 500 fp32 coalesced, convert bf16, pad k to 512
#pragma unroll
    for (int it = 0; it < 8; ++it) {
        int slot = it * 256 + tid;           // (row, kq): 16 x 128 f32x4-slots
        int row = slot >> 7, kq = slot & 127;
        float4 v = make_float4(0.f, 0.f, 0.f, 0.f);
        if (kq < 125)
            v = *reinterpret_cast<const float4*>(x + ((long)rt * 16 + row) * IN_DIM + kq * 4);
        unsigned int u0 = (unsigned int)f2bf_rne(v.x) | ((unsigned int)f2bf_rne(v.y) << 16);
        unsigned int u1 = (unsigned int)f2bf_rne(v.z) | ((unsigned int)f2bf_rne(v.w) << 16);
        *reinterpret_cast<uint2*>(&l[row * 520 + kq * 4]) = make_uint2(u0, u1);
    }
    __syncthreads();

    // phase 2: emit fragment-packed: for (t, lane): row=lane&15, k=t*32+(lane>>4)*8
#pragma unroll
    for (int it = 0; it < 4; ++it) {
        int flat = it * 256 + tid;           // 16 steps x 64 lanes
        int t = flat >> 6, lane = flat & 63;
        const uint4 v = *reinterpret_cast<const uint4*>(
            &l[(lane & 15) * 520 + t * 32 + (lane >> 4) * 8]);
        *reinterpret_cast<uint4*>(xp + (((long)rt * 16 + t) * 64 + lane) * 8) = v;
    }
}

// ---------------- packed MFMA GEMM: every load = 64 lanes x 16 B contiguous --
// h_bf16[N,64] = A @ W. A from xp (fragment-packed bf16), B from wb (packed).
// One wave per 16-row tile; T k-steps; 4 MFMA + 5 loads per step; reg prefetch.
template <int T>
__global__ __launch_bounds__(256) void k_gemm_packed(
        const unsigned short* __restrict__ xp,
        const unsigned short* __restrict__ wb,
        unsigned short* __restrict__ h) {
    const int tid  = threadIdx.x;
    const int wid  = tid >> 6;
    const int lane = tid & 63;
    const int rt   = blockIdx.x * 4 + wid;
    if (rt >= NTILE) return;

    const bf16x8* ap = reinterpret_cast<const bf16x8*>(xp) + (long)rt * T * 64 + lane;
    const bf16x8* bp = reinterpret_cast<const bf16x8*>(wb) + lane;

    f32x4 acc[4];
#pragma unroll
    for (int nt = 0; nt < 4; ++nt) acc[nt] = (f32x4){0.f, 0.f, 0.f, 0.f};

    bf16x8 ca = ap[0];
    bf16x8 cb0 = bp[0], cb1 = bp[64], cb2 = bp[128], cb3 = bp[192];

    for (int t = 0; t < T; ++t) {
        bf16x8 na, nb0, nb1, nb2, nb3;
        if (t + 1 < T) {
            na  = ap[(t + 1) * 64];
            nb0 = bp[((t + 1) * 4 + 0) * 64];
            nb1 = bp[((t + 1) * 4 + 1) * 64];
            nb2 = bp[((t + 1) * 4 + 2) * 64];
            nb3 = bp[((t + 1) * 4 + 3) * 64];
        }
        acc[0] = __builtin_amdgcn_mfma_f32_16x16x32_bf16(ca, cb0, acc[0], 0, 0, 0);
        acc[1] = __builtin_amdgcn_mfma_f32_16x16x32_bf16(ca, cb1, acc[1], 0, 0, 0);
        acc[2] = __builtin_amdgcn_mfma_f32_16x16x32_bf16(ca, cb2, acc[2], 0, 0, 0);
        acc[3] = __builtin_amdgcn_mfma_f32_16x16x32_bf16(ca, cb3, acc[3], 0, 0, 0);
        if (t + 1 < T) { ca = na; cb0 = nb0; cb1 = nb1; cb2 = nb2; cb3 = nb3; }
    }

    // C/D layout: col = lane&15 (+nt*16), row = (lane>>4)*4 + reg; store bf16
    const int l15 = lane & 15, lhi = lane >> 4;
#pragma unroll
    for (int nt = 0; nt < 4; ++nt) {
        int coln = nt * 16 + l15;
#pragma unroll
        for (int rr = 0; rr < 4; ++rr) {
            long grow = (long)rt * 16 + lhi * 4 + rr;
            h[grow * 64 + coln] = f2bf_rne(acc[nt][rr]);
        }
    }
}

// ---------------- pull aggregation + bias + BN + ReLU -> packed bf16 A -------
// lane = (edge slot e4 = lane>>4, col quad c4 = lane&15); gathers 8 B of
// h[src]; butterfly over e4; lanes e4==0 write the next GEMM's fragment-packed
// A layout (T=2): row=node, col c = 4*c4+{0..3} -> t=c4>>3, lhi=(c4>>1)&3.
__global__ __launch_bounds__(256) void k_agg_bn_relu(
        const unsigned short* __restrict__ h, const int* __restrict__ rowptr,
        const int* __restrict__ degi, const int* __restrict__ col,
        const float* __restrict__ valn, const float* __restrict__ dis,
        const float* __restrict__ bias, const float* __restrict__ g,
        const float* __restrict__ be, const float* __restrict__ m,
        const float* __restrict__ v, unsigned short* __restrict__ xp_out) {
    int node = blockIdx.x * 4 + (threadIdx.x >> 6);
    if (node >= N_NODES) return;
    const int lane = threadIdx.x & 63;
    const int e4 = lane >> 4, c4 = lane & 15;

    const int start = rowptr[node];
    const int cnt   = degi[node];

    float a0 = 0.f, a1 = 0.f, a2 = 0.f, a3 = 0.f;

    auto batch = [&](int j) {
        int jj = j + e4;
        bool valid = jj < cnt;
        int   s = valid ? col[start + jj] : 0;
        float w = valid ? valn[start + jj] : 0.0f;
        uint2 hv = *(const uint2*)(h + (long)s * 64 + c4 * 4);
        a0 += __uint_as_float(hv.x << 16) * w;
        a1 += __uint_as_float(hv.x & 0xffff0000u) * w;
        a2 += __uint_as_float(hv.y << 16) * w;
        a3 += __uint_as_float(hv.y & 0xffff0000u) * w;
    };

    int j = 0;
    for (; j + 4 < cnt; j += 8) { batch(j); batch(j + 4); }
    if (j < cnt) batch(j);

    a0 += __shfl_xor(a0, 16); a0 += __shfl_xor(a0, 32);
    a1 += __shfl_xor(a1, 16); a1 += __shfl_xor(a1, 32);
    a2 += __shfl_xor(a2, 16); a2 += __shfl_xor(a2, 32);
    a3 += __shfl_xor(a3, 16); a3 += __shfl_xor(a3, 32);

    if (e4 == 0) {
        float d = dis[node], d2 = d * d;
        uint2 sv = *(const uint2*)(h + (long)node * 64 + c4 * 4);
        float4 bb = *(const float4*)(bias + c4 * 4);
        float4 mm = *(const float4*)(m + c4 * 4);
        float4 vv = *(const float4*)(v + c4 * 4);
        float4 gg = *(const float4*)(g + c4 * 4);
        float4 ee = *(const float4*)(be + c4 * 4);
        float r0 = a0 + __uint_as_float(sv.x << 16) * d2 + bb.x;
        float r1 = a1 + __uint_as_float(sv.x & 0xffff0000u) * d2 + bb.y;
        float r2 = a2 + __uint_as_float(sv.y << 16) * d2 + bb.z;
        float r3 = a3 + __uint_as_float(sv.y & 0xffff0000u) * d2 + bb.w;
        r0 = fmaxf((r0 - mm.x) * rsqrtf(vv.x + BN_EPS) * gg.x + ee.x, 0.f);
        r1 = fmaxf((r1 - mm.y) * rsqrtf(vv.y + BN_EPS) * gg.y + ee.y, 0.f);
        r2 = fmaxf((r2 - mm.z) * rsqrtf(vv.z + BN_EPS) * gg.z + ee.z, 0.f);
        r3 = fmaxf((r3 - mm.w) * rsqrtf(vv.w + BN_EPS) * gg.w + ee.w, 0.f);

        // fragment-packed store (T=2): idx = ((rt*2+t)*64 + lhi*16 + n16)*8 + joff
        int n16 = node & 15, rt2 = node >> 4;
        int t = c4 >> 3, lh = (c4 >> 1) & 3, joff = (c4 & 1) * 4;
        long base = (((long)rt2 * 2 + t) * 64 + lh * 16 + n16) * 8 + joff;
        unsigned int u0 = (unsigned int)f2bf_rne(r0) | ((unsigned int)f2bf_rne(r1) << 16);
        unsigned int u1 = (unsigned int)f2bf_rne(r2) | ((unsigned int)f2bf_rne(r3) << 16);
        *reinterpret_cast<uint2*>(xp_out + base) = make_uint2(u0, u1);
    }
}

// ---------------- pull aggregation + bias + log_softmax (40 valid cols) -------
__global__ __launch_bounds__(256) void k_agg_lsm(
        const unsigned short* __restrict__ h, const int* __restrict__ rowptr,
        const int* __restrict__ degi, const int* __restrict__ col,
        const float* __restrict__ valn, const float* __restrict__ dis,
        const float* __restrict__ bias, float* __restrict__ out) {
    int node = blockIdx.x * 4 + (threadIdx.x >> 6);
    if (node >= N_NODES) return;
    const int lane = threadIdx.x & 63;
    const int e4 = lane >> 4, c4 = lane & 15;

    const int start = rowptr[node];
    const int cnt   = degi[node];

    float a0 = 0.f, a1 = 0.f, a2 = 0.f, a3 = 0.f;

    auto batch = [&](int j) {
        int jj = j + e4;
        bool valid = jj < cnt;
        int   s = valid ? col[start + jj] : 0;
        float w = valid ? valn[start + jj] : 0.0f;
        uint2 hv = *(const uint2*)(h + (long)s * 64 + c4 * 4);
        a0 += __uint_as_float(hv.x << 16) * w;
        a1 += __uint_as_float(hv.x & 0xffff0000u) * w;
        a2 += __uint_as_float(hv.y << 16) * w;
        a3 += __uint_as_float(hv.y & 0xffff0000u) * w;
    };

    int j = 0;
    for (; j + 4 < cnt; j += 8) { batch(j); batch(j + 4); }
    if (j < cnt) batch(j);

    a0 += __shfl_xor(a0, 16); a0 += __shfl_xor(a0, 32);
    a1 += __shfl_xor(a1, 16); a1 += __shfl_xor(a1, 32);
    a2 += __shfl_xor(a2, 16); a2 += __shfl_xor(a2, 32);
    a3 += __shfl_xor(a3, 16); a3 += __shfl_xor(a3, 32);

    const bool ok = c4 < 10;                      // cols c4*4..+3 all < 40
    float d = dis[node], d2 = d * d;
    uint2 sv = *(const uint2*)(h + (long)node * 64 + c4 * 4);
    float4 bb = ok ? *(const float4*)(bias + c4 * 4) : make_float4(0.f, 0.f, 0.f, 0.f);
    float v0 = a0 + __uint_as_float(sv.x << 16) * d2 + bb.x;
    float v1 = a1 + __uint_as_float(sv.x & 0xffff0000u) * d2 + bb.y;
    float v2 = a2 + __uint_as_float(sv.y << 16) * d2 + bb.z;
    float v3 = a3 + __uint_as_float(sv.y & 0xffff0000u) * d2 + bb.w;

    float mx = ok ? fmaxf(fmaxf(v0, v1), fmaxf(v2, v3)) : -INFINITY;
#pragma unroll
    for (int o = 1; o < 16; o <<= 1) mx = fmaxf(mx, __shfl_xor(mx, o));
    float es = ok ? (expf(v0 - mx) + expf(v1 - mx) + expf(v2 - mx) + expf(v3 - mx)) : 0.f;
#pragma unroll
    for (int o = 1; o < 16; o <<= 1) es += __shfl_xor(es, o);
    float ls = logf(es);

    if (e4 == 0 && ok)
        *(float4*)(out + (long)node * 40 + c4 * 4) =
            make_float4(v0 - mx - ls, v1 - mx - ls, v2 - mx - ls, v3 - mx - ls);
}

extern "C" void kernel_launch(void* const* d_in, const int* in_sizes, int n_in,
                              void* d_out, int out_size, void* d_ws, size_t ws_size,
                              hipStream_t stream) {
    const float* x   = (const float*)d_in[0];
    const int*   ei  = (const int*)d_in[1];
    const float* W1  = (const float*)d_in[2];
    const float* b1  = (const float*)d_in[3];
    const float* g1  = (const float*)d_in[4];
    const float* be1 = (const float*)d_in[5];
    const float* m1  = (const float*)d_in[6];
    const float* v1  = (const float*)d_in[7];
    const float* W2  = (const float*)d_in[8];
    const float* b2  = (const float*)d_in[9];
    const float* g2  = (const float*)d_in[10];
    const float* be2 = (const float*)d_in[11];
    const float* m2  = (const float*)d_in[12];
    const float* v2  = (const float*)d_in[13];
    const float* W3  = (const float*)d_in[14];
    const float* b3  = (const float*)d_in[15];
    float* out = (float*)d_out;

    // workspace layout (units: floats from base; all 16B-aligned)
    float* ws        = (float*)d_ws;
    float* dis       = ws;                            // 100096
    int*   degi      = (int*)(ws + 100096);
    int*   cursor    = (int*)(ws + 200192);
    int*   rowptr    = (int*)(ws + 300288);
    int*   blocksum  = (int*)(ws + 400384);           // 128
    int*   blockbase = (int*)(ws + 400512);           // 128
    int*   col       = (int*)(ws + 400640);           // 1.6M
    float* valn      = ws + 2000640;                  // 1.6M
    unsigned short* bufH = (unsigned short*)(ws + 3600640);    // N*64 bf16
    unsigned short* xp1  = (unsigned short*)(ws + 6800640);    // NTILE*16*512 bf16
    unsigned short* xp2  = (unsigned short*)(ws + 32400640);   // NTILE*2*512 bf16
    unsigned short* xp3  = (unsigned short*)(ws + 35600640);
    unsigned short* wb1  = (unsigned short*)(ws + 38800640);   // 32768
    unsigned short* wb2  = (unsigned short*)(ws + 38817024);   // 4096
    unsigned short* wb3  = (unsigned short*)(ws + 38819072);   // 4096

    // ---- CSR build ----
    k_zero2<<<cdiv(N_NODES, 256), 256, 0, stream>>>(degi, cursor);
    k_count_deg<<<cdiv(N_EDGES, 256), 256, 0, stream>>>(ei, degi);
    k_dis<<<cdiv(N_NODES, 256), 256, 0, stream>>>(degi, dis);
    k_scan1<<<SCAN_NB, 256, 0, stream>>>(degi, rowptr, blocksum);
    k_scan2<<<1, 128, 0, stream>>>(blocksum, blockbase);
    k_scan3<<<SCAN_NB, 256, 0, stream>>>(rowptr, blockbase);
    k_permute<<<cdiv(N_EDGES, 256), 256, 0, stream>>>(ei, rowptr, cursor, dis, col, valn);

    // ---- weight pack (fragment-ordered bf16) ----
    k_convWp<IN_DIM, HID, 16><<<128, 256, 0, stream>>>(W1, wb1);
    k_convWp<HID, HID, 2><<<16, 256, 0, stream>>>(W2, wb2);
    k_convWp<HID, OUT_DIM, 2><<<16, 256, 0, stream>>>(W3, wb3);

    // ---- x transpose+pack ----
    k_xpose<<<NTILE, 256, 0, stream>>>(x, xp1);

    const int gemm_grid = cdiv(NTILE, 4);
    const int agg_grid  = cdiv(N_NODES, 4);

    // ---- layer 1: 500 -> 64 ----
    k_gemm_packed<16><<<gemm_grid, 256, 0, stream>>>(xp1, wb1, bufH);
    k_agg_bn_relu<<<agg_grid, 256, 0, stream>>>(bufH, rowptr, degi, col, valn,
                                                dis, b1, g1, be1, m1, v1, xp2);

    // ---- layer 2: 64 -> 64 ----
    k_gemm_packed<2><<<gemm_grid, 256, 0, stream>>>(xp2, wb2, bufH);
    k_agg_bn_relu<<<agg_grid, 256, 0, stream>>>(bufH, rowptr, degi, col, valn,
                                                dis, b2, g2, be2, m2, v2, xp3);

    // ---- layer 3: 64 -> 40 (h stored 64-wide, cols 40..63 zero) ----
    k_gemm_packed<2><<<gemm_grid, 256, 0, stream>>>(xp3, wb3, bufH);
    k_agg_lsm<<<agg_grid, 256, 0, stream>>>(bufH, rowptr, degi, col, valn,
                                            dis, b3, out);
}

// Round 11
// 447.975 us; speedup vs baseline: 1.2851x; 1.0598x over previous
//
#include <hip/hip_runtime.h>
#include <math.h>

#define N_NODES 100000
#define N_EDGES 1600000
#define IN_DIM  500
#define HID     64
#define OUT_DIM 40
#define BN_EPS  1e-5f
#define SCAN_NB 98          // ceil(100000 / 1024)
#define NTILE   6250        // N_NODES / 16 (exact)

typedef __attribute__((ext_vector_type(8))) short bf16x8;
typedef __attribute__((ext_vector_type(4))) float f32x4;

static inline int cdiv(long a, int b) { return (int)((a + b - 1) / b); }

__device__ inline unsigned short f2bf_rne(float f) {
    unsigned int u = __float_as_uint(f);
    unsigned int r = (u + 0x7FFFu + ((u >> 16) & 1u)) >> 16;
    return (unsigned short)r;
}

// ---------------- zero int scratch ----------------
__global__ void k_zero2(int* a, int* b) {
    int i = blockIdx.x * 256 + threadIdx.x;
    if (i < N_NODES) { a[i] = 0; b[i] = 0; }
}

// ---------------- integer in-degree ----------------
__global__ void k_count_deg(const int* __restrict__ ei, int* degi) {
    int e = blockIdx.x * 256 + threadIdx.x;
    if (e < N_EDGES) atomicAdd(&degi[ei[N_EDGES + e]], 1);
}

__global__ void k_dis(const int* __restrict__ degi, float* dis) {
    int i = blockIdx.x * 256 + threadIdx.x;
    if (i < N_NODES) dis[i] = rsqrtf((float)degi[i] + 1.0f);
}

// ---------------- exclusive scan (3 kernels) ----------------
__global__ void k_scan1(const int* __restrict__ degi, int* __restrict__ rowptr,
                        int* __restrict__ blocksum) {
    __shared__ int sd[256];
    int tid = threadIdx.x;
    int base = blockIdx.x * 1024 + tid * 4;
    int v0 = (base + 0 < N_NODES) ? degi[base + 0] : 0;
    int v1 = (base + 1 < N_NODES) ? degi[base + 1] : 0;
    int v2 = (base + 2 < N_NODES) ? degi[base + 2] : 0;
    int v3 = (base + 3 < N_NODES) ? degi[base + 3] : 0;
    int s = v0 + v1 + v2 + v3;
    sd[tid] = s;
    __syncthreads();
    for (int off = 1; off < 256; off <<= 1) {
        int t = (tid >= off) ? sd[tid - off] : 0;
        __syncthreads();
        sd[tid] += t;
        __syncthreads();
    }
    int excl = sd[tid] - s;
    if (base + 0 < N_NODES) rowptr[base + 0] = excl;
    if (base + 1 < N_NODES) rowptr[base + 1] = excl + v0;
    if (base + 2 < N_NODES) rowptr[base + 2] = excl + v0 + v1;
    if (base + 3 < N_NODES) rowptr[base + 3] = excl + v0 + v1 + v2;
    if (tid == 255) blocksum[blockIdx.x] = sd[255];
}

__global__ void k_scan2(int* __restrict__ blocksum, int* __restrict__ blockbase) {
    __shared__ int sd[128];
    int tid = threadIdx.x;
    int v = (tid < SCAN_NB) ? blocksum[tid] : 0;
    sd[tid] = v;
    __syncthreads();
    for (int off = 1; off < 128; off <<= 1) {
        int t = (tid >= off) ? sd[tid - off] : 0;
        __syncthreads();
        sd[tid] += t;
        __syncthreads();
    }
    if (tid < SCAN_NB) blockbase[tid] = sd[tid] - v;
}

__global__ void k_scan3(int* __restrict__ rowptr, const int* __restrict__ blockbase) {
    int add = blockbase[blockIdx.x];
    int base = blockIdx.x * 1024 + threadIdx.x * 4;
#pragma unroll
    for (int i = 0; i < 4; ++i)
        if (base + i < N_NODES) rowptr[base + i] += add;
}

// ---------------- CSR permute: group edges by dst, packed meta ----------------
// epack[pos] = { src row byte offset (s*128), norm weight bits }
__global__ void k_permute(const int* __restrict__ ei, const int* __restrict__ rowptr,
                          int* __restrict__ cursor, const float* __restrict__ dis,
                          uint2* __restrict__ epack) {
    int e = blockIdx.x * 256 + threadIdx.x;
    if (e >= N_EDGES) return;
    int s = ei[e];
    int d = ei[N_EDGES + e];
    int pos = rowptr[d] + atomicAdd(&cursor[d], 1);
    epack[pos] = make_uint2((unsigned int)(s * 128),
                            __float_as_uint(dis[s] * dis[d]));
}

// ---------------- weight pack: W[K,F] -> wb[(t*4+nt)*64+lane][8] bf16 -------
template <int K, int F, int T>
__global__ void k_convWp(const float* __restrict__ W, unsigned short* __restrict__ wb) {
    int idx = blockIdx.x * 256 + threadIdx.x;
    if (idx >= T * 2048) return;
    int j    = idx & 7;
    int lane = (idx >> 3) & 63;
    int q    = idx >> 9;             // t*4 + nt
    int t    = q >> 2, nt = q & 3;
    int n = nt * 16 + (lane & 15);
    int k = t * 32 + ((lane >> 4) << 3) + j;
    float v = (k < K && n < F) ? W[(long)k * F + n] : 0.f;
    wb[idx] = f2bf_rne(v);
}

// ---------------- x transpose+pack: x[N,500] fp32 -> xp[rt][t][lane][8] bf16 -
__global__ __launch_bounds__(256) void k_xpose(const float* __restrict__ x,
                                               unsigned short* __restrict__ xp) {
    __shared__ unsigned short l[16 * 520];   // 16 rows x 512 k, stride 520
    const int rt = blockIdx.x;
    const int tid = threadIdx.x;

#pragma unroll
    for (int it = 0; it < 8; ++it) {
        int slot = it * 256 + tid;           // (row, kq): 16 x 128 f32x4-slots
        int row = slot >> 7, kq = slot & 127;
        float4 v = make_float4(0.f, 0.f, 0.f, 0.f);
        if (kq < 125)
            v = *reinterpret_cast<const float4*>(x + ((long)rt * 16 + row) * IN_DIM + kq * 4);
        unsigned int u0 = (unsigned int)f2bf_rne(v.x) | ((unsigned int)f2bf_rne(v.y) << 16);
        unsigned int u1 = (unsigned int)f2bf_rne(v.z) | ((unsigned int)f2bf_rne(v.w) << 16);
        *reinterpret_cast<uint2*>(&l[row * 520 + kq * 4]) = make_uint2(u0, u1);
    }
    __syncthreads();

#pragma unroll
    for (int it = 0; it < 4; ++it) {
        int flat = it * 256 + tid;           // 16 steps x 64 lanes
        int t = flat >> 6, lane = flat & 63;
        const uint4 v = *reinterpret_cast<const uint4*>(
            &l[(lane & 15) * 520 + t * 32 + (lane >> 4) * 8]);
        *reinterpret_cast<uint4*>(xp + (((long)rt * 16 + t) * 64 + lane) * 8) = v;
    }
}

// ---------------- packed MFMA GEMM: every load = 64 lanes x 16 B contiguous --
template <int T>
__global__ __launch_bounds__(256) void k_gemm_packed(
        const unsigned short* __restrict__ xp,
        const unsigned short* __restrict__ wb,
        unsigned short* __restrict__ h) {
    const int tid  = threadIdx.x;
    const int wid  = tid >> 6;
    const int lane = tid & 63;
    const int rt   = blockIdx.x * 4 + wid;
    if (rt >= NTILE) return;

    const bf16x8* ap = reinterpret_cast<const bf16x8*>(xp) + (long)rt * T * 64 + lane;
    const bf16x8* bp = reinterpret_cast<const bf16x8*>(wb) + lane;

    f32x4 acc[4];
#pragma unroll
    for (int nt = 0; nt < 4; ++nt) acc[nt] = (f32x4){0.f, 0.f, 0.f, 0.f};

    bf16x8 ca = ap[0];
    bf16x8 cb0 = bp[0], cb1 = bp[64], cb2 = bp[128], cb3 = bp[192];

    for (int t = 0; t < T; ++t) {
        bf16x8 na, nb0, nb1, nb2, nb3;
        if (t + 1 < T) {
            na  = ap[(t + 1) * 64];
            nb0 = bp[((t + 1) * 4 + 0) * 64];
            nb1 = bp[((t + 1) * 4 + 1) * 64];
            nb2 = bp[((t + 1) * 4 + 2) * 64];
            nb3 = bp[((t + 1) * 4 + 3) * 64];
        }
        acc[0] = __builtin_amdgcn_mfma_f32_16x16x32_bf16(ca, cb0, acc[0], 0, 0, 0);
        acc[1] = __builtin_amdgcn_mfma_f32_16x16x32_bf16(ca, cb1, acc[1], 0, 0, 0);
        acc[2] = __builtin_amdgcn_mfma_f32_16x16x32_bf16(ca, cb2, acc[2], 0, 0, 0);
        acc[3] = __builtin_amdgcn_mfma_f32_16x16x32_bf16(ca, cb3, acc[3], 0, 0, 0);
        if (t + 1 < T) { ca = na; cb0 = nb0; cb1 = nb1; cb2 = nb2; cb3 = nb3; }
    }

    const int l15 = lane & 15, lhi = lane >> 4;
#pragma unroll
    for (int nt = 0; nt < 4; ++nt) {
        int coln = nt * 16 + l15;
#pragma unroll
        for (int rr = 0; rr < 4; ++rr) {
            long grow = (long)rt * 16 + lhi * 4 + rr;
            h[grow * 64 + coln] = f2bf_rne(acc[nt][rr]);
        }
    }
}

// ---------------- pull aggregation (e8 x c8) + bias + BN + ReLU -> packed A ---
// lane = (edge slot e8 = lane>>3, col slice c8 = lane&7, 16 B = 8 cols/lane).
// One uint2 meta load + one uint4 gather per 8 edges; butterfly over e8.
__global__ __launch_bounds__(256) void k_agg_bn_relu(
        const unsigned short* __restrict__ h, const int* __restrict__ rowptr,
        const int* __restrict__ degi, const uint2* __restrict__ epack,
        const float* __restrict__ dis,
        const float* __restrict__ bias, const float* __restrict__ g,
        const float* __restrict__ be, const float* __restrict__ m,
        const float* __restrict__ v, unsigned short* __restrict__ xp_out) {
    int node = blockIdx.x * 4 + (threadIdx.x >> 6);
    if (node >= N_NODES) return;
    const int lane = threadIdx.x & 63;
    const int e8 = lane >> 3, c8 = lane & 7;

    const int start = rowptr[node];
    const int cnt   = degi[node];
    const uint2* ep = epack + start;
    const char*  hb = (const char*)h + c8 * 16;

    float a[8] = {0.f, 0.f, 0.f, 0.f, 0.f, 0.f, 0.f, 0.f};

    auto batch = [&](int j) {
        int jj = j + e8;
        bool valid = jj < cnt;
        uint2 mv = ep[valid ? jj : 0];
        float w = valid ? __uint_as_float(mv.y) : 0.0f;
        uint4 hv = *(const uint4*)(hb + mv.x);
        a[0] += __uint_as_float(hv.x << 16) * w;
        a[1] += __uint_as_float(hv.x & 0xffff0000u) * w;
        a[2] += __uint_as_float(hv.y << 16) * w;
        a[3] += __uint_as_float(hv.y & 0xffff0000u) * w;
        a[4] += __uint_as_float(hv.z << 16) * w;
        a[5] += __uint_as_float(hv.z & 0xffff0000u) * w;
        a[6] += __uint_as_float(hv.w << 16) * w;
        a[7] += __uint_as_float(hv.w & 0xffff0000u) * w;
    };

    int j = 0;
    for (; j + 8 < cnt; j += 16) { batch(j); batch(j + 8); }
    if (j < cnt) batch(j);

#pragma unroll
    for (int i = 0; i < 8; ++i) {
        a[i] += __shfl_xor(a[i], 8);
        a[i] += __shfl_xor(a[i], 16);
        a[i] += __shfl_xor(a[i], 32);
    }

    if (e8 == 0) {
        float d = dis[node], d2 = d * d;
        uint4 sv = *(const uint4*)((const char*)h + (long)node * 128 + c8 * 16);
        float sf[8] = {
            __uint_as_float(sv.x << 16), __uint_as_float(sv.x & 0xffff0000u),
            __uint_as_float(sv.y << 16), __uint_as_float(sv.y & 0xffff0000u),
            __uint_as_float(sv.z << 16), __uint_as_float(sv.z & 0xffff0000u),
            __uint_as_float(sv.w << 16), __uint_as_float(sv.w & 0xffff0000u)};
        float4 bb0 = *(const float4*)(bias + c8 * 8), bb1 = *(const float4*)(bias + c8 * 8 + 4);
        float4 mm0 = *(const float4*)(m + c8 * 8),    mm1 = *(const float4*)(m + c8 * 8 + 4);
        float4 vv0 = *(const float4*)(v + c8 * 8),    vv1 = *(const float4*)(v + c8 * 8 + 4);
        float4 gg0 = *(const float4*)(g + c8 * 8),    gg1 = *(const float4*)(g + c8 * 8 + 4);
        float4 ee0 = *(const float4*)(be + c8 * 8),   ee1 = *(const float4*)(be + c8 * 8 + 4);
        float bbv[8] = {bb0.x, bb0.y, bb0.z, bb0.w, bb1.x, bb1.y, bb1.z, bb1.w};
        float mmv[8] = {mm0.x, mm0.y, mm0.z, mm0.w, mm1.x, mm1.y, mm1.z, mm1.w};
        float vvv[8] = {vv0.x, vv0.y, vv0.z, vv0.w, vv1.x, vv1.y, vv1.z, vv1.w};
        float ggv[8] = {gg0.x, gg0.y, gg0.z, gg0.w, gg1.x, gg1.y, gg1.z, gg1.w};
        float eev[8] = {ee0.x, ee0.y, ee0.z, ee0.w, ee1.x, ee1.y, ee1.z, ee1.w};

        unsigned int u[4];
#pragma unroll
        for (int p = 0; p < 4; ++p) {
            float r0 = a[2 * p]     + sf[2 * p]     * d2 + bbv[2 * p];
            float r1 = a[2 * p + 1] + sf[2 * p + 1] * d2 + bbv[2 * p + 1];
            r0 = fmaxf((r0 - mmv[2 * p])     * rsqrtf(vvv[2 * p]     + BN_EPS) * ggv[2 * p]     + eev[2 * p],     0.f);
            r1 = fmaxf((r1 - mmv[2 * p + 1]) * rsqrtf(vvv[2 * p + 1] + BN_EPS) * ggv[2 * p + 1] + eev[2 * p + 1], 0.f);
            u[p] = (unsigned int)f2bf_rne(r0) | ((unsigned int)f2bf_rne(r1) << 16);
        }

        // fragment-packed store (T=2): cols c = c8*8 + 0..7 -> t=c8>>2, lh=c8&3
        int n16 = node & 15, rt2 = node >> 4;
        long base = (((long)rt2 * 2 + (c8 >> 2)) * 64 + (c8 & 3) * 16 + n16) * 8;
        *reinterpret_cast<uint4*>(xp_out + base) = make_uint4(u[0], u[1], u[2], u[3]);
    }
}

// ---------------- pull aggregation (e8 x c8) + bias + log_softmax -------------
__global__ __launch_bounds__(256) void k_agg_lsm(
        const unsigned short* __restrict__ h, const int* __restrict__ rowptr,
        const int* __restrict__ degi, const uint2* __restrict__ epack,
        const float* __restrict__ dis,
        const float* __restrict__ bias, float* __restrict__ out) {
    int node = blockIdx.x * 4 + (threadIdx.x >> 6);
    if (node >= N_NODES) return;
    const int lane = threadIdx.x & 63;
    const int e8 = lane >> 3, c8 = lane & 7;

    const int start = rowptr[node];
    const int cnt   = degi[node];
    const uint2* ep = epack + start;
    const char*  hb = (const char*)h + c8 * 16;

    float a[8] = {0.f, 0.f, 0.f, 0.f, 0.f, 0.f, 0.f, 0.f};

    auto batch = [&](int j) {
        int jj = j + e8;
        bool valid = jj < cnt;
        uint2 mv = ep[valid ? jj : 0];
        float w = valid ? __uint_as_float(mv.y) : 0.0f;
        uint4 hv = *(const uint4*)(hb + mv.x);
        a[0] += __uint_as_float(hv.x << 16) * w;
        a[1] += __uint_as_float(hv.x & 0xffff0000u) * w;
        a[2] += __uint_as_float(hv.y << 16) * w;
        a[3] += __uint_as_float(hv.y & 0xffff0000u) * w;
        a[4] += __uint_as_float(hv.z << 16) * w;
        a[5] += __uint_as_float(hv.z & 0xffff0000u) * w;
        a[6] += __uint_as_float(hv.w << 16) * w;
        a[7] += __uint_as_float(hv.w & 0xffff0000u) * w;
    };

    int j = 0;
    for (; j + 8 < cnt; j += 16) { batch(j); batch(j + 8); }
    if (j < cnt) batch(j);

#pragma unroll
    for (int i = 0; i < 8; ++i) {
        a[i] += __shfl_xor(a[i], 8);
        a[i] += __shfl_xor(a[i], 16);
        a[i] += __shfl_xor(a[i], 32);
    }

    const bool ok = c8 < 5;                     // cols c8*8..+7 all < 40
    float d = dis[node], d2 = d * d;
    uint4 sv = *(const uint4*)((const char*)h + (long)node * 128 + c8 * 16);
    float sf[8] = {
        __uint_as_float(sv.x << 16), __uint_as_float(sv.x & 0xffff0000u),
        __uint_as_float(sv.y << 16), __uint_as_float(sv.y & 0xffff0000u),
        __uint_as_float(sv.z << 16), __uint_as_float(sv.z & 0xffff0000u),
        __uint_as_float(sv.w << 16), __uint_as_float(sv.w & 0xffff0000u)};
    float vals[8];
    float mx = -INFINITY;
    if (ok) {
        float4 bb0 = *(const float4*)(bias + c8 * 8), bb1 = *(const float4*)(bias + c8 * 8 + 4);
        float bbv[8] = {bb0.x, bb0.y, bb0.z, bb0.w, bb1.x, bb1.y, bb1.z, bb1.w};
#pragma unroll
        for (int i = 0; i < 8; ++i) {
            vals[i] = a[i] + sf[i] * d2 + bbv[i];
            mx = fmaxf(mx, vals[i]);
        }
    }
#pragma unroll
    for (int o = 1; o < 8; o <<= 1) mx = fmaxf(mx, __shfl_xor(mx, o));
    float es = 0.f;
    if (ok) {
#pragma unroll
        for (int i = 0; i < 8; ++i) es += expf(vals[i] - mx);
    }
#pragma unroll
    for (int o = 1; o < 8; o <<= 1) es += __shfl_xor(es, o);
    float ls = logf(es);

    if (e8 == 0 && ok) {
        float* op = out + (long)node * 40 + c8 * 8;
        *(float4*)op = make_float4(vals[0] - mx - ls, vals[1] - mx - ls,
                                   vals[2] - mx - ls, vals[3] - mx - ls);
        *(float4*)(op + 4) = make_float4(vals[4] - mx - ls, vals[5] - mx - ls,
                                         vals[6] - mx - ls, vals[7] - mx - ls);
    }
}

extern "C" void kernel_launch(void* const* d_in, const int* in_sizes, int n_in,
                              void* d_out, int out_size, void* d_ws, size_t ws_size,
                              hipStream_t stream) {
    const float* x   = (const float*)d_in[0];
    const int*   ei  = (const int*)d_in[1];
    const float* W1  = (const float*)d_in[2];
    const float* b1  = (const float*)d_in[3];
    const float* g1  = (const float*)d_in[4];
    const float* be1 = (const float*)d_in[5];
    const float* m1  = (const float*)d_in[6];
    const float* v1  = (const float*)d_in[7];
    const float* W2  = (const float*)d_in[8];
    const float* b2  = (const float*)d_in[9];
    const float* g2  = (const float*)d_in[10];
    const float* be2 = (const float*)d_in[11];
    const float* m2  = (const float*)d_in[12];
    const float* v2  = (const float*)d_in[13];
    const float* W3  = (const float*)d_in[14];
    const float* b3  = (const float*)d_in[15];
    float* out = (float*)d_out;

    // workspace layout (units: floats from base; all 16B-aligned)
    float* ws        = (float*)d_ws;
    float* dis       = ws;                            // 100096
    int*   degi      = (int*)(ws + 100096);
    int*   cursor    = (int*)(ws + 200192);
    int*   rowptr    = (int*)(ws + 300288);
    int*   blocksum  = (int*)(ws + 400384);           // 128
    int*   blockbase = (int*)(ws + 400512);           // 128
    uint2* epack     = (uint2*)(ws + 400640);         // 1.6M uint2 (3.2M floats)
    unsigned short* bufH = (unsigned short*)(ws + 3600640);    // N*64 bf16
    unsigned short* xp1  = (unsigned short*)(ws + 6800640);    // NTILE*16*512 bf16
    unsigned short* xp2  = (unsigned short*)(ws + 32400640);   // NTILE*2*512 bf16
    unsigned short* xp3  = (unsigned short*)(ws + 35600640);
    unsigned short* wb1  = (unsigned short*)(ws + 38800640);   // 32768
    unsigned short* wb2  = (unsigned short*)(ws + 38817024);   // 4096
    unsigned short* wb3  = (unsigned short*)(ws + 38819072);   // 4096

    // ---- CSR build ----
    k_zero2<<<cdiv(N_NODES, 256), 256, 0, stream>>>(degi, cursor);
    k_count_deg<<<cdiv(N_EDGES, 256), 256, 0, stream>>>(ei, degi);
    k_dis<<<cdiv(N_NODES, 256), 256, 0, stream>>>(degi, dis);
    k_scan1<<<SCAN_NB, 256, 0, stream>>>(degi, rowptr, blocksum);
    k_scan2<<<1, 128, 0, stream>>>(blocksum, blockbase);
    k_scan3<<<SCAN_NB, 256, 0, stream>>>(rowptr, blockbase);
    k_permute<<<cdiv(N_EDGES, 256), 256, 0, stream>>>(ei, rowptr, cursor, dis, epack);

    // ---- weight pack (fragment-ordered bf16) ----
    k_convWp<IN_DIM, HID, 16><<<128, 256, 0, stream>>>(W1, wb1);
    k_convWp<HID, HID, 2><<<16, 256, 0, stream>>>(W2, wb2);
    k_convWp<HID, OUT_DIM, 2><<<16, 256, 0, stream>>>(W3, wb3);

    // ---- x transpose+pack ----
    k_xpose<<<NTILE, 256, 0, stream>>>(x, xp1);

    const int gemm_grid = cdiv(NTILE, 4);
    const int agg_grid  = cdiv(N_NODES, 4);

    // ---- layer 1: 500 -> 64 ----
    k_gemm_packed<16><<<gemm_grid, 256, 0, stream>>>(xp1, wb1, bufH);
    k_agg_bn_relu<<<agg_grid, 256, 0, stream>>>(bufH, rowptr, degi, epack,
                                                dis, b1, g1, be1, m1, v1, xp2);

    // ---- layer 2: 64 -> 64 ----
    k_gemm_packed<2><<<gemm_grid, 256, 0, stream>>>(xp2, wb2, bufH);
    k_agg_bn_relu<<<agg_grid, 256, 0, stream>>>(bufH, rowptr, degi, epack,
                                                dis, b2, g2, be2, m2, v2, xp3);

    // ---- layer 3: 64 -> 40 (h stored 64-wide, cols 40..63 zero) ----
    k_gemm_packed<2><<<gemm_grid, 256, 0, stream>>>(xp3, wb3, bufH);
    k_agg_lsm<<<agg_grid, 256, 0, stream>>>(bufH, rowptr, degi, epack,
                                            dis, b3, out);
}

// Round 12
// 400.762 us; speedup vs baseline: 1.4365x; 1.1178x over previous
//
#include <hip/hip_runtime.h>
#include <math.h>

#define N_NODES 100000
#define N_EDGES 1600000
#define IN_DIM  500
#define HID     64
#define OUT_DIM 40
#define BN_EPS  1e-5f
#define SCAN_NB 98          // ceil(100000 / 1024)
#define NTILE   6250        // N_NODES / 16 (exact)

typedef __attribute__((ext_vector_type(8))) short bf16x8;
typedef __attribute__((ext_vector_type(4))) float f32x4;

static inline int cdiv(long a, int b) { return (int)((a + b - 1) / b); }

__device__ inline unsigned short f2bf_rne(float f) {
    unsigned int u = __float_as_uint(f);
    unsigned int r = (u + 0x7FFFu + ((u >> 16) & 1u)) >> 16;
    return (unsigned short)r;
}

// ---------------- zero int scratch ----------------
__global__ void k_zero2(int* a, int* b) {
    int i = blockIdx.x * 256 + threadIdx.x;
    if (i < N_NODES) { a[i] = 0; b[i] = 0; }
}

// ---------------- integer in-degree ----------------
__global__ void k_count_deg(const int* __restrict__ ei, int* degi) {
    int e = blockIdx.x * 256 + threadIdx.x;
    if (e < N_EDGES) atomicAdd(&degi[ei[N_EDGES + e]], 1);
}

__global__ void k_dis(const int* __restrict__ degi, float* dis) {
    int i = blockIdx.x * 256 + threadIdx.x;
    if (i < N_NODES) dis[i] = rsqrtf((float)degi[i] + 1.0f);
}

// ---------------- exclusive scan (3 kernels) ----------------
__global__ void k_scan1(const int* __restrict__ degi, int* __restrict__ rowptr,
                        int* __restrict__ blocksum) {
    __shared__ int sd[256];
    int tid = threadIdx.x;
    int base = blockIdx.x * 1024 + tid * 4;
    int v0 = (base + 0 < N_NODES) ? degi[base + 0] : 0;
    int v1 = (base + 1 < N_NODES) ? degi[base + 1] : 0;
    int v2 = (base + 2 < N_NODES) ? degi[base + 2] : 0;
    int v3 = (base + 3 < N_NODES) ? degi[base + 3] : 0;
    int s = v0 + v1 + v2 + v3;
    sd[tid] = s;
    __syncthreads();
    for (int off = 1; off < 256; off <<= 1) {
        int t = (tid >= off) ? sd[tid - off] : 0;
        __syncthreads();
        sd[tid] += t;
        __syncthreads();
    }
    int excl = sd[tid] - s;
    if (base + 0 < N_NODES) rowptr[base + 0] = excl;
    if (base + 1 < N_NODES) rowptr[base + 1] = excl + v0;
    if (base + 2 < N_NODES) rowptr[base + 2] = excl + v0 + v1;
    if (base + 3 < N_NODES) rowptr[base + 3] = excl + v0 + v1 + v2;
    if (tid == 255) blocksum[blockIdx.x] = sd[255];
}

__global__ void k_scan2(int* __restrict__ blocksum, int* __restrict__ blockbase) {
    __shared__ int sd[128];
    int tid = threadIdx.x;
    int v = (tid < SCAN_NB) ? blocksum[tid] : 0;
    sd[tid] = v;
    __syncthreads();
    for (int off = 1; off < 128; off <<= 1) {
        int t = (tid >= off) ? sd[tid - off] : 0;
        __syncthreads();
        sd[tid] += t;
        __syncthreads();
    }
    if (tid < SCAN_NB) blockbase[tid] = sd[tid] - v;
}

__global__ void k_scan3(int* __restrict__ rowptr, const int* __restrict__ blockbase) {
    int add = blockbase[blockIdx.x];
    int base = blockIdx.x * 1024 + threadIdx.x * 4;
#pragma unroll
    for (int i = 0; i < 4; ++i)
        if (base + i < N_NODES) rowptr[base + i] += add;
}

// ---------------- CSR permute: group edges by dst, packed meta ----------------
// epack[pos] = { src row byte offset (s*128), norm weight bits }
__global__ void k_permute(const int* __restrict__ ei, const int* __restrict__ rowptr,
                          int* __restrict__ cursor, const float* __restrict__ dis,
                          uint2* __restrict__ epack) {
    int e = blockIdx.x * 256 + threadIdx.x;
    if (e >= N_EDGES) return;
    int s = ei[e];
    int d = ei[N_EDGES + e];
    int pos = rowptr[d] + atomicAdd(&cursor[d], 1);
    epack[pos] = make_uint2((unsigned int)(s * 128),
                            __float_as_uint(dis[s] * dis[d]));
}

// ---------------- weight pack: W[K,F] -> wb[(t*4+nt)*64+lane][8] bf16 -------
template <int K, int F, int T>
__global__ void k_convWp(const float* __restrict__ W, unsigned short* __restrict__ wb) {
    int idx = blockIdx.x * 256 + threadIdx.x;
    if (idx >= T * 2048) return;
    int j    = idx & 7;
    int lane = (idx >> 3) & 63;
    int q    = idx >> 9;             // t*4 + nt
    int t    = q >> 2, nt = q & 3;
    int n = nt * 16 + (lane & 15);
    int k = t * 32 + ((lane >> 4) << 3) + j;
    float v = (k < K && n < F) ? W[(long)k * F + n] : 0.f;
    wb[idx] = f2bf_rne(v);
}

// ---------------- fused layer-1: stage 16 rows of x in LDS, MFMA vs W1 -------
// One block = 16 nodes. Phase 1: 16x500 fp32 -> bf16 LDS [16][520] (k-pad 512).
// Phase 2: wave wid computes output cols wid*16..+15 over all 16 k-steps;
// A-frag from LDS (row=l15, stride 1040 B -> 2-way banks, free), B-frag
// register-prefetched from packed wb1 (L2-resident). h stored row-major bf16.
__global__ __launch_bounds__(256) void k_l1fused(
        const float* __restrict__ x,
        const unsigned short* __restrict__ wb,
        unsigned short* __restrict__ h) {
    __shared__ unsigned short l[16 * 520];
    const int rt = blockIdx.x;
    const int tid = threadIdx.x;

    // phase 1: coalesced read + convert + LDS stage
#pragma unroll
    for (int it = 0; it < 8; ++it) {
        int slot = it * 256 + tid;           // (row, kq): 16 x 128 f32x4-slots
        int row = slot >> 7, kq = slot & 127;
        float4 v = make_float4(0.f, 0.f, 0.f, 0.f);
        if (kq < 125)
            v = *reinterpret_cast<const float4*>(x + ((long)rt * 16 + row) * IN_DIM + kq * 4);
        unsigned int u0 = (unsigned int)f2bf_rne(v.x) | ((unsigned int)f2bf_rne(v.y) << 16);
        unsigned int u1 = (unsigned int)f2bf_rne(v.z) | ((unsigned int)f2bf_rne(v.w) << 16);
        *reinterpret_cast<uint2*>(&l[row * 520 + kq * 4]) = make_uint2(u0, u1);
    }
    __syncthreads();

    // phase 2: per-wave MFMA over k
    const int wid  = tid >> 6;
    const int lane = tid & 63;
    const int l15  = lane & 15;
    const int lhi  = lane >> 4;

    const bf16x8* bp = reinterpret_cast<const bf16x8*>(wb) + wid * 64 + lane;
    const unsigned short* arow = &l[l15 * 520 + lhi * 8];

    f32x4 acc = (f32x4){0.f, 0.f, 0.f, 0.f};
    bf16x8 ca = *reinterpret_cast<const bf16x8*>(arow);
    bf16x8 cb = bp[0];

#pragma unroll
    for (int t = 0; t < 16; ++t) {
        bf16x8 na, nb;
        if (t < 15) {
            na = *reinterpret_cast<const bf16x8*>(arow + (t + 1) * 32);
            nb = bp[(t + 1) * 256];          // +4 q-slots of 64 lanes
        }
        acc = __builtin_amdgcn_mfma_f32_16x16x32_bf16(ca, cb, acc, 0, 0, 0);
        if (t < 15) { ca = na; cb = nb; }
    }

    // store: col = wid*16 + l15, row = lhi*4 + rr
#pragma unroll
    for (int rr = 0; rr < 4; ++rr) {
        long grow = (long)rt * 16 + lhi * 4 + rr;
        h[grow * 64 + wid * 16 + l15] = f2bf_rne(acc[rr]);
    }
}

// ---------------- packed MFMA GEMM (layers 2/3): contiguous frag loads -------
template <int T>
__global__ __launch_bounds__(256) void k_gemm_packed(
        const unsigned short* __restrict__ xp,
        const unsigned short* __restrict__ wb,
        unsigned short* __restrict__ h) {
    const int tid  = threadIdx.x;
    const int wid  = tid >> 6;
    const int lane = tid & 63;
    const int rt   = blockIdx.x * 4 + wid;
    if (rt >= NTILE) return;

    const bf16x8* ap = reinterpret_cast<const bf16x8*>(xp) + (long)rt * T * 64 + lane;
    const bf16x8* bp = reinterpret_cast<const bf16x8*>(wb) + lane;

    f32x4 acc[4];
#pragma unroll
    for (int nt = 0; nt < 4; ++nt) acc[nt] = (f32x4){0.f, 0.f, 0.f, 0.f};

    bf16x8 ca = ap[0];
    bf16x8 cb0 = bp[0], cb1 = bp[64], cb2 = bp[128], cb3 = bp[192];

    for (int t = 0; t < T; ++t) {
        bf16x8 na, nb0, nb1, nb2, nb3;
        if (t + 1 < T) {
            na  = ap[(t + 1) * 64];
            nb0 = bp[((t + 1) * 4 + 0) * 64];
            nb1 = bp[((t + 1) * 4 + 1) * 64];
            nb2 = bp[((t + 1) * 4 + 2) * 64];
            nb3 = bp[((t + 1) * 4 + 3) * 64];
        }
        acc[0] = __builtin_amdgcn_mfma_f32_16x16x32_bf16(ca, cb0, acc[0], 0, 0, 0);
        acc[1] = __builtin_amdgcn_mfma_f32_16x16x32_bf16(ca, cb1, acc[1], 0, 0, 0);
        acc[2] = __builtin_amdgcn_mfma_f32_16x16x32_bf16(ca, cb2, acc[2], 0, 0, 0);
        acc[3] = __builtin_amdgcn_mfma_f32_16x16x32_bf16(ca, cb3, acc[3], 0, 0, 0);
        if (t + 1 < T) { ca = na; cb0 = nb0; cb1 = nb1; cb2 = nb2; cb3 = nb3; }
    }

    const int l15 = lane & 15, lhi = lane >> 4;
#pragma unroll
    for (int nt = 0; nt < 4; ++nt) {
        int coln = nt * 16 + l15;
#pragma unroll
        for (int rr = 0; rr < 4; ++rr) {
            long grow = (long)rt * 16 + lhi * 4 + rr;
            h[grow * 64 + coln] = f2bf_rne(acc[nt][rr]);
        }
    }
}

// ---------------- pull aggregation (e8 x c8) + bias + BN + ReLU -> packed A ---
__global__ __launch_bounds__(256) void k_agg_bn_relu(
        const unsigned short* __restrict__ h, const int* __restrict__ rowptr,
        const int* __restrict__ degi, const uint2* __restrict__ epack,
        const float* __restrict__ dis,
        const float* __restrict__ bias, const float* __restrict__ g,
        const float* __restrict__ be, const float* __restrict__ m,
        const float* __restrict__ v, unsigned short* __restrict__ xp_out) {
    int node = blockIdx.x * 4 + (threadIdx.x >> 6);
    if (node >= N_NODES) return;
    const int lane = threadIdx.x & 63;
    const int e8 = lane >> 3, c8 = lane & 7;

    const int start = rowptr[node];
    const int cnt   = degi[node];
    const uint2* ep = epack + start;
    const char*  hb = (const char*)h + c8 * 16;

    float a[8] = {0.f, 0.f, 0.f, 0.f, 0.f, 0.f, 0.f, 0.f};

    auto batch = [&](int j) {
        int jj = j + e8;
        bool valid = jj < cnt;
        uint2 mv = ep[valid ? jj : 0];
        float w = valid ? __uint_as_float(mv.y) : 0.0f;
        uint4 hv = *(const uint4*)(hb + mv.x);
        a[0] += __uint_as_float(hv.x << 16) * w;
        a[1] += __uint_as_float(hv.x & 0xffff0000u) * w;
        a[2] += __uint_as_float(hv.y << 16) * w;
        a[3] += __uint_as_float(hv.y & 0xffff0000u) * w;
        a[4] += __uint_as_float(hv.z << 16) * w;
        a[5] += __uint_as_float(hv.z & 0xffff0000u) * w;
        a[6] += __uint_as_float(hv.w << 16) * w;
        a[7] += __uint_as_float(hv.w & 0xffff0000u) * w;
    };

    int j = 0;
    for (; j + 8 < cnt; j += 16) { batch(j); batch(j + 8); }
    if (j < cnt) batch(j);

#pragma unroll
    for (int i = 0; i < 8; ++i) {
        a[i] += __shfl_xor(a[i], 8);
        a[i] += __shfl_xor(a[i], 16);
        a[i] += __shfl_xor(a[i], 32);
    }

    if (e8 == 0) {
        float d = dis[node], d2 = d * d;
        uint4 sv = *(const uint4*)((const char*)h + (long)node * 128 + c8 * 16);
        float sf[8] = {
            __uint_as_float(sv.x << 16), __uint_as_float(sv.x & 0xffff0000u),
            __uint_as_float(sv.y << 16), __uint_as_float(sv.y & 0xffff0000u),
            __uint_as_float(sv.z << 16), __uint_as_float(sv.z & 0xffff0000u),
            __uint_as_float(sv.w << 16), __uint_as_float(sv.w & 0xffff0000u)};
        float4 bb0 = *(const float4*)(bias + c8 * 8), bb1 = *(const float4*)(bias + c8 * 8 + 4);
        float4 mm0 = *(const float4*)(m + c8 * 8),    mm1 = *(const float4*)(m + c8 * 8 + 4);
        float4 vv0 = *(const float4*)(v + c8 * 8),    vv1 = *(const float4*)(v + c8 * 8 + 4);
        float4 gg0 = *(const float4*)(g + c8 * 8),    gg1 = *(const float4*)(g + c8 * 8 + 4);
        float4 ee0 = *(const float4*)(be + c8 * 8),   ee1 = *(const float4*)(be + c8 * 8 + 4);
        float bbv[8] = {bb0.x, bb0.y, bb0.z, bb0.w, bb1.x, bb1.y, bb1.z, bb1.w};
        float mmv[8] = {mm0.x, mm0.y, mm0.z, mm0.w, mm1.x, mm1.y, mm1.z, mm1.w};
        float vvv[8] = {vv0.x, vv0.y, vv0.z, vv0.w, vv1.x, vv1.y, vv1.z, vv1.w};
        float ggv[8] = {gg0.x, gg0.y, gg0.z, gg0.w, gg1.x, gg1.y, gg1.z, gg1.w};
        float eev[8] = {ee0.x, ee0.y, ee0.z, ee0.w, ee1.x, ee1.y, ee1.z, ee1.w};

        unsigned int u[4];
#pragma unroll
        for (int p = 0; p < 4; ++p) {
            float r0 = a[2 * p]     + sf[2 * p]     * d2 + bbv[2 * p];
            float r1 = a[2 * p + 1] + sf[2 * p + 1] * d2 + bbv[2 * p + 1];
            r0 = fmaxf((r0 - mmv[2 * p])     * rsqrtf(vvv[2 * p]     + BN_EPS) * ggv[2 * p]     + eev[2 * p],     0.f);
            r1 = fmaxf((r1 - mmv[2 * p + 1]) * rsqrtf(vvv[2 * p + 1] + BN_EPS) * ggv[2 * p + 1] + eev[2 * p + 1], 0.f);
            u[p] = (unsigned int)f2bf_rne(r0) | ((unsigned int)f2bf_rne(r1) << 16);
        }

        // fragment-packed store (T=2): cols c = c8*8 + 0..7 -> t=c8>>2, lh=c8&3
        int n16 = node & 15, rt2 = node >> 4;
        long base = (((long)rt2 * 2 + (c8 >> 2)) * 64 + (c8 & 3) * 16 + n16) * 8;
        *reinterpret_cast<uint4*>(xp_out + base) = make_uint4(u[0], u[1], u[2], u[3]);
    }
}

// ---------------- pull aggregation (e8 x c8) + bias + log_softmax -------------
__global__ __launch_bounds__(256) void k_agg_lsm(
        const unsigned short* __restrict__ h, const int* __restrict__ rowptr,
        const int* __restrict__ degi, const uint2* __restrict__ epack,
        const float* __restrict__ dis,
        const float* __restrict__ bias, float* __restrict__ out) {
    int node = blockIdx.x * 4 + (threadIdx.x >> 6);
    if (node >= N_NODES) return;
    const int lane = threadIdx.x & 63;
    const int e8 = lane >> 3, c8 = lane & 7;

    const int start = rowptr[node];
    const int cnt   = degi[node];
    const uint2* ep = epack + start;
    const char*  hb = (const char*)h + c8 * 16;

    float a[8] = {0.f, 0.f, 0.f, 0.f, 0.f, 0.f, 0.f, 0.f};

    auto batch = [&](int j) {
        int jj = j + e8;
        bool valid = jj < cnt;
        uint2 mv = ep[valid ? jj : 0];
        float w = valid ? __uint_as_float(mv.y) : 0.0f;
        uint4 hv = *(const uint4*)(hb + mv.x);
        a[0] += __uint_as_float(hv.x << 16) * w;
        a[1] += __uint_as_float(hv.x & 0xffff0000u) * w;
        a[2] += __uint_as_float(hv.y << 16) * w;
        a[3] += __uint_as_float(hv.y & 0xffff0000u) * w;
        a[4] += __uint_as_float(hv.z << 16) * w;
        a[5] += __uint_as_float(hv.z & 0xffff0000u) * w;
        a[6] += __uint_as_float(hv.w << 16) * w;
        a[7] += __uint_as_float(hv.w & 0xffff0000u) * w;
    };

    int j = 0;
    for (; j + 8 < cnt; j += 16) { batch(j); batch(j + 8); }
    if (j < cnt) batch(j);

#pragma unroll
    for (int i = 0; i < 8; ++i) {
        a[i] += __shfl_xor(a[i], 8);
        a[i] += __shfl_xor(a[i], 16);
        a[i] += __shfl_xor(a[i], 32);
    }

    const bool ok = c8 < 5;                     // cols c8*8..+7 all < 40
    float d = dis[node], d2 = d * d;
    uint4 sv = *(const uint4*)((const char*)h + (long)node * 128 + c8 * 16);
    float sf[8] = {
        __uint_as_float(sv.x << 16), __uint_as_float(sv.x & 0xffff0000u),
        __uint_as_float(sv.y << 16), __uint_as_float(sv.y & 0xffff0000u),
        __uint_as_float(sv.z << 16), __uint_as_float(sv.z & 0xffff0000u),
        __uint_as_float(sv.w << 16), __uint_as_float(sv.w & 0xffff0000u)};
    float vals[8];
    float mx = -INFINITY;
    if (ok) {
        float4 bb0 = *(const float4*)(bias + c8 * 8), bb1 = *(const float4*)(bias + c8 * 8 + 4);
        float bbv[8] = {bb0.x, bb0.y, bb0.z, bb0.w, bb1.x, bb1.y, bb1.z, bb1.w};
#pragma unroll
        for (int i = 0; i < 8; ++i) {
            vals[i] = a[i] + sf[i] * d2 + bbv[i];
            mx = fmaxf(mx, vals[i]);
        }
    }
#pragma unroll
    for (int o = 1; o < 8; o <<= 1) mx = fmaxf(mx, __shfl_xor(mx, o));
    float es = 0.f;
    if (ok) {
#pragma unroll
        for (int i = 0; i < 8; ++i) es += expf(vals[i] - mx);
    }
#pragma unroll
    for (int o = 1; o < 8; o <<= 1) es += __shfl_xor(es, o);
    float ls = logf(es);

    if (e8 == 0 && ok) {
        float* op = out + (long)node * 40 + c8 * 8;
        *(float4*)op = make_float4(vals[0] - mx - ls, vals[1] - mx - ls,
                                   vals[2] - mx - ls, vals[3] - mx - ls);
        *(float4*)(op + 4) = make_float4(vals[4] - mx - ls, vals[5] - mx - ls,
                                         vals[6] - mx - ls, vals[7] - mx - ls);
    }
}

extern "C" void kernel_launch(void* const* d_in, const int* in_sizes, int n_in,
                              void* d_out, int out_size, void* d_ws, size_t ws_size,
                              hipStream_t stream) {
    const float* x   = (const float*)d_in[0];
    const int*   ei  = (const int*)d_in[1];
    const float* W1  = (const float*)d_in[2];
    const float* b1  = (const float*)d_in[3];
    const float* g1  = (const float*)d_in[4];
    const float* be1 = (const float*)d_in[5];
    const float* m1  = (const float*)d_in[6];
    const float* v1  = (const float*)d_in[7];
    const float* W2  = (const float*)d_in[8];
    const float* b2  = (const float*)d_in[9];
    const float* g2  = (const float*)d_in[10];
    const float* be2 = (const float*)d_in[11];
    const float* m2  = (const float*)d_in[12];
    const float* v2  = (const float*)d_in[13];
    const float* W3  = (const float*)d_in[14];
    const float* b3  = (const float*)d_in[15];
    float* out = (float*)d_out;

    // workspace layout (units: floats from base; all 16B-aligned)
    float* ws        = (float*)d_ws;
    float* dis       = ws;                            // 100096
    int*   degi      = (int*)(ws + 100096);
    int*   cursor    = (int*)(ws + 200192);
    int*   rowptr    = (int*)(ws + 300288);
    int*   blocksum  = (int*)(ws + 400384);           // 128
    int*   blockbase = (int*)(ws + 400512);           // 128
    uint2* epack     = (uint2*)(ws + 400640);         // 1.6M uint2
    unsigned short* bufH = (unsigned short*)(ws + 3600640);    // N*64 bf16
    unsigned short* xp2  = (unsigned short*)(ws + 32400640);   // NTILE*2*512 bf16
    unsigned short* xp3  = (unsigned short*)(ws + 35600640);
    unsigned short* wb1  = (unsigned short*)(ws + 38800640);   // 32768
    unsigned short* wb2  = (unsigned short*)(ws + 38817024);   // 4096
    unsigned short* wb3  = (unsigned short*)(ws + 38819072);   // 4096

    // ---- CSR build ----
    k_zero2<<<cdiv(N_NODES, 256), 256, 0, stream>>>(degi, cursor);
    k_count_deg<<<cdiv(N_EDGES, 256), 256, 0, stream>>>(ei, degi);
    k_dis<<<cdiv(N_NODES, 256), 256, 0, stream>>>(degi, dis);
    k_scan1<<<SCAN_NB, 256, 0, stream>>>(degi, rowptr, blocksum);
    k_scan2<<<1, 128, 0, stream>>>(blocksum, blockbase);
    k_scan3<<<SCAN_NB, 256, 0, stream>>>(rowptr, blockbase);
    k_permute<<<cdiv(N_EDGES, 256), 256, 0, stream>>>(ei, rowptr, cursor, dis, epack);

    // ---- weight pack (fragment-ordered bf16) ----
    k_convWp<IN_DIM, HID, 16><<<128, 256, 0, stream>>>(W1, wb1);
    k_convWp<HID, HID, 2><<<16, 256, 0, stream>>>(W2, wb2);
    k_convWp<HID, OUT_DIM, 2><<<16, 256, 0, stream>>>(W3, wb3);

    const int gemm_grid = cdiv(NTILE, 4);
    const int agg_grid  = cdiv(N_NODES, 4);

    // ---- layer 1: fused transpose+convert+GEMM (500 -> 64) ----
    k_l1fused<<<NTILE, 256, 0, stream>>>(x, wb1, bufH);
    k_agg_bn_relu<<<agg_grid, 256, 0, stream>>>(bufH, rowptr, degi, epack,
                                                dis, b1, g1, be1, m1, v1, xp2);

    // ---- layer 2: 64 -> 64 ----
    k_gemm_packed<2><<<gemm_grid, 256, 0, stream>>>(xp2, wb2, bufH);
    k_agg_bn_relu<<<agg_grid, 256, 0, stream>>>(bufH, rowptr, degi, epack,
                                                dis, b2, g2, be2, m2, v2, xp3);

    // ---- layer 3: 64 -> 40 (h stored 64-wide, cols 40..63 zero) ----
    k_gemm_packed<2><<<gemm_grid, 256, 0, stream>>>(xp3, wb3, bufH);
    k_agg_lsm<<<agg_grid, 256, 0, stream>>>(bufH, rowptr, degi, epack,
                                            dis, b3, out);
}

// Round 13
// 394.513 us; speedup vs baseline: 1.4593x; 1.0158x over previous
//
#include <hip/hip_runtime.h>
#include <math.h>

#define N_NODES 100000
#define N_EDGES 1600000
#define IN_DIM  500
#define HID     64
#define OUT_DIM 40
#define BN_EPS  1e-5f
#define SCAN_NB 98          // ceil(100000 / 1024)
#define NTILE   6250        // N_NODES / 16 (exact)

typedef _Float16 f16;
typedef __attribute__((ext_vector_type(2))) _Float16 f16x2;
typedef __attribute__((ext_vector_type(8))) _Float16 f16x8;
typedef __attribute__((ext_vector_type(4))) float f32x4;

static inline int cdiv(long a, int b) { return (int)((a + b - 1) / b); }

__device__ inline unsigned short f2h_bits(float f) {
    f16 h = (f16)f;
    return __builtin_bit_cast(unsigned short, h);
}
__device__ inline f16x2 bits2h2(unsigned int u) {
    return __builtin_bit_cast(f16x2, u);
}

// ---------------- integer in-degree ----------------
__global__ void k_count_deg(const int* __restrict__ ei, int* degi) {
    int e = blockIdx.x * 256 + threadIdx.x;
    if (e < N_EDGES) atomicAdd(&degi[ei[N_EDGES + e]], 1);
}

// ---------------- exclusive scan (3 kernels; scan1 also emits dis) ----------
__global__ void k_scan1(const int* __restrict__ degi, int* __restrict__ rowptr,
                        int* __restrict__ blocksum, float* __restrict__ dis) {
    __shared__ int sd[256];
    int tid = threadIdx.x;
    int base = blockIdx.x * 1024 + tid * 4;
    int v0 = (base + 0 < N_NODES) ? degi[base + 0] : 0;
    int v1 = (base + 1 < N_NODES) ? degi[base + 1] : 0;
    int v2 = (base + 2 < N_NODES) ? degi[base + 2] : 0;
    int v3 = (base + 3 < N_NODES) ? degi[base + 3] : 0;
    if (base + 0 < N_NODES) dis[base + 0] = rsqrtf((float)v0 + 1.0f);
    if (base + 1 < N_NODES) dis[base + 1] = rsqrtf((float)v1 + 1.0f);
    if (base + 2 < N_NODES) dis[base + 2] = rsqrtf((float)v2 + 1.0f);
    if (base + 3 < N_NODES) dis[base + 3] = rsqrtf((float)v3 + 1.0f);
    int s = v0 + v1 + v2 + v3;
    sd[tid] = s;
    __syncthreads();
    for (int off = 1; off < 256; off <<= 1) {
        int t = (tid >= off) ? sd[tid - off] : 0;
        __syncthreads();
        sd[tid] += t;
        __syncthreads();
    }
    int excl = sd[tid] - s;
    if (base + 0 < N_NODES) rowptr[base + 0] = excl;
    if (base + 1 < N_NODES) rowptr[base + 1] = excl + v0;
    if (base + 2 < N_NODES) rowptr[base + 2] = excl + v0 + v1;
    if (base + 3 < N_NODES) rowptr[base + 3] = excl + v0 + v1 + v2;
    if (tid == 255) blocksum[blockIdx.x] = sd[255];
}

__global__ void k_scan2(int* __restrict__ blocksum, int* __restrict__ blockbase) {
    __shared__ int sd[128];
    int tid = threadIdx.x;
    int v = (tid < SCAN_NB) ? blocksum[tid] : 0;
    sd[tid] = v;
    __syncthreads();
    for (int off = 1; off < 128; off <<= 1) {
        int t = (tid >= off) ? sd[tid - off] : 0;
        __syncthreads();
        sd[tid] += t;
        __syncthreads();
    }
    if (tid < SCAN_NB) blockbase[tid] = sd[tid] - v;
}

__global__ void k_scan3(int* __restrict__ rowptr, const int* __restrict__ blockbase) {
    int add = blockbase[blockIdx.x];
    int base = blockIdx.x * 1024 + threadIdx.x * 4;
#pragma unroll
    for (int i = 0; i < 4; ++i)
        if (base + i < N_NODES) rowptr[base + i] += add;
}

// ---------------- CSR permute: group edges by dst, packed meta ----------------
// epack[pos] = { src row byte offset (s*128), half2(w,w) bits }
__global__ void k_permute(const int* __restrict__ ei, const int* __restrict__ rowptr,
                          int* __restrict__ cursor, const float* __restrict__ dis,
                          uint2* __restrict__ epack) {
    int e = blockIdx.x * 256 + threadIdx.x;
    if (e >= N_EDGES) return;
    int s = ei[e];
    int d = ei[N_EDGES + e];
    int pos = rowptr[d] + atomicAdd(&cursor[d], 1);
    unsigned int hb = f2h_bits(dis[s] * dis[d]);
    epack[pos] = make_uint2((unsigned int)(s * 128), (hb << 16) | hb);
}

// ---------------- weight pack (all 3 layers, one dispatch) -------------------
// wb layout per layer: [(t*4+nt)*64+lane][8] f16; n=nt*16+(lane&15),
// k=t*32+(lane>>4)*8+j, zero-padded outside K x F.
__device__ inline void convW_one(const float* W, unsigned short* wb,
                                 int idx, int K, int F) {
    int j    = idx & 7;
    int lane = (idx >> 3) & 63;
    int q    = idx >> 9;             // t*4 + nt
    int t    = q >> 2, nt = q & 3;
    int n = nt * 16 + (lane & 15);
    int k = t * 32 + ((lane >> 4) << 3) + j;
    float v = (k < K && n < F) ? W[(long)k * F + n] : 0.f;
    wb[idx] = f2h_bits(v);
}

__global__ void k_convall(const float* __restrict__ W1, const float* __restrict__ W2,
                          const float* __restrict__ W3,
                          unsigned short* __restrict__ wb1,
                          unsigned short* __restrict__ wb2,
                          unsigned short* __restrict__ wb3) {
    int idx = blockIdx.x * 256 + threadIdx.x;   // 160*256 = 40960
    if (idx < 32768) {
        convW_one(W1, wb1, idx, IN_DIM, HID);
    } else if (idx < 36864) {
        convW_one(W2, wb2, idx - 32768, HID, HID);
    } else {
        convW_one(W3, wb3, idx - 36864, HID, OUT_DIM);
    }
}

// ---------------- fused layer-1: stage 16 rows of x in LDS, MFMA vs W1 -------
__global__ __launch_bounds__(256) void k_l1fused(
        const float* __restrict__ x,
        const unsigned short* __restrict__ wb,
        unsigned short* __restrict__ h) {
    __shared__ unsigned short l[16 * 520];
    const int rt = blockIdx.x;
    const int tid = threadIdx.x;

    // phase 1: coalesced read + f16 convert + LDS stage
#pragma unroll
    for (int it = 0; it < 8; ++it) {
        int slot = it * 256 + tid;           // (row, kq): 16 x 128 f32x4-slots
        int row = slot >> 7, kq = slot & 127;
        float4 v = make_float4(0.f, 0.f, 0.f, 0.f);
        if (kq < 125)
            v = *reinterpret_cast<const float4*>(x + ((long)rt * 16 + row) * IN_DIM + kq * 4);
        unsigned int u0 = (unsigned int)f2h_bits(v.x) | ((unsigned int)f2h_bits(v.y) << 16);
        unsigned int u1 = (unsigned int)f2h_bits(v.z) | ((unsigned int)f2h_bits(v.w) << 16);
        *reinterpret_cast<uint2*>(&l[row * 520 + kq * 4]) = make_uint2(u0, u1);
    }
    __syncthreads();

    // phase 2: per-wave MFMA over 16 k-steps
    const int wid  = tid >> 6;
    const int lane = tid & 63;
    const int l15  = lane & 15;
    const int lhi  = lane >> 4;

    const f16x8* bp = reinterpret_cast<const f16x8*>(wb) + wid * 64 + lane;
    const unsigned short* arow = &l[l15 * 520 + lhi * 8];

    f32x4 acc = (f32x4){0.f, 0.f, 0.f, 0.f};
    f16x8 ca = *reinterpret_cast<const f16x8*>(arow);
    f16x8 cb = bp[0];

#pragma unroll
    for (int t = 0; t < 16; ++t) {
        f16x8 na, nb;
        if (t < 15) {
            na = *reinterpret_cast<const f16x8*>(arow + (t + 1) * 32);
            nb = bp[(t + 1) * 256];
        }
        acc = __builtin_amdgcn_mfma_f32_16x16x32_f16(ca, cb, acc, 0, 0, 0);
        if (t < 15) { ca = na; cb = nb; }
    }

    // store: col = wid*16 + l15, row = lhi*4 + rr
#pragma unroll
    for (int rr = 0; rr < 4; ++rr) {
        long grow = (long)rt * 16 + lhi * 4 + rr;
        h[grow * 64 + wid * 16 + l15] = f2h_bits(acc[rr]);
    }
}

// ---------------- packed MFMA GEMM (layers 2/3) -------------------------------
template <int T>
__global__ __launch_bounds__(256) void k_gemm_packed(
        const unsigned short* __restrict__ xp,
        const unsigned short* __restrict__ wb,
        unsigned short* __restrict__ h) {
    const int tid  = threadIdx.x;
    const int wid  = tid >> 6;
    const int lane = tid & 63;
    const int rt   = blockIdx.x * 4 + wid;
    if (rt >= NTILE) return;

    const f16x8* ap = reinterpret_cast<const f16x8*>(xp) + (long)rt * T * 64 + lane;
    const f16x8* bp = reinterpret_cast<const f16x8*>(wb) + lane;

    f32x4 acc[4];
#pragma unroll
    for (int nt = 0; nt < 4; ++nt) acc[nt] = (f32x4){0.f, 0.f, 0.f, 0.f};

    f16x8 ca = ap[0];
    f16x8 cb0 = bp[0], cb1 = bp[64], cb2 = bp[128], cb3 = bp[192];

    for (int t = 0; t < T; ++t) {
        f16x8 na, nb0, nb1, nb2, nb3;
        if (t + 1 < T) {
            na  = ap[(t + 1) * 64];
            nb0 = bp[((t + 1) * 4 + 0) * 64];
            nb1 = bp[((t + 1) * 4 + 1) * 64];
            nb2 = bp[((t + 1) * 4 + 2) * 64];
            nb3 = bp[((t + 1) * 4 + 3) * 64];
        }
        acc[0] = __builtin_amdgcn_mfma_f32_16x16x32_f16(ca, cb0, acc[0], 0, 0, 0);
        acc[1] = __builtin_amdgcn_mfma_f32_16x16x32_f16(ca, cb1, acc[1], 0, 0, 0);
        acc[2] = __builtin_amdgcn_mfma_f32_16x16x32_f16(ca, cb2, acc[2], 0, 0, 0);
        acc[3] = __builtin_amdgcn_mfma_f32_16x16x32_f16(ca, cb3, acc[3], 0, 0, 0);
        if (t + 1 < T) { ca = na; cb0 = nb0; cb1 = nb1; cb2 = nb2; cb3 = nb3; }
    }

    const int l15 = lane & 15, lhi = lane >> 4;
#pragma unroll
    for (int nt = 0; nt < 4; ++nt) {
        int coln = nt * 16 + l15;
#pragma unroll
        for (int rr = 0; rr < 4; ++rr) {
            long grow = (long)rt * 16 + lhi * 4 + rr;
            h[grow * 64 + coln] = f2h_bits(acc[nt][rr]);
        }
    }
}

// ---------------- pull aggregation (e8 x c8, packed fp16 FMA) -----------------
// lane = (edge slot e8 = lane>>3, col slice c8 = lane&7, 16 B = 8 f16 cols).
// Hot loop per 8 edges: 1 uint2 meta + 1 uint4 gather + 4 v_pk_fma_f16.
__global__ __launch_bounds__(256) void k_agg_bn_relu(
        const unsigned short* __restrict__ h, const int* __restrict__ rowptr,
        const int* __restrict__ degi, const uint2* __restrict__ epack,
        const float* __restrict__ dis,
        const float* __restrict__ bias, const float* __restrict__ g,
        const float* __restrict__ be, const float* __restrict__ m,
        const float* __restrict__ v, unsigned short* __restrict__ xp_out) {
    int node = blockIdx.x * 4 + (threadIdx.x >> 6);
    if (node >= N_NODES) return;
    const int lane = threadIdx.x & 63;
    const int e8 = lane >> 3, c8 = lane & 7;

    const int start = rowptr[node];
    const int cnt   = degi[node];
    const uint2* ep = epack + start;
    const char*  hb = (const char*)h + c8 * 16;

    f16x2 a[4] = {(f16x2)0, (f16x2)0, (f16x2)0, (f16x2)0};

    auto batch = [&](int j) {
        int jj = j + e8;
        bool valid = jj < cnt;
        uint2 mv = ep[valid ? jj : 0];
        f16x2 w2 = bits2h2(valid ? mv.y : 0u);
        uint4 hv = *(const uint4*)(hb + mv.x);
        a[0] += bits2h2(hv.x) * w2;
        a[1] += bits2h2(hv.y) * w2;
        a[2] += bits2h2(hv.z) * w2;
        a[3] += bits2h2(hv.w) * w2;
    };

    int j = 0;
    for (; j + 8 < cnt; j += 16) { batch(j); batch(j + 8); }
    if (j < cnt) batch(j);

    // packed butterfly reduce over e8 (lanes 8,16,32)
#pragma unroll
    for (int off = 8; off < 64; off <<= 1) {
#pragma unroll
        for (int i = 0; i < 4; ++i) {
            unsigned int u = __builtin_bit_cast(unsigned int, a[i]);
            a[i] += bits2h2((unsigned int)__shfl_xor((int)u, off));
        }
    }

    if (e8 == 0) {
        float d = dis[node], d2 = d * d;
        uint4 sv = *(const uint4*)((const char*)h + (long)node * 128 + c8 * 16);
        f16x2 s01 = bits2h2(sv.x), s23 = bits2h2(sv.y);
        f16x2 s45 = bits2h2(sv.z), s67 = bits2h2(sv.w);
        float av[8] = {(float)a[0][0], (float)a[0][1], (float)a[1][0], (float)a[1][1],
                       (float)a[2][0], (float)a[2][1], (float)a[3][0], (float)a[3][1]};
        float sf[8] = {(float)s01[0], (float)s01[1], (float)s23[0], (float)s23[1],
                       (float)s45[0], (float)s45[1], (float)s67[0], (float)s67[1]};
        float4 bb0 = *(const float4*)(bias + c8 * 8), bb1 = *(const float4*)(bias + c8 * 8 + 4);
        float4 mm0 = *(const float4*)(m + c8 * 8),    mm1 = *(const float4*)(m + c8 * 8 + 4);
        float4 vv0 = *(const float4*)(v + c8 * 8),    vv1 = *(const float4*)(v + c8 * 8 + 4);
        float4 gg0 = *(const float4*)(g + c8 * 8),    gg1 = *(const float4*)(g + c8 * 8 + 4);
        float4 ee0 = *(const float4*)(be + c8 * 8),   ee1 = *(const float4*)(be + c8 * 8 + 4);
        float bbv[8] = {bb0.x, bb0.y, bb0.z, bb0.w, bb1.x, bb1.y, bb1.z, bb1.w};
        float mmv[8] = {mm0.x, mm0.y, mm0.z, mm0.w, mm1.x, mm1.y, mm1.z, mm1.w};
        float vvv[8] = {vv0.x, vv0.y, vv0.z, vv0.w, vv1.x, vv1.y, vv1.z, vv1.w};
        float ggv[8] = {gg0.x, gg0.y, gg0.z, gg0.w, gg1.x, gg1.y, gg1.z, gg1.w};
        float eev[8] = {ee0.x, ee0.y, ee0.z, ee0.w, ee1.x, ee1.y, ee1.z, ee1.w};

        unsigned int u[4];
#pragma unroll
        for (int p = 0; p < 4; ++p) {
            float r0 = av[2 * p]     + sf[2 * p]     * d2 + bbv[2 * p];
            float r1 = av[2 * p + 1] + sf[2 * p + 1] * d2 + bbv[2 * p + 1];
            r0 = fmaxf((r0 - mmv[2 * p])     * rsqrtf(vvv[2 * p]     + BN_EPS) * ggv[2 * p]     + eev[2 * p],     0.f);
            r1 = fmaxf((r1 - mmv[2 * p + 1]) * rsqrtf(vvv[2 * p + 1] + BN_EPS) * ggv[2 * p + 1] + eev[2 * p + 1], 0.f);
            u[p] = (unsigned int)f2h_bits(r0) | ((unsigned int)f2h_bits(r1) << 16);
        }

        // fragment-packed store (T=2): cols c = c8*8 + 0..7 -> t=c8>>2, lh=c8&3
        int n16 = node & 15, rt2 = node >> 4;
        long base = (((long)rt2 * 2 + (c8 >> 2)) * 64 + (c8 & 3) * 16 + n16) * 8;
        *reinterpret_cast<uint4*>(xp_out + base) = make_uint4(u[0], u[1], u[2], u[3]);
    }
}

// ---------------- pull aggregation + bias + log_softmax -----------------------
__global__ __launch_bounds__(256) void k_agg_lsm(
        const unsigned short* __restrict__ h, const int* __restrict__ rowptr,
        const int* __restrict__ degi, const uint2* __restrict__ epack,
        const float* __restrict__ dis,
        const float* __restrict__ bias, float* __restrict__ out) {
    int node = blockIdx.x * 4 + (threadIdx.x >> 6);
    if (node >= N_NODES) return;
    const int lane = threadIdx.x & 63;
    const int e8 = lane >> 3, c8 = lane & 7;

    const int start = rowptr[node];
    const int cnt   = degi[node];
    const uint2* ep = epack + start;
    const char*  hb = (const char*)h + c8 * 16;

    f16x2 a[4] = {(f16x2)0, (f16x2)0, (f16x2)0, (f16x2)0};

    auto batch = [&](int j) {
        int jj = j + e8;
        bool valid = jj < cnt;
        uint2 mv = ep[valid ? jj : 0];
        f16x2 w2 = bits2h2(valid ? mv.y : 0u);
        uint4 hv = *(const uint4*)(hb + mv.x);
        a[0] += bits2h2(hv.x) * w2;
        a[1] += bits2h2(hv.y) * w2;
        a[2] += bits2h2(hv.z) * w2;
        a[3] += bits2h2(hv.w) * w2;
    };

    int j = 0;
    for (; j + 8 < cnt; j += 16) { batch(j); batch(j + 8); }
    if (j < cnt) batch(j);

#pragma unroll
    for (int off = 8; off < 64; off <<= 1) {
#pragma unroll
        for (int i = 0; i < 4; ++i) {
            unsigned int u = __builtin_bit_cast(unsigned int, a[i]);
            a[i] += bits2h2((unsigned int)__shfl_xor((int)u, off));
        }
    }

    const bool ok = c8 < 5;                     // cols c8*8..+7 all < 40
    float d = dis[node], d2 = d * d;
    uint4 sv = *(const uint4*)((const char*)h + (long)node * 128 + c8 * 16);
    f16x2 s01 = bits2h2(sv.x), s23 = bits2h2(sv.y);
    f16x2 s45 = bits2h2(sv.z), s67 = bits2h2(sv.w);
    float av[8] = {(float)a[0][0], (float)a[0][1], (float)a[1][0], (float)a[1][1],
                   (float)a[2][0], (float)a[2][1], (float)a[3][0], (float)a[3][1]};
    float sf[8] = {(float)s01[0], (float)s01[1], (float)s23[0], (float)s23[1],
                   (float)s45[0], (float)s45[1], (float)s67[0], (float)s67[1]};
    float vals[8];
    float mx = -INFINITY;
    if (ok) {
        float4 bb0 = *(const float4*)(bias + c8 * 8), bb1 = *(const float4*)(bias + c8 * 8 + 4);
        float bbv[8] = {bb0.x, bb0.y, bb0.z, bb0.w, bb1.x, bb1.y, bb1.z, bb1.w};
#pragma unroll
        for (int i = 0; i < 8; ++i) {
            vals[i] = av[i] + sf[i] * d2 + bbv[i];
            mx = fmaxf(mx, vals[i]);
        }
    }
#pragma unroll
    for (int o = 1; o < 8; o <<= 1) mx = fmaxf(mx, __shfl_xor(mx, o));
    float es = 0.f;
    if (ok) {
#pragma unroll
        for (int i = 0; i < 8; ++i) es += expf(vals[i] - mx);
    }
#pragma unroll
    for (int o = 1; o < 8; o <<= 1) es += __shfl_xor(es, o);
    float ls = logf(es);

    if (e8 == 0 && ok) {
        float* op = out + (long)node * 40 + c8 * 8;
        *(float4*)op = make_float4(vals[0] - mx - ls, vals[1] - mx - ls,
                                   vals[2] - mx - ls, vals[3] - mx - ls);
        *(float4*)(op + 4) = make_float4(vals[4] - mx - ls, vals[5] - mx - ls,
                                         vals[6] - mx - ls, vals[7] - mx - ls);
    }
}

extern "C" void kernel_launch(void* const* d_in, const int* in_sizes, int n_in,
                              void* d_out, int out_size, void* d_ws, size_t ws_size,
                              hipStream_t stream) {
    const float* x   = (const float*)d_in[0];
    const int*   ei  = (const int*)d_in[1];
    const float* W1  = (const float*)d_in[2];
    const float* b1  = (const float*)d_in[3];
    const float* g1  = (const float*)d_in[4];
    const float* be1 = (const float*)d_in[5];
    const float* m1  = (const float*)d_in[6];
    const float* v1  = (const float*)d_in[7];
    const float* W2  = (const float*)d_in[8];
    const float* b2  = (const float*)d_in[9];
    const float* g2  = (const float*)d_in[10];
    const float* be2 = (const float*)d_in[11];
    const float* m2  = (const float*)d_in[12];
    const float* v2  = (const float*)d_in[13];
    const float* W3  = (const float*)d_in[14];
    const float* b3  = (const float*)d_in[15];
    float* out = (float*)d_out;

    // workspace layout (units: floats from base; all 16B-aligned)
    float* ws        = (float*)d_ws;
    float* dis       = ws;                            // 100096
    int*   degi      = (int*)(ws + 100096);
    int*   cursor    = (int*)(ws + 200192);           // adjacent to degi
    int*   rowptr    = (int*)(ws + 300288);
    int*   blocksum  = (int*)(ws + 400384);           // 128
    int*   blockbase = (int*)(ws + 400512);           // 128
    uint2* epack     = (uint2*)(ws + 400640);         // 1.6M uint2
    unsigned short* bufH = (unsigned short*)(ws + 3600640);    // N*64 f16
    unsigned short* xp2  = (unsigned short*)(ws + 32400640);   // NTILE*2*512 f16
    unsigned short* xp3  = (unsigned short*)(ws + 35600640);
    unsigned short* wb1  = (unsigned short*)(ws + 38800640);   // 32768
    unsigned short* wb2  = (unsigned short*)(ws + 38817024);   // 4096
    unsigned short* wb3  = (unsigned short*)(ws + 38819072);   // 4096

    // ---- CSR build ----
    hipMemsetAsync(degi, 0, 2 * 100096 * sizeof(int), stream);  // degi + cursor
    k_count_deg<<<cdiv(N_EDGES, 256), 256, 0, stream>>>(ei, degi);
    k_scan1<<<SCAN_NB, 256, 0, stream>>>(degi, rowptr, blocksum, dis);
    k_scan2<<<1, 128, 0, stream>>>(blocksum, blockbase);
    k_scan3<<<SCAN_NB, 256, 0, stream>>>(rowptr, blockbase);
    k_permute<<<cdiv(N_EDGES, 256), 256, 0, stream>>>(ei, rowptr, cursor, dis, epack);

    // ---- weight pack (all layers, f16 fragments) ----
    k_convall<<<160, 256, 0, stream>>>(W1, W2, W3, wb1, wb2, wb3);

    const int gemm_grid = cdiv(NTILE, 4);
    const int agg_grid  = cdiv(N_NODES, 4);

    // ---- layer 1: fused transpose+convert+GEMM (500 -> 64) ----
    k_l1fused<<<NTILE, 256, 0, stream>>>(x, wb1, bufH);
    k_agg_bn_relu<<<agg_grid, 256, 0, stream>>>(bufH, rowptr, degi, epack,
                                                dis, b1, g1, be1, m1, v1, xp2);

    // ---- layer 2: 64 -> 64 ----
    k_gemm_packed<2><<<gemm_grid, 256, 0, stream>>>(xp2, wb2, bufH);
    k_agg_bn_relu<<<agg_grid, 256, 0, stream>>>(bufH, rowptr, degi, epack,
                                                dis, b2, g2, be2, m2, v2, xp3);

    // ---- layer 3: 64 -> 40 (h stored 64-wide, cols 40..63 zero) ----
    k_gemm_packed<2><<<gemm_grid, 256, 0, stream>>>(xp3, wb3, bufH);
    k_agg_lsm<<<agg_grid, 256, 0, stream>>>(bufH, rowptr, degi, epack,
                                            dis, b3, out);
}

// Round 14
// 363.143 us; speedup vs baseline: 1.5853x; 1.0864x over previous
//
#include <hip/hip_runtime.h>
#include <math.h>

#define N_NODES 100000
#define N_EDGES 1600000
#define IN_DIM  500
#define HID     64
#define OUT_DIM 40
#define BN_EPS  1e-5f
#define SCAN_NB 98          // ceil(100000 / 1024)
#define NTILE   6250        // N_NODES / 16 (exact)

typedef _Float16 f16;
typedef __attribute__((ext_vector_type(2))) _Float16 f16x2;
typedef __attribute__((ext_vector_type(8))) _Float16 f16x8;
typedef __attribute__((ext_vector_type(4))) float f32x4;

static inline int cdiv(long a, int b) { return (int)((a + b - 1) / b); }

__device__ inline unsigned short f2h_bits(float f) {
    f16 h = (f16)f;
    return __builtin_bit_cast(unsigned short, h);
}
__device__ inline f16x2 bits2h2(unsigned int u) {
    return __builtin_bit_cast(f16x2, u);
}

// ---------------- integer in-degree ----------------
__global__ void k_count_deg(const int* __restrict__ ei, int* degi) {
    int e = blockIdx.x * 256 + threadIdx.x;
    if (e < N_EDGES) atomicAdd(&degi[ei[N_EDGES + e]], 1);
}

// ---------------- exclusive scan over (deg+1); also emits dis ----------------
__global__ void k_scan1(const int* __restrict__ degi, int* __restrict__ rowptr,
                        int* __restrict__ blocksum, float* __restrict__ dis) {
    __shared__ int sd[256];
    int tid = threadIdx.x;
    int base = blockIdx.x * 1024 + tid * 4;
    int v0 = (base + 0 < N_NODES) ? degi[base + 0] : -1;
    int v1 = (base + 1 < N_NODES) ? degi[base + 1] : -1;
    int v2 = (base + 2 < N_NODES) ? degi[base + 2] : -1;
    int v3 = (base + 3 < N_NODES) ? degi[base + 3] : -1;
    if (base + 0 < N_NODES) dis[base + 0] = rsqrtf((float)v0 + 1.0f);
    if (base + 1 < N_NODES) dis[base + 1] = rsqrtf((float)v1 + 1.0f);
    if (base + 2 < N_NODES) dis[base + 2] = rsqrtf((float)v2 + 1.0f);
    if (base + 3 < N_NODES) dis[base + 3] = rsqrtf((float)v3 + 1.0f);
    int w0 = v0 + 1, w1 = v1 + 1, w2 = v2 + 1, w3 = v3 + 1;   // deg+1 (0 if OOB)
    int s = w0 + w1 + w2 + w3;
    sd[tid] = s;
    __syncthreads();
    for (int off = 1; off < 256; off <<= 1) {
        int t = (tid >= off) ? sd[tid - off] : 0;
        __syncthreads();
        sd[tid] += t;
        __syncthreads();
    }
    int excl = sd[tid] - s;
    if (base + 0 < N_NODES) rowptr[base + 0] = excl;
    if (base + 1 < N_NODES) rowptr[base + 1] = excl + w0;
    if (base + 2 < N_NODES) rowptr[base + 2] = excl + w0 + w1;
    if (base + 3 < N_NODES) rowptr[base + 3] = excl + w0 + w1 + w2;
    if (tid == 255) blocksum[blockIdx.x] = sd[255];
}

__global__ void k_scan2(int* __restrict__ blocksum, int* __restrict__ blockbase) {
    __shared__ int sd[128];
    int tid = threadIdx.x;
    int v = (tid < SCAN_NB) ? blocksum[tid] : 0;
    sd[tid] = v;
    __syncthreads();
    for (int off = 1; off < 128; off <<= 1) {
        int t = (tid >= off) ? sd[tid - off] : 0;
        __syncthreads();
        sd[tid] += t;
        __syncthreads();
    }
    if (tid < SCAN_NB) blockbase[tid] = sd[tid] - v;
}

// scan3: finalize rowptr, write self-loop CSR entry + cursor=1, sentinel.
__global__ void k_scan3(int* __restrict__ rowptr, const int* __restrict__ blockbase,
                        const int* __restrict__ degi, int* __restrict__ cursor,
                        uint2* __restrict__ epack) {
    int add = blockbase[blockIdx.x];
    int base = blockIdx.x * 1024 + threadIdx.x * 4;
#pragma unroll
    for (int i = 0; i < 4; ++i) {
        int node = base + i;
        if (node < N_NODES) {
            int rp = rowptr[node] + add;
            rowptr[node] = rp;
            float d2 = 1.0f / (float)(degi[node] + 1);   // dis^2 exactly
            unsigned int hb = f2h_bits(d2);
            epack[rp] = make_uint2((unsigned int)(node * 128), (hb << 16) | hb);
            cursor[node] = 1;
        }
    }
    if (blockIdx.x == 0 && threadIdx.x == 0)
        rowptr[N_NODES] = N_EDGES + N_NODES;   // sentinel
}

// ---------------- CSR permute: group edges by dst, packed meta ----------------
__global__ void k_permute(const int* __restrict__ ei, const int* __restrict__ rowptr,
                          int* __restrict__ cursor, const float* __restrict__ dis,
                          uint2* __restrict__ epack) {
    int e = blockIdx.x * 256 + threadIdx.x;
    if (e >= N_EDGES) return;
    int s = ei[e];
    int d = ei[N_EDGES + e];
    int pos = rowptr[d] + atomicAdd(&cursor[d], 1);
    unsigned int hb = f2h_bits(dis[s] * dis[d]);
    epack[pos] = make_uint2((unsigned int)(s * 128), (hb << 16) | hb);
}

// ---------------- weight pack (all 3 layers, one dispatch) -------------------
__device__ inline void convW_one(const float* W, unsigned short* wb,
                                 int idx, int K, int F) {
    int j    = idx & 7;
    int lane = (idx >> 3) & 63;
    int q    = idx >> 9;             // t*4 + nt
    int t    = q >> 2, nt = q & 3;
    int n = nt * 16 + (lane & 15);
    int k = t * 32 + ((lane >> 4) << 3) + j;
    float v = (k < K && n < F) ? W[(long)k * F + n] : 0.f;
    wb[idx] = f2h_bits(v);
}

__global__ void k_convall(const float* __restrict__ W1, const float* __restrict__ W2,
                          const float* __restrict__ W3,
                          unsigned short* __restrict__ wb1,
                          unsigned short* __restrict__ wb2,
                          unsigned short* __restrict__ wb3) {
    int idx = blockIdx.x * 256 + threadIdx.x;   // 160*256 = 40960
    if (idx < 32768) {
        convW_one(W1, wb1, idx, IN_DIM, HID);
    } else if (idx < 36864) {
        convW_one(W2, wb2, idx - 32768, HID, HID);
    } else {
        convW_one(W3, wb3, idx - 36864, HID, OUT_DIM);
    }
}

// ---------------- BN fold: S = g*rsqrt(v+eps); C = (b-m)*S + be  (f16) -------
// sc layout: [0..63] = S, [64..127] = C.
__global__ void k_bnfold(const float* __restrict__ b1, const float* __restrict__ g1,
                         const float* __restrict__ be1, const float* __restrict__ m1,
                         const float* __restrict__ v1,
                         const float* __restrict__ b2, const float* __restrict__ g2,
                         const float* __restrict__ be2, const float* __restrict__ m2,
                         const float* __restrict__ v2,
                         unsigned short* __restrict__ sc1,
                         unsigned short* __restrict__ sc2) {
    int t = threadIdx.x;   // 0..127
    int c = t & 63;
    const float *b, *g, *be, *m, *v;
    unsigned short* sc;
    if (t < 64) { b = b1; g = g1; be = be1; m = m1; v = v1; sc = sc1; }
    else        { b = b2; g = g2; be = be2; m = m2; v = v2; sc = sc2; }
    float S = g[c] * rsqrtf(v[c] + BN_EPS);
    float C = (b[c] - m[c]) * S + be[c];
    sc[c]      = f2h_bits(S);
    sc[64 + c] = f2h_bits(C);
}

// ---------------- fused layer-1: stage 16 rows of x in LDS, MFMA vs W1 -------
__global__ __launch_bounds__(256) void k_l1fused(
        const float* __restrict__ x,
        const unsigned short* __restrict__ wb,
        unsigned short* __restrict__ h) {
    __shared__ unsigned short l[16 * 520];
    const int rt = blockIdx.x;
    const int tid = threadIdx.x;

#pragma unroll
    for (int it = 0; it < 8; ++it) {
        int slot = it * 256 + tid;
        int row = slot >> 7, kq = slot & 127;
        float4 v = make_float4(0.f, 0.f, 0.f, 0.f);
        if (kq < 125)
            v = *reinterpret_cast<const float4*>(x + ((long)rt * 16 + row) * IN_DIM + kq * 4);
        unsigned int u0 = (unsigned int)f2h_bits(v.x) | ((unsigned int)f2h_bits(v.y) << 16);
        unsigned int u1 = (unsigned int)f2h_bits(v.z) | ((unsigned int)f2h_bits(v.w) << 16);
        *reinterpret_cast<uint2*>(&l[row * 520 + kq * 4]) = make_uint2(u0, u1);
    }
    __syncthreads();

    const int wid  = tid >> 6;
    const int lane = tid & 63;
    const int l15  = lane & 15;
    const int lhi  = lane >> 4;

    const f16x8* bp = reinterpret_cast<const f16x8*>(wb) + wid * 64 + lane;
    const unsigned short* arow = &l[l15 * 520 + lhi * 8];

    f32x4 acc = (f32x4){0.f, 0.f, 0.f, 0.f};
    f16x8 ca = *reinterpret_cast<const f16x8*>(arow);
    f16x8 cb = bp[0];

#pragma unroll
    for (int t = 0; t < 16; ++t) {
        f16x8 na, nb;
        if (t < 15) {
            na = *reinterpret_cast<const f16x8*>(arow + (t + 1) * 32);
            nb = bp[(t + 1) * 256];
        }
        acc = __builtin_amdgcn_mfma_f32_16x16x32_f16(ca, cb, acc, 0, 0, 0);
        if (t < 15) { ca = na; cb = nb; }
    }

#pragma unroll
    for (int rr = 0; rr < 4; ++rr) {
        long grow = (long)rt * 16 + lhi * 4 + rr;
        h[grow * 64 + wid * 16 + l15] = f2h_bits(acc[rr]);
    }
}

// ---------------- packed MFMA GEMM (layers 2/3) -------------------------------
template <int T>
__global__ __launch_bounds__(256) void k_gemm_packed(
        const unsigned short* __restrict__ xp,
        const unsigned short* __restrict__ wb,
        unsigned short* __restrict__ h) {
    const int tid  = threadIdx.x;
    const int wid  = tid >> 6;
    const int lane = tid & 63;
    const int rt   = blockIdx.x * 4 + wid;
    if (rt >= NTILE) return;

    const f16x8* ap = reinterpret_cast<const f16x8*>(xp) + (long)rt * T * 64 + lane;
    const f16x8* bp = reinterpret_cast<const f16x8*>(wb) + lane;

    f32x4 acc[4];
#pragma unroll
    for (int nt = 0; nt < 4; ++nt) acc[nt] = (f32x4){0.f, 0.f, 0.f, 0.f};

    f16x8 ca = ap[0];
    f16x8 cb0 = bp[0], cb1 = bp[64], cb2 = bp[128], cb3 = bp[192];

    for (int t = 0; t < T; ++t) {
        f16x8 na, nb0, nb1, nb2, nb3;
        if (t + 1 < T) {
            na  = ap[(t + 1) * 64];
            nb0 = bp[((t + 1) * 4 + 0) * 64];
            nb1 = bp[((t + 1) * 4 + 1) * 64];
            nb2 = bp[((t + 1) * 4 + 2) * 64];
            nb3 = bp[((t + 1) * 4 + 3) * 64];
        }
        acc[0] = __builtin_amdgcn_mfma_f32_16x16x32_f16(ca, cb0, acc[0], 0, 0, 0);
        acc[1] = __builtin_amdgcn_mfma_f32_16x16x32_f16(ca, cb1, acc[1], 0, 0, 0);
        acc[2] = __builtin_amdgcn_mfma_f32_16x16x32_f16(ca, cb2, acc[2], 0, 0, 0);
        acc[3] = __builtin_amdgcn_mfma_f32_16x16x32_f16(ca, cb3, acc[3], 0, 0, 0);
        if (t + 1 < T) { ca = na; cb0 = nb0; cb1 = nb1; cb2 = nb2; cb3 = nb3; }
    }

    const int l15 = lane & 15, lhi = lane >> 4;
#pragma unroll
    for (int nt = 0; nt < 4; ++nt) {
        int coln = nt * 16 + l15;
#pragma unroll
        for (int rr = 0; rr < 4; ++rr) {
            long grow = (long)rt * 16 + lhi * 4 + rr;
            h[grow * 64 + coln] = f2h_bits(acc[nt][rr]);
        }
    }
}

// ---------------- pull aggregation (self-loop in CSR) + folded BN + ReLU ------
// lane = (edge slot e8 = lane>>3, col slice c8 = lane&7, 16 B = 8 f16 cols).
// Epilogue: 2 uint4 loads (S,C f16) + 4 pk_fma + 4 pk_max + 1 store.
__global__ __launch_bounds__(256) void k_agg_bn_relu(
        const unsigned short* __restrict__ h, const int* __restrict__ rowptr,
        const uint2* __restrict__ epack, const unsigned short* __restrict__ sc,
        unsigned short* __restrict__ xp_out) {
    int node = blockIdx.x * 4 + (threadIdx.x >> 6);
    if (node >= N_NODES) return;
    const int lane = threadIdx.x & 63;
    const int e8 = lane >> 3, c8 = lane & 7;

    const int start = rowptr[node];
    const int cnt   = rowptr[node + 1] - start;   // includes self entry
    const uint2* ep = epack + start;
    const char*  hb = (const char*)h + c8 * 16;

    f16x2 a[4] = {(f16x2)0, (f16x2)0, (f16x2)0, (f16x2)0};

    auto batch = [&](int j) {
        int jj = j + e8;
        bool valid = jj < cnt;
        uint2 mv = ep[valid ? jj : 0];
        f16x2 w2 = bits2h2(valid ? mv.y : 0u);
        uint4 hv = *(const uint4*)(hb + mv.x);
        a[0] += bits2h2(hv.x) * w2;
        a[1] += bits2h2(hv.y) * w2;
        a[2] += bits2h2(hv.z) * w2;
        a[3] += bits2h2(hv.w) * w2;
    };

    int j = 0;
    for (; j + 8 < cnt; j += 16) { batch(j); batch(j + 8); }
    if (j < cnt) batch(j);

#pragma unroll
    for (int off = 8; off < 64; off <<= 1) {
#pragma unroll
        for (int i = 0; i < 4; ++i) {
            unsigned int u = __builtin_bit_cast(unsigned int, a[i]);
            a[i] += bits2h2((unsigned int)__shfl_xor((int)u, off));
        }
    }

    if (e8 == 0) {
        uint4 Su = *(const uint4*)(sc + c8 * 8);         // S, 8 cols
        uint4 Cu = *(const uint4*)(sc + 64 + c8 * 8);    // C, 8 cols
        unsigned int sw[4] = {Su.x, Su.y, Su.z, Su.w};
        unsigned int cw[4] = {Cu.x, Cu.y, Cu.z, Cu.w};
        unsigned int u[4];
#pragma unroll
        for (int p = 0; p < 4; ++p) {
            f16x2 r = a[p] * bits2h2(sw[p]) + bits2h2(cw[p]);
            r[0] = r[0] > (f16)0 ? r[0] : (f16)0;
            r[1] = r[1] > (f16)0 ? r[1] : (f16)0;
            u[p] = __builtin_bit_cast(unsigned int, r);
        }

        // fragment-packed store (T=2): cols c = c8*8 + 0..7 -> t=c8>>2, lh=c8&3
        int n16 = node & 15, rt2 = node >> 4;
        long base = (((long)rt2 * 2 + (c8 >> 2)) * 64 + (c8 & 3) * 16 + n16) * 8;
        *reinterpret_cast<uint4*>(xp_out + base) = make_uint4(u[0], u[1], u[2], u[3]);
    }
}

// ---------------- pull aggregation + bias + log_softmax -----------------------
__global__ __launch_bounds__(256) void k_agg_lsm(
        const unsigned short* __restrict__ h, const int* __restrict__ rowptr,
        const uint2* __restrict__ epack,
        const float* __restrict__ bias, float* __restrict__ out) {
    int node = blockIdx.x * 4 + (threadIdx.x >> 6);
    if (node >= N_NODES) return;
    const int lane = threadIdx.x & 63;
    const int e8 = lane >> 3, c8 = lane & 7;

    const int start = rowptr[node];
    const int cnt   = rowptr[node + 1] - start;   // includes self entry
    const uint2* ep = epack + start;
    const char*  hb = (const char*)h + c8 * 16;

    f16x2 a[4] = {(f16x2)0, (f16x2)0, (f16x2)0, (f16x2)0};

    auto batch = [&](int j) {
        int jj = j + e8;
        bool valid = jj < cnt;
        uint2 mv = ep[valid ? jj : 0];
        f16x2 w2 = bits2h2(valid ? mv.y : 0u);
        uint4 hv = *(const uint4*)(hb + mv.x);
        a[0] += bits2h2(hv.x) * w2;
        a[1] += bits2h2(hv.y) * w2;
        a[2] += bits2h2(hv.z) * w2;
        a[3] += bits2h2(hv.w) * w2;
    };

    int j = 0;
    for (; j + 8 < cnt; j += 16) { batch(j); batch(j + 8); }
    if (j < cnt) batch(j);

#pragma unroll
    for (int off = 8; off < 64; off <<= 1) {
#pragma unroll
        for (int i = 0; i < 4; ++i) {
            unsigned int u = __builtin_bit_cast(unsigned int, a[i]);
            a[i] += bits2h2((unsigned int)__shfl_xor((int)u, off));
        }
    }

    const bool ok = c8 < 5;                     // cols c8*8..+7 all < 40
    float av[8] = {(float)a[0][0], (float)a[0][1], (float)a[1][0], (float)a[1][1],
                   (float)a[2][0], (float)a[2][1], (float)a[3][0], (float)a[3][1]};
    float vals[8];
    float mx = -INFINITY;
    if (ok) {
        float4 bb0 = *(const float4*)(bias + c8 * 8), bb1 = *(const float4*)(bias + c8 * 8 + 4);
        float bbv[8] = {bb0.x, bb0.y, bb0.z, bb0.w, bb1.x, bb1.y, bb1.z, bb1.w};
#pragma unroll
        for (int i = 0; i < 8; ++i) {
            vals[i] = av[i] + bbv[i];
            mx = fmaxf(mx, vals[i]);
        }
    }
#pragma unroll
    for (int o = 1; o < 8; o <<= 1) mx = fmaxf(mx, __shfl_xor(mx, o));
    float es = 0.f;
    if (ok) {
#pragma unroll
        for (int i = 0; i < 8; ++i) es += expf(vals[i] - mx);
    }
#pragma unroll
    for (int o = 1; o < 8; o <<= 1) es += __shfl_xor(es, o);
    float ls = logf(es);

    if (e8 == 0 && ok) {
        float* op = out + (long)node * 40 + c8 * 8;
        *(float4*)op = make_float4(vals[0] - mx - ls, vals[1] - mx - ls,
                                   vals[2] - mx - ls, vals[3] - mx - ls);
        *(float4*)(op + 4) = make_float4(vals[4] - mx - ls, vals[5] - mx - ls,
                                         vals[6] - mx - ls, vals[7] - mx - ls);
    }
}

extern "C" void kernel_launch(void* const* d_in, const int* in_sizes, int n_in,
                              void* d_out, int out_size, void* d_ws, size_t ws_size,
                              hipStream_t stream) {
    const float* x   = (const float*)d_in[0];
    const int*   ei  = (const int*)d_in[1];
    const float* W1  = (const float*)d_in[2];
    const float* b1  = (const float*)d_in[3];
    const float* g1  = (const float*)d_in[4];
    const float* be1 = (const float*)d_in[5];
    const float* m1  = (const float*)d_in[6];
    const float* v1  = (const float*)d_in[7];
    const float* W2  = (const float*)d_in[8];
    const float* b2  = (const float*)d_in[9];
    const float* g2  = (const float*)d_in[10];
    const float* be2 = (const float*)d_in[11];
    const float* m2  = (const float*)d_in[12];
    const float* v2  = (const float*)d_in[13];
    const float* W3  = (const float*)d_in[14];
    const float* b3  = (const float*)d_in[15];
    float* out = (float*)d_out;

    // workspace layout (units: floats from base; all 16B-aligned)
    float* ws        = (float*)d_ws;
    float* dis       = ws;                            // 100096
    int*   degi      = (int*)(ws + 100096);
    int*   cursor    = (int*)(ws + 200192);
    int*   rowptr    = (int*)(ws + 300288);           // 100096 (incl sentinel)
    int*   blocksum  = (int*)(ws + 400384);           // 128
    int*   blockbase = (int*)(ws + 400512);           // 128
    uint2* epack     = (uint2*)(ws + 400640);         // (E+N) uint2 = 3.4M floats
    unsigned short* bufH = (unsigned short*)(ws + 3800640);    // N*64 f16
    unsigned short* xp2  = (unsigned short*)(ws + 32400640);   // NTILE*2*512 f16
    unsigned short* xp3  = (unsigned short*)(ws + 35600640);
    unsigned short* wb1  = (unsigned short*)(ws + 38800640);   // 32768 f16
    unsigned short* wb2  = (unsigned short*)(ws + 38817024);   // 4096
    unsigned short* wb3  = (unsigned short*)(ws + 38819072);   // 4096
    unsigned short* sc1  = (unsigned short*)(ws + 38821120);   // 128 f16
    unsigned short* sc2  = sc1 + 128;

    // ---- CSR build (self-loops included as explicit entries) ----
    hipMemsetAsync(degi, 0, 100096 * sizeof(int), stream);
    k_count_deg<<<cdiv(N_EDGES, 256), 256, 0, stream>>>(ei, degi);
    k_scan1<<<SCAN_NB, 256, 0, stream>>>(degi, rowptr, blocksum, dis);
    k_scan2<<<1, 128, 0, stream>>>(blocksum, blockbase);
    k_scan3<<<SCAN_NB, 256, 0, stream>>>(rowptr, blockbase, degi, cursor, epack);
    k_permute<<<cdiv(N_EDGES, 256), 256, 0, stream>>>(ei, rowptr, cursor, dis, epack);

    // ---- weight pack + BN fold ----
    k_convall<<<160, 256, 0, stream>>>(W1, W2, W3, wb1, wb2, wb3);
    k_bnfold<<<1, 128, 0, stream>>>(b1, g1, be1, m1, v1, b2, g2, be2, m2, v2, sc1, sc2);

    const int gemm_grid = cdiv(NTILE, 4);
    const int agg_grid  = cdiv(N_NODES, 4);

    // ---- layer 1: fused transpose+convert+GEMM (500 -> 64) ----
    k_l1fused<<<NTILE, 256, 0, stream>>>(x, wb1, bufH);
    k_agg_bn_relu<<<agg_grid, 256, 0, stream>>>(bufH, rowptr, epack, sc1, xp2);

    // ---- layer 2: 64 -> 64 ----
    k_gemm_packed<2><<<gemm_grid, 256, 0, stream>>>(xp2, wb2, bufH);
    k_agg_bn_relu<<<agg_grid, 256, 0, stream>>>(bufH, rowptr, epack, sc2, xp3);

    // ---- layer 3: 64 -> 40 (h stored 64-wide, cols 40..63 zero) ----
    k_gemm_packed<2><<<gemm_grid, 256, 0, stream>>>(xp3, wb3, bufH);
    k_agg_lsm<<<agg_grid, 256, 0, stream>>>(bufH, rowptr, epack, b3, out);
}

// Round 15
// 343.780 us; speedup vs baseline: 1.6746x; 1.0563x over previous
//
#include <hip/hip_runtime.h>
#include <math.h>

#define N_NODES 100000
#define N_EDGES 1600000
#define IN_DIM  500
#define HID     64
#define OUT_DIM 40
#define BN_EPS  1e-5f
#define SCAN_NB 98          // ceil(100000 / 1024)
#define NTILE   6250        // N_NODES / 16 (exact)

typedef _Float16 f16;
typedef __attribute__((ext_vector_type(2))) _Float16 f16x2;
typedef __attribute__((ext_vector_type(8))) _Float16 f16x8;
typedef __attribute__((ext_vector_type(4))) float f32x4;

static inline int cdiv(long a, int b) { return (int)((a + b - 1) / b); }

__device__ inline unsigned short f2h_bits(float f) {
    f16 h = (f16)f;
    return __builtin_bit_cast(unsigned short, h);
}
__device__ inline f16x2 bits2h2(unsigned int u) {
    return __builtin_bit_cast(f16x2, u);
}

// ---------------- integer in-degree ----------------
__global__ void k_count_deg(const int* __restrict__ ei, int* degi) {
    int e = blockIdx.x * 256 + threadIdx.x;
    if (e < N_EDGES) atomicAdd(&degi[ei[N_EDGES + e]], 1);
}

// ---------------- exclusive scan over (deg+1); also emits dis ----------------
__global__ void k_scan1(const int* __restrict__ degi, int* __restrict__ rowptr,
                        int* __restrict__ blocksum, float* __restrict__ dis) {
    __shared__ int sd[256];
    int tid = threadIdx.x;
    int base = blockIdx.x * 1024 + tid * 4;
    int v0 = (base + 0 < N_NODES) ? degi[base + 0] : -1;
    int v1 = (base + 1 < N_NODES) ? degi[base + 1] : -1;
    int v2 = (base + 2 < N_NODES) ? degi[base + 2] : -1;
    int v3 = (base + 3 < N_NODES) ? degi[base + 3] : -1;
    if (base + 0 < N_NODES) dis[base + 0] = rsqrtf((float)v0 + 1.0f);
    if (base + 1 < N_NODES) dis[base + 1] = rsqrtf((float)v1 + 1.0f);
    if (base + 2 < N_NODES) dis[base + 2] = rsqrtf((float)v2 + 1.0f);
    if (base + 3 < N_NODES) dis[base + 3] = rsqrtf((float)v3 + 1.0f);
    int w0 = v0 + 1, w1 = v1 + 1, w2 = v2 + 1, w3 = v3 + 1;   // deg+1 (0 if OOB)
    int s = w0 + w1 + w2 + w3;
    sd[tid] = s;
    __syncthreads();
    for (int off = 1; off < 256; off <<= 1) {
        int t = (tid >= off) ? sd[tid - off] : 0;
        __syncthreads();
        sd[tid] += t;
        __syncthreads();
    }
    int excl = sd[tid] - s;
    if (base + 0 < N_NODES) rowptr[base + 0] = excl;
    if (base + 1 < N_NODES) rowptr[base + 1] = excl + w0;
    if (base + 2 < N_NODES) rowptr[base + 2] = excl + w0 + w1;
    if (base + 3 < N_NODES) rowptr[base + 3] = excl + w0 + w1 + w2;
    if (tid == 255) blocksum[blockIdx.x] = sd[255];
}

__global__ void k_scan2(int* __restrict__ blocksum, int* __restrict__ blockbase) {
    __shared__ int sd[128];
    int tid = threadIdx.x;
    int v = (tid < SCAN_NB) ? blocksum[tid] : 0;
    sd[tid] = v;
    __syncthreads();
    for (int off = 1; off < 128; off <<= 1) {
        int t = (tid >= off) ? sd[tid - off] : 0;
        __syncthreads();
        sd[tid] += t;
        __syncthreads();
    }
    if (tid < SCAN_NB) blockbase[tid] = sd[tid] - v;
}

// scan3: finalize rowptr, write self-loop CSR entry + cursor=1, sentinel.
__global__ void k_scan3(int* __restrict__ rowptr, const int* __restrict__ blockbase,
                        const int* __restrict__ degi, int* __restrict__ cursor,
                        uint2* __restrict__ epack) {
    int add = blockbase[blockIdx.x];
    int base = blockIdx.x * 1024 + threadIdx.x * 4;
#pragma unroll
    for (int i = 0; i < 4; ++i) {
        int node = base + i;
        if (node < N_NODES) {
            int rp = rowptr[node] + add;
            rowptr[node] = rp;
            float d2 = 1.0f / (float)(degi[node] + 1);   // dis^2 exactly
            unsigned int hb = f2h_bits(d2);
            epack[rp] = make_uint2((unsigned int)(node * 128), (hb << 16) | hb);
            cursor[node] = 1;
        }
    }
    if (blockIdx.x == 0 && threadIdx.x == 0)
        rowptr[N_NODES] = N_EDGES + N_NODES;   // sentinel
}

// ---------------- CSR permute: group edges by dst, packed meta ----------------
__global__ void k_permute(const int* __restrict__ ei, const int* __restrict__ rowptr,
                          int* __restrict__ cursor, const float* __restrict__ dis,
                          uint2* __restrict__ epack) {
    int e = blockIdx.x * 256 + threadIdx.x;
    if (e >= N_EDGES) return;
    int s = ei[e];
    int d = ei[N_EDGES + e];
    int pos = rowptr[d] + atomicAdd(&cursor[d], 1);
    unsigned int hb = f2h_bits(dis[s] * dis[d]);
    epack[pos] = make_uint2((unsigned int)(s * 128), (hb << 16) | hb);
}

// ---------------- weight pack (all 3 layers, one dispatch) -------------------
__device__ inline void convW_one(const float* W, unsigned short* wb,
                                 int idx, int K, int F) {
    int j    = idx & 7;
    int lane = (idx >> 3) & 63;
    int q    = idx >> 9;             // t*4 + nt
    int t    = q >> 2, nt = q & 3;
    int n = nt * 16 + (lane & 15);
    int k = t * 32 + ((lane >> 4) << 3) + j;
    float v = (k < K && n < F) ? W[(long)k * F + n] : 0.f;
    wb[idx] = f2h_bits(v);
}

__global__ void k_convall(const float* __restrict__ W1, const float* __restrict__ W2,
                          const float* __restrict__ W3,
                          unsigned short* __restrict__ wb1,
                          unsigned short* __restrict__ wb2,
                          unsigned short* __restrict__ wb3) {
    int idx = blockIdx.x * 256 + threadIdx.x;   // 160*256 = 40960
    if (idx < 32768) {
        convW_one(W1, wb1, idx, IN_DIM, HID);
    } else if (idx < 36864) {
        convW_one(W2, wb2, idx - 32768, HID, HID);
    } else {
        convW_one(W3, wb3, idx - 36864, HID, OUT_DIM);
    }
}

// ---------------- BN fold: S = g*rsqrt(v+eps); C = (b-m)*S + be  (f16) -------
__global__ void k_bnfold(const float* __restrict__ b1, const float* __restrict__ g1,
                         const float* __restrict__ be1, const float* __restrict__ m1,
                         const float* __restrict__ v1,
                         const float* __restrict__ b2, const float* __restrict__ g2,
                         const float* __restrict__ be2, const float* __restrict__ m2,
                         const float* __restrict__ v2,
                         unsigned short* __restrict__ sc1,
                         unsigned short* __restrict__ sc2) {
    int t = threadIdx.x;   // 0..127
    int c = t & 63;
    const float *b, *g, *be, *m, *v;
    unsigned short* sc;
    if (t < 64) { b = b1; g = g1; be = be1; m = m1; v = v1; sc = sc1; }
    else        { b = b2; g = g2; be = be2; m = m2; v = v2; sc = sc2; }
    float S = g[c] * rsqrtf(v[c] + BN_EPS);
    float C = (b[c] - m[c]) * S + be[c];
    sc[c]      = f2h_bits(S);
    sc[64 + c] = f2h_bits(C);
}

// ---------------- fused layer-1: stage 16 rows of x in LDS, MFMA vs W1 -------
__global__ __launch_bounds__(256) void k_l1fused(
        const float* __restrict__ x,
        const unsigned short* __restrict__ wb,
        unsigned short* __restrict__ h) {
    __shared__ unsigned short l[16 * 520];
    const int rt = blockIdx.x;
    const int tid = threadIdx.x;

#pragma unroll
    for (int it = 0; it < 8; ++it) {
        int slot = it * 256 + tid;
        int row = slot >> 7, kq = slot & 127;
        float4 v = make_float4(0.f, 0.f, 0.f, 0.f);
        if (kq < 125)
            v = *reinterpret_cast<const float4*>(x + ((long)rt * 16 + row) * IN_DIM + kq * 4);
        unsigned int u0 = (unsigned int)f2h_bits(v.x) | ((unsigned int)f2h_bits(v.y) << 16);
        unsigned int u1 = (unsigned int)f2h_bits(v.z) | ((unsigned int)f2h_bits(v.w) << 16);
        *reinterpret_cast<uint2*>(&l[row * 520 + kq * 4]) = make_uint2(u0, u1);
    }
    __syncthreads();

    const int wid  = tid >> 6;
    const int lane = tid & 63;
    const int l15  = lane & 15;
    const int lhi  = lane >> 4;

    const f16x8* bp = reinterpret_cast<const f16x8*>(wb) + wid * 64 + lane;
    const unsigned short* arow = &l[l15 * 520 + lhi * 8];

    f32x4 acc = (f32x4){0.f, 0.f, 0.f, 0.f};
    f16x8 ca = *reinterpret_cast<const f16x8*>(arow);
    f16x8 cb = bp[0];

#pragma unroll
    for (int t = 0; t < 16; ++t) {
        f16x8 na, nb;
        if (t < 15) {
            na = *reinterpret_cast<const f16x8*>(arow + (t + 1) * 32);
            nb = bp[(t + 1) * 256];
        }
        acc = __builtin_amdgcn_mfma_f32_16x16x32_f16(ca, cb, acc, 0, 0, 0);
        if (t < 15) { ca = na; cb = nb; }
    }

#pragma unroll
    for (int rr = 0; rr < 4; ++rr) {
        long grow = (long)rt * 16 + lhi * 4 + rr;
        h[grow * 64 + wid * 16 + l15] = f2h_bits(acc[rr]);
    }
}

// ---------------- fused agg + BN/ReLU + GEMM --------------------------------
// Block = 16 nodes, 4 waves. Phase 1: wave w aggregates nodes base+w*4..+3
// (e8 x c8 gather, butterfly over e8), applies folded BN+ReLU, stores the
// 16x64 f16 tile in LDS (stride 80 f16 = 160 B, 16B-aligned rows). Phase 2:
// wave w MFMAs the tile against packed W cols w*16..+15 (2 k-steps) and
// writes h_out row-major. Kills the xp intermediate + separate GEMM dispatch.
__global__ __launch_bounds__(256) void k_agg_gemm(
        const unsigned short* __restrict__ h_in, const int* __restrict__ rowptr,
        const uint2* __restrict__ epack, const unsigned short* __restrict__ sc,
        const unsigned short* __restrict__ wb, unsigned short* __restrict__ h_out) {
    __shared__ unsigned short st[16 * 80];
    const int base = blockIdx.x * 16;
    const int tid  = threadIdx.x;
    const int wid  = tid >> 6;
    const int lane = tid & 63;
    const int e8 = lane >> 3, c8 = lane & 7;

    // phase 1: aggregate 4 nodes per wave
    for (int sub = 0; sub < 4; ++sub) {
        const int node  = base + wid * 4 + sub;
        const int start = rowptr[node];
        const int cnt   = rowptr[node + 1] - start;   // includes self entry
        const uint2* ep = epack + start;
        const char*  hb = (const char*)h_in + c8 * 16;

        f16x2 a[4] = {(f16x2)0, (f16x2)0, (f16x2)0, (f16x2)0};

        auto batch = [&](int j) {
            int jj = j + e8;
            bool valid = jj < cnt;
            uint2 mv = ep[valid ? jj : 0];
            f16x2 w2 = bits2h2(valid ? mv.y : 0u);
            uint4 hv = *(const uint4*)(hb + mv.x);
            a[0] += bits2h2(hv.x) * w2;
            a[1] += bits2h2(hv.y) * w2;
            a[2] += bits2h2(hv.z) * w2;
            a[3] += bits2h2(hv.w) * w2;
        };

        int j = 0;
        for (; j + 8 < cnt; j += 16) { batch(j); batch(j + 8); }
        if (j < cnt) batch(j);

#pragma unroll
        for (int off = 8; off < 64; off <<= 1) {
#pragma unroll
            for (int i = 0; i < 4; ++i) {
                unsigned int u = __builtin_bit_cast(unsigned int, a[i]);
                a[i] += bits2h2((unsigned int)__shfl_xor((int)u, off));
            }
        }

        if (e8 == 0) {
            uint4 Su = *(const uint4*)(sc + c8 * 8);
            uint4 Cu = *(const uint4*)(sc + 64 + c8 * 8);
            unsigned int sw[4] = {Su.x, Su.y, Su.z, Su.w};
            unsigned int cw[4] = {Cu.x, Cu.y, Cu.z, Cu.w};
            unsigned int u[4];
#pragma unroll
            for (int p = 0; p < 4; ++p) {
                f16x2 r = a[p] * bits2h2(sw[p]) + bits2h2(cw[p]);
                r[0] = r[0] > (f16)0 ? r[0] : (f16)0;
                r[1] = r[1] > (f16)0 ? r[1] : (f16)0;
                u[p] = __builtin_bit_cast(unsigned int, r);
            }
            int row = wid * 4 + sub;
            *reinterpret_cast<uint4*>(&st[row * 80 + c8 * 8]) =
                make_uint4(u[0], u[1], u[2], u[3]);
        }
    }
    __syncthreads();

    // phase 2: 16x64 tile @ W cols wid*16..+15 (A row = l15, k = lhi*8 + t*32)
    const int l15 = lane & 15, lhi = lane >> 4;
    const unsigned short* arow = &st[l15 * 80 + lhi * 8];
    const f16x8* bp = reinterpret_cast<const f16x8*>(wb) + wid * 64 + lane;

    f32x4 acc = (f32x4){0.f, 0.f, 0.f, 0.f};
    f16x8 a0 = *reinterpret_cast<const f16x8*>(arow);
    f16x8 a1 = *reinterpret_cast<const f16x8*>(arow + 32);
    f16x8 b0 = bp[0];
    f16x8 b1 = bp[256];
    acc = __builtin_amdgcn_mfma_f32_16x16x32_f16(a0, b0, acc, 0, 0, 0);
    acc = __builtin_amdgcn_mfma_f32_16x16x32_f16(a1, b1, acc, 0, 0, 0);

#pragma unroll
    for (int rr = 0; rr < 4; ++rr) {
        long grow = (long)base + lhi * 4 + rr;
        h_out[grow * 64 + wid * 16 + l15] = f2h_bits(acc[rr]);
    }
}

// ---------------- pull aggregation + bias + log_softmax -----------------------
__global__ __launch_bounds__(256) void k_agg_lsm(
        const unsigned short* __restrict__ h, const int* __restrict__ rowptr,
        const uint2* __restrict__ epack,
        const float* __restrict__ bias, float* __restrict__ out) {
    int node = blockIdx.x * 4 + (threadIdx.x >> 6);
    if (node >= N_NODES) return;
    const int lane = threadIdx.x & 63;
    const int e8 = lane >> 3, c8 = lane & 7;

    const int start = rowptr[node];
    const int cnt   = rowptr[node + 1] - start;   // includes self entry
    const uint2* ep = epack + start;
    const char*  hb = (const char*)h + c8 * 16;

    f16x2 a[4] = {(f16x2)0, (f16x2)0, (f16x2)0, (f16x2)0};

    auto batch = [&](int j) {
        int jj = j + e8;
        bool valid = jj < cnt;
        uint2 mv = ep[valid ? jj : 0];
        f16x2 w2 = bits2h2(valid ? mv.y : 0u);
        uint4 hv = *(const uint4*)(hb + mv.x);
        a[0] += bits2h2(hv.x) * w2;
        a[1] += bits2h2(hv.y) * w2;
        a[2] += bits2h2(hv.z) * w2;
        a[3] += bits2h2(hv.w) * w2;
    };

    int j = 0;
    for (; j + 8 < cnt; j += 16) { batch(j); batch(j + 8); }
    if (j < cnt) batch(j);

#pragma unroll
    for (int off = 8; off < 64; off <<= 1) {
#pragma unroll
        for (int i = 0; i < 4; ++i) {
            unsigned int u = __builtin_bit_cast(unsigned int, a[i]);
            a[i] += bits2h2((unsigned int)__shfl_xor((int)u, off));
        }
    }

    const bool ok = c8 < 5;                     // cols c8*8..+7 all < 40
    float av[8] = {(float)a[0][0], (float)a[0][1], (float)a[1][0], (float)a[1][1],
                   (float)a[2][0], (float)a[2][1], (float)a[3][0], (float)a[3][1]};
    float vals[8];
    float mx = -INFINITY;
    if (ok) {
        float4 bb0 = *(const float4*)(bias + c8 * 8), bb1 = *(const float4*)(bias + c8 * 8 + 4);
        float bbv[8] = {bb0.x, bb0.y, bb0.z, bb0.w, bb1.x, bb1.y, bb1.z, bb1.w};
#pragma unroll
        for (int i = 0; i < 8; ++i) {
            vals[i] = av[i] + bbv[i];
            mx = fmaxf(mx, vals[i]);
        }
    }
#pragma unroll
    for (int o = 1; o < 8; o <<= 1) mx = fmaxf(mx, __shfl_xor(mx, o));
    float es = 0.f;
    if (ok) {
#pragma unroll
        for (int i = 0; i < 8; ++i) es += expf(vals[i] - mx);
    }
#pragma unroll
    for (int o = 1; o < 8; o <<= 1) es += __shfl_xor(es, o);
    float ls = logf(es);

    if (e8 == 0 && ok) {
        float* op = out + (long)node * 40 + c8 * 8;
        *(float4*)op = make_float4(vals[0] - mx - ls, vals[1] - mx - ls,
                                   vals[2] - mx - ls, vals[3] - mx - ls);
        *(float4*)(op + 4) = make_float4(vals[4] - mx - ls, vals[5] - mx - ls,
                                         vals[6] - mx - ls, vals[7] - mx - ls);
    }
}

extern "C" void kernel_launch(void* const* d_in, const int* in_sizes, int n_in,
                              void* d_out, int out_size, void* d_ws, size_t ws_size,
                              hipStream_t stream) {
    const float* x   = (const float*)d_in[0];
    const int*   ei  = (const int*)d_in[1];
    const float* W1  = (const float*)d_in[2];
    const float* b1  = (const float*)d_in[3];
    const float* g1  = (const float*)d_in[4];
    const float* be1 = (const float*)d_in[5];
    const float* m1  = (const float*)d_in[6];
    const float* v1  = (const float*)d_in[7];
    const float* W2  = (const float*)d_in[8];
    const float* b2  = (const float*)d_in[9];
    const float* g2  = (const float*)d_in[10];
    const float* be2 = (const float*)d_in[11];
    const float* m2  = (const float*)d_in[12];
    const float* v2  = (const float*)d_in[13];
    const float* W3  = (const float*)d_in[14];
    const float* b3  = (const float*)d_in[15];
    float* out = (float*)d_out;

    // workspace layout (units: floats from base; all 16B-aligned)
    float* ws        = (float*)d_ws;
    float* dis       = ws;                            // 100096
    int*   degi      = (int*)(ws + 100096);
    int*   cursor    = (int*)(ws + 200192);
    int*   rowptr    = (int*)(ws + 300288);           // 100096 (incl sentinel)
    int*   blocksum  = (int*)(ws + 400384);           // 128
    int*   blockbase = (int*)(ws + 400512);           // 128
    uint2* epack     = (uint2*)(ws + 400640);         // (E+N) uint2 = 3.4M floats
    unsigned short* h1 = (unsigned short*)(ws + 3800640);     // N*64 f16
    unsigned short* h2 = (unsigned short*)(ws + 7000640);
    unsigned short* h3 = (unsigned short*)(ws + 10200640);
    unsigned short* wb1 = (unsigned short*)(ws + 13400640);   // 32768 f16
    unsigned short* wb2 = (unsigned short*)(ws + 13417024);   // 4096
    unsigned short* wb3 = (unsigned short*)(ws + 13419072);   // 4096
    unsigned short* sc1 = (unsigned short*)(ws + 13421120);   // 128 f16
    unsigned short* sc2 = sc1 + 128;

    // ---- CSR build (self-loops included as explicit entries) ----
    hipMemsetAsync(degi, 0, 100096 * sizeof(int), stream);
    k_count_deg<<<cdiv(N_EDGES, 256), 256, 0, stream>>>(ei, degi);
    k_scan1<<<SCAN_NB, 256, 0, stream>>>(degi, rowptr, blocksum, dis);
    k_scan2<<<1, 128, 0, stream>>>(blocksum, blockbase);
    k_scan3<<<SCAN_NB, 256, 0, stream>>>(rowptr, blockbase, degi, cursor, epack);
    k_permute<<<cdiv(N_EDGES, 256), 256, 0, stream>>>(ei, rowptr, cursor, dis, epack);

    // ---- weight pack + BN fold ----
    k_convall<<<160, 256, 0, stream>>>(W1, W2, W3, wb1, wb2, wb3);
    k_bnfold<<<1, 128, 0, stream>>>(b1, g1, be1, m1, v1, b2, g2, be2, m2, v2, sc1, sc2);

    const int agg_grid = cdiv(N_NODES, 4);

    // ---- layer 1: fused transpose+convert+GEMM (500 -> 64) ----
    k_l1fused<<<NTILE, 256, 0, stream>>>(x, wb1, h1);

    // ---- agg1 + BN1/ReLU + GEMM2 (fused) ----
    k_agg_gemm<<<NTILE, 256, 0, stream>>>(h1, rowptr, epack, sc1, wb2, h2);

    // ---- agg2 + BN2/ReLU + GEMM3 (fused; h3 64-wide, cols 40..63 zero) ----
    k_agg_gemm<<<NTILE, 256, 0, stream>>>(h2, rowptr, epack, sc2, wb3, h3);

    // ---- agg3 + bias + log_softmax ----
    k_agg_lsm<<<agg_grid, 256, 0, stream>>>(h3, rowptr, epack, b3, out);
}

// Round 16
// 334.838 us; speedup vs baseline: 1.7193x; 1.0267x over previous
//
#include <hip/hip_runtime.h>
#include <math.h>

#define N_NODES 100000
#define N_EDGES 1600000
#define IN_DIM  500
#define HID     64
#define OUT_DIM 40
#define BN_EPS  1e-5f
#define SCAN_NB 98          // ceil(100000 / 1024)
#define NTILE   6250        // N_NODES / 16 (exact)

typedef _Float16 f16;
typedef __attribute__((ext_vector_type(2))) _Float16 f16x2;
typedef __attribute__((ext_vector_type(8))) _Float16 f16x8;
typedef __attribute__((ext_vector_type(4))) float f32x4;

static inline int cdiv(long a, int b) { return (int)((a + b - 1) / b); }

__device__ inline unsigned short f2h_bits(float f) {
    f16 h = (f16)f;
    return __builtin_bit_cast(unsigned short, h);
}
__device__ inline f16x2 bits2h2(unsigned int u) {
    return __builtin_bit_cast(f16x2, u);
}

// ---------------- integer in-degree ----------------
__global__ void k_count_deg(const int* __restrict__ ei, int* degi) {
    int e = blockIdx.x * 256 + threadIdx.x;
    if (e < N_EDGES) atomicAdd(&degi[ei[N_EDGES + e]], 1);
}

// ---------------- exclusive scan over (deg+1); also emits dis ----------------
__global__ void k_scan1(const int* __restrict__ degi, int* __restrict__ rowptr,
                        int* __restrict__ blocksum, float* __restrict__ dis) {
    __shared__ int sd[256];
    int tid = threadIdx.x;
    int base = blockIdx.x * 1024 + tid * 4;
    int v0 = (base + 0 < N_NODES) ? degi[base + 0] : -1;
    int v1 = (base + 1 < N_NODES) ? degi[base + 1] : -1;
    int v2 = (base + 2 < N_NODES) ? degi[base + 2] : -1;
    int v3 = (base + 3 < N_NODES) ? degi[base + 3] : -1;
    if (base + 0 < N_NODES) dis[base + 0] = rsqrtf((float)v0 + 1.0f);
    if (base + 1 < N_NODES) dis[base + 1] = rsqrtf((float)v1 + 1.0f);
    if (base + 2 < N_NODES) dis[base + 2] = rsqrtf((float)v2 + 1.0f);
    if (base + 3 < N_NODES) dis[base + 3] = rsqrtf((float)v3 + 1.0f);
    int w0 = v0 + 1, w1 = v1 + 1, w2 = v2 + 1, w3 = v3 + 1;   // deg+1 (0 if OOB)
    int s = w0 + w1 + w2 + w3;
    sd[tid] = s;
    __syncthreads();
    for (int off = 1; off < 256; off <<= 1) {
        int t = (tid >= off) ? sd[tid - off] : 0;
        __syncthreads();
        sd[tid] += t;
        __syncthreads();
    }
    int excl = sd[tid] - s;
    if (base + 0 < N_NODES) rowptr[base + 0] = excl;
    if (base + 1 < N_NODES) rowptr[base + 1] = excl + w0;
    if (base + 2 < N_NODES) rowptr[base + 2] = excl + w0 + w1;
    if (base + 3 < N_NODES) rowptr[base + 3] = excl + w0 + w1 + w2;
    if (tid == 255) blocksum[blockIdx.x] = sd[255];
}

__global__ void k_scan2(int* __restrict__ blocksum, int* __restrict__ blockbase) {
    __shared__ int sd[128];
    int tid = threadIdx.x;
    int v = (tid < SCAN_NB) ? blocksum[tid] : 0;
    sd[tid] = v;
    __syncthreads();
    for (int off = 1; off < 128; off <<= 1) {
        int t = (tid >= off) ? sd[tid - off] : 0;
        __syncthreads();
        sd[tid] += t;
        __syncthreads();
    }
    if (tid < SCAN_NB) blockbase[tid] = sd[tid] - v;
}

// scan3: finalize rowptr, write self-loop CSR entry + cursor=1, sentinel.
__global__ void k_scan3(int* __restrict__ rowptr, const int* __restrict__ blockbase,
                        const int* __restrict__ degi, int* __restrict__ cursor,
                        uint2* __restrict__ epack) {
    int add = blockbase[blockIdx.x];
    int base = blockIdx.x * 1024 + threadIdx.x * 4;
#pragma unroll
    for (int i = 0; i < 4; ++i) {
        int node = base + i;
        if (node < N_NODES) {
            int rp = rowptr[node] + add;
            rowptr[node] = rp;
            float d2 = 1.0f / (float)(degi[node] + 1);   // dis^2 exactly
            unsigned int hb = f2h_bits(d2);
            epack[rp] = make_uint2((unsigned int)(node * 128), (hb << 16) | hb);
            cursor[node] = 1;
        }
    }
    if (blockIdx.x == 0 && threadIdx.x == 0)
        rowptr[N_NODES] = N_EDGES + N_NODES;   // sentinel
}

// ---------------- CSR permute: group edges by dst, packed meta ----------------
__global__ void k_permute(const int* __restrict__ ei, const int* __restrict__ rowptr,
                          int* __restrict__ cursor, const float* __restrict__ dis,
                          uint2* __restrict__ epack) {
    int e = blockIdx.x * 256 + threadIdx.x;
    if (e >= N_EDGES) return;
    int s = ei[e];
    int d = ei[N_EDGES + e];
    int pos = rowptr[d] + atomicAdd(&cursor[d], 1);
    unsigned int hb = f2h_bits(dis[s] * dis[d]);
    epack[pos] = make_uint2((unsigned int)(s * 128), (hb << 16) | hb);
}

// ---------------- weight pack (all 3 layers, one dispatch) -------------------
__device__ inline void convW_one(const float* W, unsigned short* wb,
                                 int idx, int K, int F) {
    int j    = idx & 7;
    int lane = (idx >> 3) & 63;
    int q    = idx >> 9;             // t*4 + nt
    int t    = q >> 2, nt = q & 3;
    int n = nt * 16 + (lane & 15);
    int k = t * 32 + ((lane >> 4) << 3) + j;
    float v = (k < K && n < F) ? W[(long)k * F + n] : 0.f;
    wb[idx] = f2h_bits(v);
}

__global__ void k_convall(const float* __restrict__ W1, const float* __restrict__ W2,
                          const float* __restrict__ W3,
                          unsigned short* __restrict__ wb1,
                          unsigned short* __restrict__ wb2,
                          unsigned short* __restrict__ wb3) {
    int idx = blockIdx.x * 256 + threadIdx.x;   // 160*256 = 40960
    if (idx < 32768) {
        convW_one(W1, wb1, idx, IN_DIM, HID);
    } else if (idx < 36864) {
        convW_one(W2, wb2, idx - 32768, HID, HID);
    } else {
        convW_one(W3, wb3, idx - 36864, HID, OUT_DIM);
    }
}

// ---------------- BN fold: S = g*rsqrt(v+eps); C = (b-m)*S + be  (f16) -------
__global__ void k_bnfold(const float* __restrict__ b1, const float* __restrict__ g1,
                         const float* __restrict__ be1, const float* __restrict__ m1,
                         const float* __restrict__ v1,
                         const float* __restrict__ b2, const float* __restrict__ g2,
                         const float* __restrict__ be2, const float* __restrict__ m2,
                         const float* __restrict__ v2,
                         unsigned short* __restrict__ sc1,
                         unsigned short* __restrict__ sc2) {
    int t = threadIdx.x;   // 0..127
    int c = t & 63;
    const float *b, *g, *be, *m, *v;
    unsigned short* sc;
    if (t < 64) { b = b1; g = g1; be = be1; m = m1; v = v1; sc = sc1; }
    else        { b = b2; g = g2; be = be2; m = m2; v = v2; sc = sc2; }
    float S = g[c] * rsqrtf(v[c] + BN_EPS);
    float C = (b[c] - m[c]) * S + be[c];
    sc[c]      = f2h_bits(S);
    sc[64 + c] = f2h_bits(C);
}

// ---------------- fused layer-1: stage 16 rows of x in LDS, MFMA vs W1 -------
__global__ __launch_bounds__(256) void k_l1fused(
        const float* __restrict__ x,
        const unsigned short* __restrict__ wb,
        unsigned short* __restrict__ h) {
    __shared__ unsigned short l[16 * 520];
    const int rt = blockIdx.x;
    const int tid = threadIdx.x;

#pragma unroll
    for (int it = 0; it < 8; ++it) {
        int slot = it * 256 + tid;
        int row = slot >> 7, kq = slot & 127;
        float4 v = make_float4(0.f, 0.f, 0.f, 0.f);
        if (kq < 125)
            v = *reinterpret_cast<const float4*>(x + ((long)rt * 16 + row) * IN_DIM + kq * 4);
        unsigned int u0 = (unsigned int)f2h_bits(v.x) | ((unsigned int)f2h_bits(v.y) << 16);
        unsigned int u1 = (unsigned int)f2h_bits(v.z) | ((unsigned int)f2h_bits(v.w) << 16);
        *reinterpret_cast<uint2*>(&l[row * 520 + kq * 4]) = make_uint2(u0, u1);
    }
    __syncthreads();

    const int wid  = tid >> 6;
    const int lane = tid & 63;
    const int l15  = lane & 15;
    const int lhi  = lane >> 4;

    const f16x8* bp = reinterpret_cast<const f16x8*>(wb) + wid * 64 + lane;
    const unsigned short* arow = &l[l15 * 520 + lhi * 8];

    f32x4 acc = (f32x4){0.f, 0.f, 0.f, 0.f};
    f16x8 ca = *reinterpret_cast<const f16x8*>(arow);
    f16x8 cb = bp[0];

#pragma unroll
    for (int t = 0; t < 16; ++t) {
        f16x8 na, nb;
        if (t < 15) {
            na = *reinterpret_cast<const f16x8*>(arow + (t + 1) * 32);
            nb = bp[(t + 1) * 256];
        }
        acc = __builtin_amdgcn_mfma_f32_16x16x32_f16(ca, cb, acc, 0, 0, 0);
        if (t < 15) { ca = na; cb = nb; }
    }

#pragma unroll
    for (int rr = 0; rr < 4; ++rr) {
        long grow = (long)rt * 16 + lhi * 4 + rr;
        h[grow * 64 + wid * 16 + l15] = f2h_bits(acc[rr]);
    }
}

// ---------------- fused agg + BN/ReLU + GEMM --------------------------------
// Block = 16 nodes, 4 waves. Phase 1: wave w aggregates its 4 nodes
// CONCURRENTLY (a[4][4] in regs, one j-loop over max cnt, all 4 segments
// predicated per iteration -> 4 independent meta->gather chains in flight).
// Butterfly + folded BN/ReLU once at the end; 16x64 f16 tile in LDS.
// Phase 2: wave w MFMAs the tile against packed W cols w*16..+15.
__global__ __launch_bounds__(256) void k_agg_gemm(
        const unsigned short* __restrict__ h_in, const int* __restrict__ rowptr,
        const uint2* __restrict__ epack, const unsigned short* __restrict__ sc,
        const unsigned short* __restrict__ wb, unsigned short* __restrict__ h_out) {
    __shared__ unsigned short st[16 * 80];
    const int base = blockIdx.x * 16;
    const int tid  = threadIdx.x;
    const int wid  = tid >> 6;
    const int lane = tid & 63;
    const int e8 = lane >> 3, c8 = lane & 7;
    const int node0 = base + wid * 4;

    int start[4], cnt[4];
    {
        int r0 = rowptr[node0 + 0], r1 = rowptr[node0 + 1], r2 = rowptr[node0 + 2];
        int r3 = rowptr[node0 + 3], r4 = rowptr[node0 + 4];
        start[0] = r0; cnt[0] = r1 - r0;
        start[1] = r1; cnt[1] = r2 - r1;
        start[2] = r2; cnt[2] = r3 - r2;
        start[3] = r3; cnt[3] = r4 - r3;
    }
    const char* hb = (const char*)h_in + c8 * 16;

    f16x2 a[4][4];
#pragma unroll
    for (int s = 0; s < 4; ++s)
#pragma unroll
        for (int i = 0; i < 4; ++i) a[s][i] = (f16x2)0;

    int maxc = max(max(cnt[0], cnt[1]), max(cnt[2], cnt[3]));

    for (int j = 0; j < maxc; j += 8) {
        int jj = j + e8;
#pragma unroll
        for (int s = 0; s < 4; ++s) {
            bool valid = jj < cnt[s];
            uint2 mv = epack[start[s] + (valid ? jj : 0)];
            f16x2 w2 = bits2h2(valid ? mv.y : 0u);
            uint4 hv = *(const uint4*)(hb + mv.x);
            a[s][0] += bits2h2(hv.x) * w2;
            a[s][1] += bits2h2(hv.y) * w2;
            a[s][2] += bits2h2(hv.z) * w2;
            a[s][3] += bits2h2(hv.w) * w2;
        }
    }

#pragma unroll
    for (int off = 8; off < 64; off <<= 1) {
#pragma unroll
        for (int s = 0; s < 4; ++s)
#pragma unroll
            for (int i = 0; i < 4; ++i) {
                unsigned int u = __builtin_bit_cast(unsigned int, a[s][i]);
                a[s][i] += bits2h2((unsigned int)__shfl_xor((int)u, off));
            }
    }

    if (e8 == 0) {
        uint4 Su = *(const uint4*)(sc + c8 * 8);
        uint4 Cu = *(const uint4*)(sc + 64 + c8 * 8);
        unsigned int sw[4] = {Su.x, Su.y, Su.z, Su.w};
        unsigned int cw[4] = {Cu.x, Cu.y, Cu.z, Cu.w};
#pragma unroll
        for (int s = 0; s < 4; ++s) {
            unsigned int u[4];
#pragma unroll
            for (int p = 0; p < 4; ++p) {
                f16x2 r = a[s][p] * bits2h2(sw[p]) + bits2h2(cw[p]);
                r[0] = r[0] > (f16)0 ? r[0] : (f16)0;
                r[1] = r[1] > (f16)0 ? r[1] : (f16)0;
                u[p] = __builtin_bit_cast(unsigned int, r);
            }
            int row = wid * 4 + s;
            *reinterpret_cast<uint4*>(&st[row * 80 + c8 * 8]) =
                make_uint4(u[0], u[1], u[2], u[3]);
        }
    }
    __syncthreads();

    // phase 2: 16x64 tile @ W cols wid*16..+15 (A row = l15, k = lhi*8 + t*32)
    const int l15 = lane & 15, lhi = lane >> 4;
    const unsigned short* arow = &st[l15 * 80 + lhi * 8];
    const f16x8* bp = reinterpret_cast<const f16x8*>(wb) + wid * 64 + lane;

    f32x4 acc = (f32x4){0.f, 0.f, 0.f, 0.f};
    f16x8 a0 = *reinterpret_cast<const f16x8*>(arow);
    f16x8 a1 = *reinterpret_cast<const f16x8*>(arow + 32);
    f16x8 b0 = bp[0];
    f16x8 b1 = bp[256];
    acc = __builtin_amdgcn_mfma_f32_16x16x32_f16(a0, b0, acc, 0, 0, 0);
    acc = __builtin_amdgcn_mfma_f32_16x16x32_f16(a1, b1, acc, 0, 0, 0);

#pragma unroll
    for (int rr = 0; rr < 4; ++rr) {
        long grow = (long)base + lhi * 4 + rr;
        h_out[grow * 64 + wid * 16 + l15] = f2h_bits(acc[rr]);
    }
}

// ---------------- pull aggregation + bias + log_softmax -----------------------
// c8>=5 lanes (cols 40..63, known zero) gather a fixed row-0 line (w=0):
// random traffic x5/8. Up to 4 gather rounds issued up-front (deg<=31 covered).
__global__ __launch_bounds__(256) void k_agg_lsm(
        const unsigned short* __restrict__ h, const int* __restrict__ rowptr,
        const uint2* __restrict__ epack,
        const float* __restrict__ bias, float* __restrict__ out) {
    int node = blockIdx.x * 4 + (threadIdx.x >> 6);
    if (node >= N_NODES) return;
    const int lane = threadIdx.x & 63;
    const int e8 = lane >> 3, c8 = lane & 7;
    const bool okc = c8 < 5;

    const int start = rowptr[node];
    const int cnt   = rowptr[node + 1] - start;   // includes self entry
    const uint2* ep = epack + start;
    const char*  hb = (const char*)h + c8 * 16;

    f16x2 a[4] = {(f16x2)0, (f16x2)0, (f16x2)0, (f16x2)0};

    auto batch = [&](int j) {
        int jj = j + e8;
        bool valid = jj < cnt;
        uint2 mv = ep[valid ? jj : 0];
        f16x2 w2 = bits2h2((valid && okc) ? mv.y : 0u);
        uint4 hv = *(const uint4*)(hb + (okc ? mv.x : 0u));
        a[0] += bits2h2(hv.x) * w2;
        a[1] += bits2h2(hv.y) * w2;
        a[2] += bits2h2(hv.z) * w2;
        a[3] += bits2h2(hv.w) * w2;
    };

    // up to 4 rounds in flight (covers deg+1 <= 32; loop handles the rest)
    batch(0);
    if (cnt > 8)  batch(8);
    if (cnt > 16) batch(16);
    if (cnt > 24) batch(24);
    for (int j = 32; j < cnt; j += 8) batch(j);

#pragma unroll
    for (int off = 8; off < 64; off <<= 1) {
#pragma unroll
        for (int i = 0; i < 4; ++i) {
            unsigned int u = __builtin_bit_cast(unsigned int, a[i]);
            a[i] += bits2h2((unsigned int)__shfl_xor((int)u, off));
        }
    }

    float av[8] = {(float)a[0][0], (float)a[0][1], (float)a[1][0], (float)a[1][1],
                   (float)a[2][0], (float)a[2][1], (float)a[3][0], (float)a[3][1]};
    float vals[8];
    float mx = -INFINITY;
    if (okc) {
        float4 bb0 = *(const float4*)(bias + c8 * 8), bb1 = *(const float4*)(bias + c8 * 8 + 4);
        float bbv[8] = {bb0.x, bb0.y, bb0.z, bb0.w, bb1.x, bb1.y, bb1.z, bb1.w};
#pragma unroll
        for (int i = 0; i < 8; ++i) {
            vals[i] = av[i] + bbv[i];
            mx = fmaxf(mx, vals[i]);
        }
    }
#pragma unroll
    for (int o = 1; o < 8; o <<= 1) mx = fmaxf(mx, __shfl_xor(mx, o));
    float es = 0.f;
    if (okc) {
#pragma unroll
        for (int i = 0; i < 8; ++i) es += expf(vals[i] - mx);
    }
#pragma unroll
    for (int o = 1; o < 8; o <<= 1) es += __shfl_xor(es, o);
    float ls = logf(es);

    if (e8 == 0 && okc) {
        float* op = out + (long)node * 40 + c8 * 8;
        *(float4*)op = make_float4(vals[0] - mx - ls, vals[1] - mx - ls,
                                   vals[2] - mx - ls, vals[3] - mx - ls);
        *(float4*)(op + 4) = make_float4(vals[4] - mx - ls, vals[5] - mx - ls,
                                         vals[6] - mx - ls, vals[7] - mx - ls);
    }
}

extern "C" void kernel_launch(void* const* d_in, const int* in_sizes, int n_in,
                              void* d_out, int out_size, void* d_ws, size_t ws_size,
                              hipStream_t stream) {
    const float* x   = (const float*)d_in[0];
    const int*   ei  = (const int*)d_in[1];
    const float* W1  = (const float*)d_in[2];
    const float* b1  = (const float*)d_in[3];
    const float* g1  = (const float*)d_in[4];
    const float* be1 = (const float*)d_in[5];
    const float* m1  = (const float*)d_in[6];
    const float* v1  = (const float*)d_in[7];
    const float* W2  = (const float*)d_in[8];
    const float* b2  = (const float*)d_in[9];
    const float* g2  = (const float*)d_in[10];
    const float* be2 = (const float*)d_in[11];
    const float* m2  = (const float*)d_in[12];
    const float* v2  = (const float*)d_in[13];
    const float* W3  = (const float*)d_in[14];
    const float* b3  = (const float*)d_in[15];
    float* out = (float*)d_out;

    // workspace layout (units: floats from base; all 16B-aligned)
    float* ws        = (float*)d_ws;
    float* dis       = ws;                            // 100096
    int*   degi      = (int*)(ws + 100096);
    int*   cursor    = (int*)(ws + 200192);
    int*   rowptr    = (int*)(ws + 300288);           // 100096 (incl sentinel)
    int*   blocksum  = (int*)(ws + 400384);           // 128
    int*   blockbase = (int*)(ws + 400512);           // 128
    uint2* epack     = (uint2*)(ws + 400640);         // (E+N) uint2 = 3.4M floats
    unsigned short* h1 = (unsigned short*)(ws + 3800640);     // N*64 f16
    unsigned short* h2 = (unsigned short*)(ws + 7000640);
    unsigned short* h3 = (unsigned short*)(ws + 10200640);
    unsigned short* wb1 = (unsigned short*)(ws + 13400640);   // 32768 f16
    unsigned short* wb2 = (unsigned short*)(ws + 13417024);   // 4096
    unsigned short* wb3 = (unsigned short*)(ws + 13419072);   // 4096
    unsigned short* sc1 = (unsigned short*)(ws + 13421120);   // 128 f16
    unsigned short* sc2 = sc1 + 128;

    // ---- CSR build (self-loops included as explicit entries) ----
    hipMemsetAsync(degi, 0, 100096 * sizeof(int), stream);
    k_count_deg<<<cdiv(N_EDGES, 256), 256, 0, stream>>>(ei, degi);
    k_scan1<<<SCAN_NB, 256, 0, stream>>>(degi, rowptr, blocksum, dis);
    k_scan2<<<1, 128, 0, stream>>>(blocksum, blockbase);
    k_scan3<<<SCAN_NB, 256, 0, stream>>>(rowptr, blockbase, degi, cursor, epack);
    k_permute<<<cdiv(N_EDGES, 256), 256, 0, stream>>>(ei, rowptr, cursor, dis, epack);

    // ---- weight pack + BN fold ----
    k_convall<<<160, 256, 0, stream>>>(W1, W2, W3, wb1, wb2, wb3);
    k_bnfold<<<1, 128, 0, stream>>>(b1, g1, be1, m1, v1, b2, g2, be2, m2, v2, sc1, sc2);

    const int agg_grid = cdiv(N_NODES, 4);

    // ---- layer 1: fused transpose+convert+GEMM (500 -> 64) ----
    k_l1fused<<<NTILE, 256, 0, stream>>>(x, wb1, h1);

    // ---- agg1 + BN1/ReLU + GEMM2 (fused) ----
    k_agg_gemm<<<NTILE, 256, 0, stream>>>(h1, rowptr, epack, sc1, wb2, h2);

    // ---- agg2 + BN2/ReLU + GEMM3 (fused; h3 64-wide, cols 40..63 zero) ----
    k_agg_gemm<<<NTILE, 256, 0, stream>>>(h2, rowptr, epack, sc2, wb3, h3);

    // ---- agg3 + bias + log_softmax ----
    k_agg_lsm<<<agg_grid, 256, 0, stream>>>(h3, rowptr, epack, b3, out);
}